// Round 1
// baseline (6678.233 us; speedup 1.0000x reference)
//
#include <hip/hip_runtime.h>
#include <math.h>

// Problem constants (fixed by the reference)
#define N_SUP 65536
#define E_DIM 512
#define H_HEADS 8
#define C_CLS 64
#define DHD 64
#define L_LEV 3
#define LN_EPS 1e-5f

// ---------------------------------------------------------------------------
// GEMM: C[M x 512] = A[M x 512] @ W[512 x 512] + bias[512]
// 128x128 tile, BK=16, 256 threads, 8x8 per thread register blocking.
// ---------------------------------------------------------------------------
#define BM 128
#define BN 128
#define BKK 16
#define TM 8
#define TN 8

__global__ __launch_bounds__(256)
void sgemm_bias(const float* __restrict__ A, const float* __restrict__ W,
                const float* __restrict__ bias, float* __restrict__ C) {
    __shared__ float As[BKK][BM + 4];   // +4 keeps 16B alignment, breaks conflicts
    __shared__ float Bs[BKK][BN + 4];
    const int K = E_DIM, NC = E_DIM;
    const int bm = blockIdx.x, bn = blockIdx.y;
    const int tid = threadIdx.x;
    const int tx = tid & 15;        // 16 col-groups of 8
    const int ty = tid >> 4;        // 16 row-groups of 8
    const int row0 = bm * BM, col0 = bn * BN;

    float acc[TM][TN];
#pragma unroll
    for (int i = 0; i < TM; ++i)
#pragma unroll
        for (int j = 0; j < TN; ++j) acc[i][j] = 0.f;

    const int arow = tid >> 4;      // 0..15
    const int acol = tid & 15;      // k index within tile
    const int brow = tid >> 7;      // 0..1
    const int bcol = tid & 127;

    for (int k0 = 0; k0 < K; k0 += BKK) {
        // A tile: 128 rows x 16 k, stored transposed As[k][row]
#pragma unroll
        for (int p = 0; p < 8; ++p) {
            int r = arow + p * 16;
            As[acol][r] = A[(size_t)(row0 + r) * K + (k0 + acol)];
        }
        // B tile: 16 k x 128 cols
#pragma unroll
        for (int p = 0; p < 8; ++p) {
            int r = brow + p * 2;
            Bs[r][bcol] = W[(size_t)(k0 + r) * NC + (col0 + bcol)];
        }
        __syncthreads();
#pragma unroll
        for (int kk = 0; kk < BKK; ++kk) {
            float a[TM], b[TN];
#pragma unroll
            for (int i = 0; i < TM; ++i) a[i] = As[kk][ty * TM + i];
#pragma unroll
            for (int j = 0; j < TN; ++j) b[j] = Bs[kk][tx * TN + j];
#pragma unroll
            for (int i = 0; i < TM; ++i)
#pragma unroll
                for (int j = 0; j < TN; ++j)
                    acc[i][j] = fmaf(a[i], b[j], acc[i][j]);
        }
        __syncthreads();
    }
#pragma unroll
    for (int i = 0; i < TM; ++i) {
        int row = row0 + ty * TM + i;
#pragma unroll
        for (int j = 0; j < TN; ++j) {
            int col = col0 + tx * TN + j;
            C[(size_t)row * NC + col] = acc[i][j] + bias[col];
        }
    }
}

// ---------------------------------------------------------------------------
// In-place LayerNorm (biased var, eps=1e-5) + ReLU over rows of 512.
// One block (256 threads) per row; 2 elements per thread.
// ---------------------------------------------------------------------------
__global__ __launch_bounds__(256)
void ln_relu(float* __restrict__ P, const float* __restrict__ gamma,
             const float* __restrict__ beta) {
    const int row = blockIdx.x;
    const int tid = threadIdx.x;
    const size_t base = (size_t)row * E_DIM;
    float x0 = P[base + tid];
    float x1 = P[base + tid + 256];
    float s = x0 + x1;
    float s2 = x0 * x0 + x1 * x1;
#pragma unroll
    for (int off = 32; off; off >>= 1) {
        s  += __shfl_xor(s, off);
        s2 += __shfl_xor(s2, off);
    }
    __shared__ float red[8];
    const int wave = tid >> 6, lane = tid & 63;
    if (lane == 0) { red[wave] = s; red[wave + 4] = s2; }
    __syncthreads();
    s  = red[0] + red[1] + red[2] + red[3];
    s2 = red[4] + red[5] + red[6] + red[7];
    const float mean = s * (1.f / E_DIM);
    const float var  = s2 * (1.f / E_DIM) - mean * mean;
    const float rstd = rsqrtf(var + LN_EPS);
    float y0 = (x0 - mean) * rstd * gamma[tid] + beta[tid];
    float y1 = (x1 - mean) * rstd * gamma[tid + 256] + beta[tid + 256];
    P[base + tid]       = fmaxf(y0, 0.f);
    P[base + tid + 256] = fmaxf(y1, 0.f);
}

// ---------------------------------------------------------------------------
// Class-membership preprocessing: counts, offsets, member lists (counting sort)
// ---------------------------------------------------------------------------
__global__ void init_counts(int* counts, int* cursor) {
    int t = threadIdx.x;
    if (t < C_CLS) { counts[t] = 0; cursor[t] = 0; }
}

__global__ void hist_kernel(const int* __restrict__ labels, int* counts) {
    int i = blockIdx.x * blockDim.x + threadIdx.x;
    if (i < N_SUP) atomicAdd(&counts[labels[i]], 1);
}

__global__ void offsets_kernel(const int* __restrict__ counts, int* offsets) {
    if (threadIdx.x == 0) {
        int a = 0;
        for (int c = 0; c < C_CLS; ++c) { offsets[c] = a; a += counts[c]; }
        offsets[C_CLS] = a;
    }
}

__global__ void scatter_kernel(const int* __restrict__ labels,
                               const int* __restrict__ offsets,
                               int* cursor, int* members) {
    int i = blockIdx.x * blockDim.x + threadIdx.x;
    if (i < N_SUP) {
        int c = labels[i];
        int p = atomicAdd(&cursor[c], 1);
        members[offsets[c] + p] = i;
    }
}

// ---------------------------------------------------------------------------
// ctx[c,:] = mean over class members of feat[n,:]
// grid (C, 8): block = class c, 64-column chunk; 4 members in flight.
// ---------------------------------------------------------------------------
__global__ __launch_bounds__(256)
void ctx_mean(const float* __restrict__ feat, const int* __restrict__ members,
              const int* __restrict__ offsets, const int* __restrict__ counts,
              float* __restrict__ ctx) {
    const int c = blockIdx.x, chunk = blockIdx.y;
    const int tid = threadIdx.x;
    const int sub = tid >> 6, lane = tid & 63;
    const int col = chunk * 64 + lane;
    const int start = offsets[c], end = offsets[c + 1];
    float acc = 0.f;
    for (int i = start + sub; i < end; i += 4) {
        int n = members[i];
        acc += feat[(size_t)n * E_DIM + col];
    }
    __shared__ float red[4][64];
    red[sub][lane] = acc;
    __syncthreads();
    if (sub == 0) {
        float t = red[0][lane] + red[1][lane] + red[2][lane] + red[3][lane];
        ctx[c * E_DIM + col] = t / (float)counts[c];
    }
}

// ---------------------------------------------------------------------------
// q[c,:] = ctx[c,:] @ Wq + bq   (tiny GEMM, one block per class row)
// ---------------------------------------------------------------------------
__global__ __launch_bounds__(256)
void row_gemm_q(const float* __restrict__ ctx, const float* __restrict__ Wq,
                const float* __restrict__ bq, float* __restrict__ q) {
    const int c = blockIdx.x;
    const int tid = threadIdx.x;
    __shared__ float xrow[E_DIM];
    xrow[tid]       = ctx[c * E_DIM + tid];
    xrow[tid + 256] = ctx[c * E_DIM + tid + 256];
    __syncthreads();
    float a0 = 0.f, a1 = 0.f;
#pragma unroll 8
    for (int k = 0; k < E_DIM; ++k) {
        float cv = xrow[k];
        a0 = fmaf(cv, Wq[(size_t)k * E_DIM + tid], a0);
        a1 = fmaf(cv, Wq[(size_t)k * E_DIM + tid + 256], a1);
    }
    q[c * E_DIM + tid]       = a0 + bq[tid];
    q[c * E_DIM + tid + 256] = a1 + bq[tid + 256];
}

// ---------------------------------------------------------------------------
// Segment attention: block per (class, head). Online softmax over members.
// One wave handles every 4th member; lane j owns dim j of DH=64.
// ---------------------------------------------------------------------------
__global__ __launch_bounds__(256)
void attn_kernel(const float* __restrict__ q, const float* __restrict__ kbuf,
                 const float* __restrict__ vbuf, const int* __restrict__ members,
                 const int* __restrict__ offsets, float* __restrict__ attn_out) {
    const int c = blockIdx.x, h = blockIdx.y;
    const int tid = threadIdx.x;
    const int wave = tid >> 6, lane = tid & 63;
    const float qj = q[c * E_DIM + h * DHD + lane];
    const int start = offsets[c], end = offsets[c + 1];
    float m = -INFINITY, lsum = 0.f, acc = 0.f;
    for (int i = start + wave; i < end; i += 4) {
        int n = members[i];
        size_t base = (size_t)n * E_DIM + h * DHD;
        float kv = kbuf[base + lane];
        float vv = vbuf[base + lane];
        float d = qj * kv;
#pragma unroll
        for (int off = 32; off; off >>= 1) d += __shfl_xor(d, off);
        float sc = d * 0.125f;               // * 1/sqrt(DH)
        float nm = fmaxf(m, sc);
        float alpha = expf(m - nm);          // m=-inf first iter -> 0
        float p = expf(sc - nm);
        lsum = lsum * alpha + p;
        acc  = acc  * alpha + p * vv;
        m = nm;
    }
    __shared__ float rm[4], rl[4], racc[4][64];
    racc[wave][lane] = acc;
    if (lane == 0) { rm[wave] = m; rl[wave] = lsum; }
    __syncthreads();
    if (wave == 0) {
        float M = fmaxf(fmaxf(rm[0], rm[1]), fmaxf(rm[2], rm[3]));
        float o = 0.f, Lt = 0.f;
#pragma unroll
        for (int w = 0; w < 4; ++w) {
            float al = expf(rm[w] - M);      // empty wave (m=-inf) -> 0
            o  += al * racc[w][lane];
            Lt += al * rl[w];
        }
        attn_out[c * E_DIM + h * DHD + lane] = o / Lt;
    }
}

// ---------------------------------------------------------------------------
// proto = attn_out @ Wo + bo; out (+)= coef_l * proto, coef = softmax(lw)/temp
// ---------------------------------------------------------------------------
__global__ __launch_bounds__(256)
void proto_accum(const float* __restrict__ attn_out, const float* __restrict__ Wo,
                 const float* __restrict__ bo, const float* __restrict__ lvlw,
                 const float* __restrict__ lvlt, int l, float* __restrict__ out) {
    const int c = blockIdx.x;
    const int tid = threadIdx.x;
    __shared__ float xrow[E_DIM];
    xrow[tid]       = attn_out[c * E_DIM + tid];
    xrow[tid + 256] = attn_out[c * E_DIM + tid + 256];
    __syncthreads();
    float a0 = 0.f, a1 = 0.f;
#pragma unroll 8
    for (int k = 0; k < E_DIM; ++k) {
        float cv = xrow[k];
        a0 = fmaf(cv, Wo[(size_t)k * E_DIM + tid], a0);
        a1 = fmaf(cv, Wo[(size_t)k * E_DIM + tid + 256], a1);
    }
    float w0 = lvlw[0], w1 = lvlw[1], w2 = lvlw[2];
    float mx = fmaxf(w0, fmaxf(w1, w2));
    float e0 = expf(w0 - mx), e1 = expf(w1 - mx), e2 = expf(w2 - mx);
    float ssum = e0 + e1 + e2;
    float lw = (l == 0 ? e0 : (l == 1 ? e1 : e2)) / ssum;
    float coef = lw / lvlt[l];
    float r0 = (a0 + bo[tid]) * coef;
    float r1 = (a1 + bo[tid + 256]) * coef;
    if (l == 0) {
        out[c * E_DIM + tid]       = r0;
        out[c * E_DIM + tid + 256] = r1;
    } else {
        out[c * E_DIM + tid]       += r0;
        out[c * E_DIM + tid + 256] += r1;
    }
}

// ---------------------------------------------------------------------------
extern "C" void kernel_launch(void* const* d_in, const int* in_sizes, int n_in,
                              void* d_out, int out_size, void* d_ws, size_t ws_size,
                              hipStream_t stream) {
    const float* X      = (const float*)d_in[0];
    const int*   labels = (const int*)  d_in[1];
    const float* W1     = (const float*)d_in[2];
    const float* b1     = (const float*)d_in[3];
    const float* gamma  = (const float*)d_in[4];
    const float* beta   = (const float*)d_in[5];
    const float* W2     = (const float*)d_in[6];
    const float* b2     = (const float*)d_in[7];
    const float* Wq     = (const float*)d_in[8];
    const float* bq     = (const float*)d_in[9];
    const float* Wk     = (const float*)d_in[10];
    const float* bk     = (const float*)d_in[11];
    const float* Wv     = (const float*)d_in[12];
    const float* bv     = (const float*)d_in[13];
    const float* Wo     = (const float*)d_in[14];
    const float* bo     = (const float*)d_in[15];
    const float* lvlw   = (const float*)d_in[16];
    const float* lvlt   = (const float*)d_in[17];
    float* out = (float*)d_out;

    // Workspace carve (~403 MB)
    char* p = (char*)d_ws;
    const size_t big = (size_t)N_SUP * E_DIM * sizeof(float);
    float* bufA = (float*)p; p += big;   // pre/h, later k
    float* bufB = (float*)p; p += big;   // feat
    float* bufC = (float*)p; p += big;   // v
    float* ctx  = (float*)p; p += C_CLS * E_DIM * sizeof(float);
    float* qb   = (float*)p; p += C_CLS * E_DIM * sizeof(float);
    float* ao   = (float*)p; p += C_CLS * E_DIM * sizeof(float);
    int* counts = (int*)p; p += 256;
    int* cursor = (int*)p; p += 256;
    int* offs   = (int*)p; p += 512;
    int* members= (int*)p; p += (size_t)N_SUP * sizeof(int);

    // Class membership preprocessing (ws is re-poisoned every call)
    init_counts<<<1, 64, 0, stream>>>(counts, cursor);
    hist_kernel<<<(N_SUP + 255) / 256, 256, 0, stream>>>(labels, counts);
    offsets_kernel<<<1, 1, 0, stream>>>(counts, offs);
    scatter_kernel<<<(N_SUP + 255) / 256, 256, 0, stream>>>(labels, offs, cursor, members);

    const dim3 gGemm(N_SUP / BM, E_DIM / BN);
    for (int l = 0; l < L_LEV; ++l) {
        const float* W1l = W1 + (size_t)l * E_DIM * E_DIM;
        const float* W2l = W2 + (size_t)l * E_DIM * E_DIM;
        // pre = X @ W1 + b1 -> bufA
        sgemm_bias<<<gGemm, 256, 0, stream>>>(X, W1l, b1 + l * E_DIM, bufA);
        // h = relu(LN(pre)) in-place
        ln_relu<<<N_SUP, 256, 0, stream>>>(bufA, gamma + l * E_DIM, beta + l * E_DIM);
        // feat = h @ W2 + b2 -> bufB
        sgemm_bias<<<gGemm, 256, 0, stream>>>(bufA, W2l, b2 + l * E_DIM, bufB);
        // k = feat @ Wk + bk -> bufA (h is dead)
        sgemm_bias<<<gGemm, 256, 0, stream>>>(bufB, Wk, bk, bufA);
        // v = feat @ Wv + bv -> bufC
        sgemm_bias<<<gGemm, 256, 0, stream>>>(bufB, Wv, bv, bufC);
        // ctx = segment mean of feat
        ctx_mean<<<dim3(C_CLS, 8), 256, 0, stream>>>(bufB, members, offs, counts, ctx);
        // q = ctx @ Wq + bq
        row_gemm_q<<<C_CLS, 256, 0, stream>>>(ctx, Wq, bq, qb);
        // segment attention -> ao
        attn_kernel<<<dim3(C_CLS, H_HEADS), 256, 0, stream>>>(qb, bufA, bufC, members, offs, ao);
        // out (+)= coef_l * (ao @ Wo + bo)
        proto_accum<<<C_CLS, 256, 0, stream>>>(ao, Wo, bo, lvlw, lvlt, l, out);
    }
}

// Round 2
// 2570.388 us; speedup vs baseline: 2.5981x; 2.5981x over previous
//
#include <hip/hip_runtime.h>
#include <math.h>

// Problem constants (fixed by the reference)
#define N_SUP 65536
#define E_DIM 512
#define H_HEADS 8
#define C_CLS 64
#define DHD 64
#define L_LEV 3
#define LN_EPS 1e-5f

typedef _Float16 f16x8 __attribute__((ext_vector_type(8)));
typedef _Float16 f16x4 __attribute__((ext_vector_type(4)));
typedef float f32x4 __attribute__((ext_vector_type(4)));

// ---------------------------------------------------------------------------
// async global->LDS copy, 16B per lane. LDS dest must be wave-uniform;
// HW deposits at ldsbase + lane*16.
// ---------------------------------------------------------------------------
__device__ __forceinline__ void gload_lds16(const void* g, void* lds) {
    __builtin_amdgcn_global_load_lds((const __attribute__((address_space(1))) void*)g,
                                     (__attribute__((address_space(3))) void*)lds,
                                     16, 0, 0);
}

// ---------------------------------------------------------------------------
// fp16 GEMM: C[M x 512] = A[M x 512] @ B + bias, where Bt is B^T [512 x 512]
// (row n holds column n of B, k-contiguous). Output fp16.
// 128x128 tile, BK=32, 4 waves in 2x2, each wave 4x4 grid of 16x16x32 MFMA.
// LDS tiles hold k-chunks XOR-swizzled by ((row>>1)&3) to spread banks; the
// gather staging absorbs the swizzle on the global-address side for free.
// ---------------------------------------------------------------------------
__global__ __launch_bounds__(256)
void hgemm_bt(const _Float16* __restrict__ A, const _Float16* __restrict__ Bt,
              const float* __restrict__ bias, _Float16* __restrict__ C) {
    __shared__ _Float16 As[128][32];
    __shared__ _Float16 Bs[128][32];
    const int tid = threadIdx.x;
    const int wave = tid >> 6, lane = tid & 63;
    const int row0 = blockIdx.x * 128, col0 = blockIdx.y * 128;
    const int wm = (wave & 1) * 64, wn = (wave >> 1) * 64;

    // Staging geometry: 512 chunks of 16B per tile; wave w stages chunks
    // [w*128, w*128+128) via two instructions of 64 chunks.
    const int ci0 = wave * 128 + lane, ci1 = ci0 + 64;
    const int r0 = ci0 >> 2, gc0 = (ci0 & 3) ^ ((r0 >> 1) & 3);
    const int r1 = ci1 >> 2, gc1 = (ci1 & 3) ^ ((r1 >> 1) & 3);
    const _Float16* Ar0 = A + (size_t)(row0 + r0) * E_DIM + gc0 * 8;
    const _Float16* Ar1 = A + (size_t)(row0 + r1) * E_DIM + gc1 * 8;
    const _Float16* Br0 = Bt + (size_t)(col0 + r0) * E_DIM + gc0 * 8;
    const _Float16* Br1 = Bt + (size_t)(col0 + r1) * E_DIM + gc1 * 8;
    char* ldsA = (char*)&As[0][0] + wave * 2048;
    char* ldsB = (char*)&Bs[0][0] + wave * 2048;

    const int m = lane & 15, q = lane >> 4;
    const int koff = ((q ^ ((m >> 1) & 3))) * 8;   // de-swizzled k-chunk

    f32x4 acc[4][4];
#pragma unroll
    for (int i = 0; i < 4; ++i)
#pragma unroll
        for (int j = 0; j < 4; ++j) acc[i][j] = (f32x4){0.f, 0.f, 0.f, 0.f};

    for (int k0 = 0; k0 < E_DIM; k0 += 32) {
        gload_lds16(Ar0 + k0, ldsA);
        gload_lds16(Ar1 + k0, ldsA + 1024);
        gload_lds16(Br0 + k0, ldsB);
        gload_lds16(Br1 + k0, ldsB + 1024);
        __syncthreads();   // drains vmcnt (global_load_lds) before use

        f16x8 af[4], bf[4];
#pragma unroll
        for (int i = 0; i < 4; ++i)
            af[i] = *(const f16x8*)&As[wm + i * 16 + m][koff];
#pragma unroll
        for (int j = 0; j < 4; ++j)
            bf[j] = *(const f16x8*)&Bs[wn + j * 16 + m][koff];
#pragma unroll
        for (int i = 0; i < 4; ++i)
#pragma unroll
            for (int j = 0; j < 4; ++j)
                acc[i][j] = __builtin_amdgcn_mfma_f32_16x16x32_f16(af[i], bf[j], acc[i][j], 0, 0, 0);
        __syncthreads();   // protect LDS tiles before next staging
    }

    // C/D layout: col = lane&15, row = (lane>>4)*4 + reg
#pragma unroll
    for (int i = 0; i < 4; ++i) {
        const int rbase = row0 + wm + i * 16 + q * 4;
#pragma unroll
        for (int j = 0; j < 4; ++j) {
            const int col = col0 + wn + j * 16 + m;
            const float bv = bias[col];
#pragma unroll
            for (int r = 0; r < 4; ++r)
                C[(size_t)(rbase + r) * E_DIM + col] = (_Float16)(acc[i][j][r] + bv);
        }
    }
}

// ---------------------------------------------------------------------------
// fp32 -> fp16 elementwise (vectorized x4)
// ---------------------------------------------------------------------------
__global__ __launch_bounds__(256)
void conv32to16(const float* __restrict__ in, _Float16* __restrict__ out, int n4) {
    int i = blockIdx.x * 256 + threadIdx.x;
    if (i < n4) {
        f32x4 v = ((const f32x4*)in)[i];
        f16x4 o = {(_Float16)v[0], (_Float16)v[1], (_Float16)v[2], (_Float16)v[3]};
        ((f16x4*)out)[i] = o;
    }
}

// ---------------------------------------------------------------------------
// W[512x512] fp32 (k-major) -> Wt[512x512] fp16 (n-major), LDS-tiled transpose
// ---------------------------------------------------------------------------
__global__ __launch_bounds__(256)
void transpose_w_f16(const float* __restrict__ W, _Float16* __restrict__ Wt) {
    __shared__ float t[32][33];
    const int k0 = blockIdx.x * 32, n0 = blockIdx.y * 32;
    const int tx = threadIdx.x & 31, ty = threadIdx.x >> 5;  // 8 rows per pass
#pragma unroll
    for (int r = 0; r < 32; r += 8)
        t[ty + r][tx] = W[(size_t)(k0 + ty + r) * E_DIM + n0 + tx];
    __syncthreads();
#pragma unroll
    for (int r = 0; r < 32; r += 8)
        Wt[(size_t)(n0 + ty + r) * E_DIM + k0 + tx] = (_Float16)t[tx][ty + r];
}

// ---------------------------------------------------------------------------
// In-place LayerNorm (biased var) + ReLU on fp16 rows of 512, fp32 stats.
// ---------------------------------------------------------------------------
__global__ __launch_bounds__(256)
void ln_relu_h(_Float16* __restrict__ P, const float* __restrict__ gamma,
               const float* __restrict__ beta) {
    const int row = blockIdx.x;
    const int tid = threadIdx.x;
    const size_t base = (size_t)row * E_DIM;
    float x0 = (float)P[base + tid];
    float x1 = (float)P[base + tid + 256];
    float s = x0 + x1;
    float s2 = x0 * x0 + x1 * x1;
#pragma unroll
    for (int off = 32; off; off >>= 1) {
        s  += __shfl_xor(s, off);
        s2 += __shfl_xor(s2, off);
    }
    __shared__ float red[8];
    const int wave = tid >> 6, lane = tid & 63;
    if (lane == 0) { red[wave] = s; red[wave + 4] = s2; }
    __syncthreads();
    s  = red[0] + red[1] + red[2] + red[3];
    s2 = red[4] + red[5] + red[6] + red[7];
    const float mean = s * (1.f / E_DIM);
    const float var  = s2 * (1.f / E_DIM) - mean * mean;
    const float rstd = rsqrtf(var + LN_EPS);
    float y0 = (x0 - mean) * rstd * gamma[tid] + beta[tid];
    float y1 = (x1 - mean) * rstd * gamma[tid + 256] + beta[tid + 256];
    P[base + tid]       = (_Float16)fmaxf(y0, 0.f);
    P[base + tid + 256] = (_Float16)fmaxf(y1, 0.f);
}

// ---------------------------------------------------------------------------
// Class-membership preprocessing
// ---------------------------------------------------------------------------
__global__ void init_counts(int* counts, int* cursor) {
    int t = threadIdx.x;
    if (t < C_CLS) { counts[t] = 0; cursor[t] = 0; }
}

__global__ void hist_kernel(const int* __restrict__ labels, int* counts) {
    int i = blockIdx.x * blockDim.x + threadIdx.x;
    if (i < N_SUP) atomicAdd(&counts[labels[i]], 1);
}

__global__ void offsets_kernel(const int* __restrict__ counts, int* offsets) {
    if (threadIdx.x == 0) {
        int a = 0;
        for (int c = 0; c < C_CLS; ++c) { offsets[c] = a; a += counts[c]; }
        offsets[C_CLS] = a;
    }
}

__global__ void scatter_kernel(const int* __restrict__ labels,
                               const int* __restrict__ offsets,
                               int* cursor, int* members) {
    int i = blockIdx.x * blockDim.x + threadIdx.x;
    if (i < N_SUP) {
        int c = labels[i];
        int p = atomicAdd(&cursor[c], 1);
        members[offsets[c] + p] = i;
    }
}

// ---------------------------------------------------------------------------
// ctx[c,:] = mean over class members of feat(fp16)[n,:]
// ---------------------------------------------------------------------------
__global__ __launch_bounds__(256)
void ctx_mean(const _Float16* __restrict__ feat, const int* __restrict__ members,
              const int* __restrict__ offsets, const int* __restrict__ counts,
              float* __restrict__ ctx) {
    const int c = blockIdx.x, chunk = blockIdx.y;
    const int tid = threadIdx.x;
    const int sub = tid >> 6, lane = tid & 63;
    const int col = chunk * 64 + lane;
    const int start = offsets[c], end = offsets[c + 1];
    float acc = 0.f;
    for (int i = start + sub; i < end; i += 4) {
        int n = members[i];
        acc += (float)feat[(size_t)n * E_DIM + col];
    }
    __shared__ float red[4][64];
    red[sub][lane] = acc;
    __syncthreads();
    if (sub == 0) {
        float t = red[0][lane] + red[1][lane] + red[2][lane] + red[3][lane];
        ctx[c * E_DIM + col] = t / (float)counts[c];
    }
}

// ---------------------------------------------------------------------------
// q[c,:] = ctx[c,:] @ Wq + bq   (fp32, tiny)
// ---------------------------------------------------------------------------
__global__ __launch_bounds__(256)
void row_gemm_q(const float* __restrict__ ctx, const float* __restrict__ Wq,
                const float* __restrict__ bq, float* __restrict__ q) {
    const int c = blockIdx.x;
    const int tid = threadIdx.x;
    __shared__ float xrow[E_DIM];
    xrow[tid]       = ctx[c * E_DIM + tid];
    xrow[tid + 256] = ctx[c * E_DIM + tid + 256];
    __syncthreads();
    float a0 = 0.f, a1 = 0.f;
#pragma unroll 8
    for (int k = 0; k < E_DIM; ++k) {
        float cv = xrow[k];
        a0 = fmaf(cv, Wq[(size_t)k * E_DIM + tid], a0);
        a1 = fmaf(cv, Wq[(size_t)k * E_DIM + tid + 256], a1);
    }
    q[c * E_DIM + tid]       = a0 + bq[tid];
    q[c * E_DIM + tid + 256] = a1 + bq[tid + 256];
}

// ---------------------------------------------------------------------------
// Segment attention: block per (class, head); fp16 K/V, fp32 math.
// ---------------------------------------------------------------------------
__global__ __launch_bounds__(256)
void attn_kernel(const float* __restrict__ q, const _Float16* __restrict__ kbuf,
                 const _Float16* __restrict__ vbuf, const int* __restrict__ members,
                 const int* __restrict__ offsets, float* __restrict__ attn_out) {
    const int c = blockIdx.x, h = blockIdx.y;
    const int tid = threadIdx.x;
    const int wave = tid >> 6, lane = tid & 63;
    const float qj = q[c * E_DIM + h * DHD + lane];
    const int start = offsets[c], end = offsets[c + 1];
    float m = -INFINITY, lsum = 0.f, acc = 0.f;
    for (int i = start + wave; i < end; i += 4) {
        int n = members[i];
        size_t base = (size_t)n * E_DIM + h * DHD;
        float kv = (float)kbuf[base + lane];
        float vv = (float)vbuf[base + lane];
        float d = qj * kv;
#pragma unroll
        for (int off = 32; off; off >>= 1) d += __shfl_xor(d, off);
        float sc = d * 0.125f;               // * 1/sqrt(DH)
        float nm = fmaxf(m, sc);
        float alpha = expf(m - nm);          // m=-inf first iter -> 0
        float p = expf(sc - nm);
        lsum = lsum * alpha + p;
        acc  = acc  * alpha + p * vv;
        m = nm;
    }
    __shared__ float rm[4], rl[4], racc[4][64];
    racc[wave][lane] = acc;
    if (lane == 0) { rm[wave] = m; rl[wave] = lsum; }
    __syncthreads();
    if (wave == 0) {
        float M = fmaxf(fmaxf(rm[0], rm[1]), fmaxf(rm[2], rm[3]));
        float o = 0.f, Lt = 0.f;
#pragma unroll
        for (int w = 0; w < 4; ++w) {
            float al = expf(rm[w] - M);      // empty wave (m=-inf) -> 0
            o  += al * racc[w][lane];
            Lt += al * rl[w];
        }
        attn_out[c * E_DIM + h * DHD + lane] = o / Lt;
    }
}

// ---------------------------------------------------------------------------
// proto = attn_out @ Wo + bo; out (+)= coef_l * proto
// ---------------------------------------------------------------------------
__global__ __launch_bounds__(256)
void proto_accum(const float* __restrict__ attn_out, const float* __restrict__ Wo,
                 const float* __restrict__ bo, const float* __restrict__ lvlw,
                 const float* __restrict__ lvlt, int l, float* __restrict__ out) {
    const int c = blockIdx.x;
    const int tid = threadIdx.x;
    __shared__ float xrow[E_DIM];
    xrow[tid]       = attn_out[c * E_DIM + tid];
    xrow[tid + 256] = attn_out[c * E_DIM + tid + 256];
    __syncthreads();
    float a0 = 0.f, a1 = 0.f;
#pragma unroll 8
    for (int k = 0; k < E_DIM; ++k) {
        float cv = xrow[k];
        a0 = fmaf(cv, Wo[(size_t)k * E_DIM + tid], a0);
        a1 = fmaf(cv, Wo[(size_t)k * E_DIM + tid + 256], a1);
    }
    float w0 = lvlw[0], w1 = lvlw[1], w2 = lvlw[2];
    float mx = fmaxf(w0, fmaxf(w1, w2));
    float e0 = expf(w0 - mx), e1 = expf(w1 - mx), e2 = expf(w2 - mx);
    float ssum = e0 + e1 + e2;
    float lw = (l == 0 ? e0 : (l == 1 ? e1 : e2)) / ssum;
    float coef = lw / lvlt[l];
    float r0 = (a0 + bo[tid]) * coef;
    float r1 = (a1 + bo[tid + 256]) * coef;
    if (l == 0) {
        out[c * E_DIM + tid]       = r0;
        out[c * E_DIM + tid + 256] = r1;
    } else {
        out[c * E_DIM + tid]       += r0;
        out[c * E_DIM + tid + 256] += r1;
    }
}

// ---------------------------------------------------------------------------
extern "C" void kernel_launch(void* const* d_in, const int* in_sizes, int n_in,
                              void* d_out, int out_size, void* d_ws, size_t ws_size,
                              hipStream_t stream) {
    const float* X      = (const float*)d_in[0];
    const int*   labels = (const int*)  d_in[1];
    const float* W1     = (const float*)d_in[2];
    const float* b1     = (const float*)d_in[3];
    const float* gamma  = (const float*)d_in[4];
    const float* beta   = (const float*)d_in[5];
    const float* W2     = (const float*)d_in[6];
    const float* b2     = (const float*)d_in[7];
    const float* Wq     = (const float*)d_in[8];
    const float* bq     = (const float*)d_in[9];
    const float* Wk     = (const float*)d_in[10];
    const float* bk     = (const float*)d_in[11];
    const float* Wv     = (const float*)d_in[12];
    const float* bv     = (const float*)d_in[13];
    const float* Wo     = (const float*)d_in[14];
    const float* bo     = (const float*)d_in[15];
    const float* lvlw   = (const float*)d_in[16];
    const float* lvlt   = (const float*)d_in[17];
    float* out = (float*)d_out;

    // Workspace carve (~323 MB of fp16 big buffers + small fp32/int)
    char* p = (char*)d_ws;
    const size_t bigh = (size_t)N_SUP * E_DIM * sizeof(_Float16);   // 64 MB
    _Float16* Xh   = (_Float16*)p; p += bigh;
    _Float16* bufP = (_Float16*)p; p += bigh;   // pre -> h (in-place LN)
    _Float16* bufF = (_Float16*)p; p += bigh;   // feat
    _Float16* bufK = (_Float16*)p; p += bigh;   // k
    _Float16* bufV = (_Float16*)p; p += bigh;   // v
    _Float16* W1t  = (_Float16*)p; p += (size_t)E_DIM * E_DIM * sizeof(_Float16);
    _Float16* W2t  = (_Float16*)p; p += (size_t)E_DIM * E_DIM * sizeof(_Float16);
    _Float16* Wkt  = (_Float16*)p; p += (size_t)E_DIM * E_DIM * sizeof(_Float16);
    _Float16* Wvt  = (_Float16*)p; p += (size_t)E_DIM * E_DIM * sizeof(_Float16);
    float* ctx  = (float*)p; p += C_CLS * E_DIM * sizeof(float);
    float* qb   = (float*)p; p += C_CLS * E_DIM * sizeof(float);
    float* ao   = (float*)p; p += C_CLS * E_DIM * sizeof(float);
    int* counts = (int*)p; p += 256;
    int* cursor = (int*)p; p += 256;
    int* offs   = (int*)p; p += 512;
    int* members= (int*)p; p += (size_t)N_SUP * sizeof(int);

    // Class membership preprocessing
    init_counts<<<1, 64, 0, stream>>>(counts, cursor);
    hist_kernel<<<(N_SUP + 255) / 256, 256, 0, stream>>>(labels, counts);
    offsets_kernel<<<1, 1, 0, stream>>>(counts, offs);
    scatter_kernel<<<(N_SUP + 255) / 256, 256, 0, stream>>>(labels, offs, cursor, members);

    // One-time conversions
    const int n4 = N_SUP * E_DIM / 4;
    conv32to16<<<n4 / 256, 256, 0, stream>>>(X, Xh, n4);
    transpose_w_f16<<<dim3(16, 16), 256, 0, stream>>>(Wk, Wkt);
    transpose_w_f16<<<dim3(16, 16), 256, 0, stream>>>(Wv, Wvt);

    const dim3 gGemm(N_SUP / 128, E_DIM / 128);
    for (int l = 0; l < L_LEV; ++l) {
        const float* W1l = W1 + (size_t)l * E_DIM * E_DIM;
        const float* W2l = W2 + (size_t)l * E_DIM * E_DIM;
        transpose_w_f16<<<dim3(16, 16), 256, 0, stream>>>(W1l, W1t);
        transpose_w_f16<<<dim3(16, 16), 256, 0, stream>>>(W2l, W2t);
        // pre = Xh @ W1 + b1 -> bufP (fp16)
        hgemm_bt<<<gGemm, 256, 0, stream>>>(Xh, W1t, b1 + l * E_DIM, bufP);
        // h = relu(LN(pre)) in place
        ln_relu_h<<<N_SUP, 256, 0, stream>>>(bufP, gamma + l * E_DIM, beta + l * E_DIM);
        // feat = h @ W2 + b2 -> bufF
        hgemm_bt<<<gGemm, 256, 0, stream>>>(bufP, W2t, b2 + l * E_DIM, bufF);
        // k = feat @ Wk + bk ; v = feat @ Wv + bv
        hgemm_bt<<<gGemm, 256, 0, stream>>>(bufF, Wkt, bk, bufK);
        hgemm_bt<<<gGemm, 256, 0, stream>>>(bufF, Wvt, bv, bufV);
        // ctx = segment mean of feat
        ctx_mean<<<dim3(C_CLS, 8), 256, 0, stream>>>(bufF, members, offs, counts, ctx);
        // q = ctx @ Wq + bq
        row_gemm_q<<<C_CLS, 256, 0, stream>>>(ctx, Wq, bq, qb);
        // segment attention -> ao
        attn_kernel<<<dim3(C_CLS, H_HEADS), 256, 0, stream>>>(qb, bufK, bufV, members, offs, ao);
        // out (+)= coef_l * (ao @ Wo + bo)
        proto_accum<<<C_CLS, 256, 0, stream>>>(ao, Wo, bo, lvlw, lvlt, l, out);
    }
}

// Round 3
// 2249.328 us; speedup vs baseline: 2.9690x; 1.1427x over previous
//
#include <hip/hip_runtime.h>
#include <math.h>

// Problem constants (fixed by the reference)
#define N_SUP 65536
#define E_DIM 512
#define H_HEADS 8
#define C_CLS 64
#define DHD 64
#define L_LEV 3
#define LN_EPS 1e-5f

typedef _Float16 f16x8 __attribute__((ext_vector_type(8)));
typedef _Float16 f16x4 __attribute__((ext_vector_type(4)));
typedef float f32x4 __attribute__((ext_vector_type(4)));

// ---------------------------------------------------------------------------
// async global->LDS copy, 16B per lane. LDS dest must be wave-uniform;
// HW deposits at ldsbase + lane*16.
// ---------------------------------------------------------------------------
__device__ __forceinline__ void gload_lds16(const void* g, void* lds) {
    __builtin_amdgcn_global_load_lds((const __attribute__((address_space(1))) void*)g,
                                     (__attribute__((address_space(3))) void*)lds,
                                     16, 0, 0);
}

// ---------------------------------------------------------------------------
// fp16 GEMM: C[M x 512] = A[M x 512] @ B + bias, where Bt is B^T [512 x 512]
// (row n holds column n of B, k-contiguous). Output fp16.
// 128x128 tile, BK=32, 4 waves in 2x2, each wave 4x4 grid of 16x16x32 MFMA.
// ---------------------------------------------------------------------------
__global__ __launch_bounds__(256)
void hgemm_bt(const _Float16* __restrict__ A, const _Float16* __restrict__ Bt,
              const float* __restrict__ bias, _Float16* __restrict__ C) {
    __shared__ _Float16 As[128][32];
    __shared__ _Float16 Bs[128][32];
    const int tid = threadIdx.x;
    const int wave = tid >> 6, lane = tid & 63;
    const int row0 = blockIdx.x * 128, col0 = blockIdx.y * 128;
    const int wm = (wave & 1) * 64, wn = (wave >> 1) * 64;

    const int ci0 = wave * 128 + lane, ci1 = ci0 + 64;
    const int r0 = ci0 >> 2, gc0 = (ci0 & 3) ^ ((r0 >> 1) & 3);
    const int r1 = ci1 >> 2, gc1 = (ci1 & 3) ^ ((r1 >> 1) & 3);
    const _Float16* Ar0 = A + (size_t)(row0 + r0) * E_DIM + gc0 * 8;
    const _Float16* Ar1 = A + (size_t)(row0 + r1) * E_DIM + gc1 * 8;
    const _Float16* Br0 = Bt + (size_t)(col0 + r0) * E_DIM + gc0 * 8;
    const _Float16* Br1 = Bt + (size_t)(col0 + r1) * E_DIM + gc1 * 8;
    char* ldsA = (char*)&As[0][0] + wave * 2048;
    char* ldsB = (char*)&Bs[0][0] + wave * 2048;

    const int m = lane & 15, q = lane >> 4;
    const int koff = ((q ^ ((m >> 1) & 3))) * 8;

    f32x4 acc[4][4];
#pragma unroll
    for (int i = 0; i < 4; ++i)
#pragma unroll
        for (int j = 0; j < 4; ++j) acc[i][j] = (f32x4){0.f, 0.f, 0.f, 0.f};

    for (int k0 = 0; k0 < E_DIM; k0 += 32) {
        gload_lds16(Ar0 + k0, ldsA);
        gload_lds16(Ar1 + k0, ldsA + 1024);
        gload_lds16(Br0 + k0, ldsB);
        gload_lds16(Br1 + k0, ldsB + 1024);
        __syncthreads();

        f16x8 af[4], bf[4];
#pragma unroll
        for (int i = 0; i < 4; ++i)
            af[i] = *(const f16x8*)&As[wm + i * 16 + m][koff];
#pragma unroll
        for (int j = 0; j < 4; ++j)
            bf[j] = *(const f16x8*)&Bs[wn + j * 16 + m][koff];
#pragma unroll
        for (int i = 0; i < 4; ++i)
#pragma unroll
            for (int j = 0; j < 4; ++j)
                acc[i][j] = __builtin_amdgcn_mfma_f32_16x16x32_f16(af[i], bf[j], acc[i][j], 0, 0, 0);
        __syncthreads();
    }

    // C/D layout: col = lane&15, row = (lane>>4)*4 + reg
#pragma unroll
    for (int i = 0; i < 4; ++i) {
        const int rbase = row0 + wm + i * 16 + q * 4;
#pragma unroll
        for (int j = 0; j < 4; ++j) {
            const int col = col0 + wn + j * 16 + m;
            const float bv = bias[col];
#pragma unroll
            for (int r = 0; r < 4; ++r)
                C[(size_t)(rbase + r) * E_DIM + col] = (_Float16)(acc[i][j][r] + bv);
        }
    }
}

// ---------------------------------------------------------------------------
// fp32 -> fp16 elementwise (vectorized x4)
// ---------------------------------------------------------------------------
__global__ __launch_bounds__(256)
void conv32to16(const float* __restrict__ in, _Float16* __restrict__ out, int n4) {
    int i = blockIdx.x * 256 + threadIdx.x;
    if (i < n4) {
        f32x4 v = ((const f32x4*)in)[i];
        f16x4 o = {(_Float16)v[0], (_Float16)v[1], (_Float16)v[2], (_Float16)v[3]};
        ((f16x4*)out)[i] = o;
    }
}

// ---------------------------------------------------------------------------
// W[512x512] fp32 (k-major) -> Wt[512x512] fp16 (n-major), LDS-tiled transpose
// ---------------------------------------------------------------------------
__global__ __launch_bounds__(256)
void transpose_w_f16(const float* __restrict__ W, _Float16* __restrict__ Wt) {
    __shared__ float t[32][33];
    const int k0 = blockIdx.x * 32, n0 = blockIdx.y * 32;
    const int tx = threadIdx.x & 31, ty = threadIdx.x >> 5;
#pragma unroll
    for (int r = 0; r < 32; r += 8)
        t[ty + r][tx] = W[(size_t)(k0 + ty + r) * E_DIM + n0 + tx];
    __syncthreads();
#pragma unroll
    for (int r = 0; r < 32; r += 8)
        Wt[(size_t)(n0 + ty + r) * E_DIM + k0 + tx] = (_Float16)t[tx][ty + r];
}

// ---------------------------------------------------------------------------
// In-place LayerNorm (biased var) + ReLU on fp16 rows of 512, fp32 stats.
// ---------------------------------------------------------------------------
__global__ __launch_bounds__(256)
void ln_relu_h(_Float16* __restrict__ P, const float* __restrict__ gamma,
               const float* __restrict__ beta) {
    const int row = blockIdx.x;
    const int tid = threadIdx.x;
    const size_t base = (size_t)row * E_DIM;
    float x0 = (float)P[base + tid];
    float x1 = (float)P[base + tid + 256];
    float s = x0 + x1;
    float s2 = x0 * x0 + x1 * x1;
#pragma unroll
    for (int off = 32; off; off >>= 1) {
        s  += __shfl_xor(s, off);
        s2 += __shfl_xor(s2, off);
    }
    __shared__ float red[8];
    const int wave = tid >> 6, lane = tid & 63;
    if (lane == 0) { red[wave] = s; red[wave + 4] = s2; }
    __syncthreads();
    s  = red[0] + red[1] + red[2] + red[3];
    s2 = red[4] + red[5] + red[6] + red[7];
    const float mean = s * (1.f / E_DIM);
    const float var  = s2 * (1.f / E_DIM) - mean * mean;
    const float rstd = rsqrtf(var + LN_EPS);
    float y0 = (x0 - mean) * rstd * gamma[tid] + beta[tid];
    float y1 = (x1 - mean) * rstd * gamma[tid + 256] + beta[tid + 256];
    P[base + tid]       = (_Float16)fmaxf(y0, 0.f);
    P[base + tid + 256] = (_Float16)fmaxf(y1, 0.f);
}

// ---------------------------------------------------------------------------
// Class-membership preprocessing
// ---------------------------------------------------------------------------
__global__ void init_counts(int* counts, int* cursor) {
    int t = threadIdx.x;
    if (t < C_CLS) { counts[t] = 0; cursor[t] = 0; }
}

__global__ void hist_kernel(const int* __restrict__ labels, int* counts) {
    int i = blockIdx.x * blockDim.x + threadIdx.x;
    if (i < N_SUP) atomicAdd(&counts[labels[i]], 1);
}

__global__ void offsets_kernel(const int* __restrict__ counts, int* offsets) {
    if (threadIdx.x == 0) {
        int a = 0;
        for (int c = 0; c < C_CLS; ++c) { offsets[c] = a; a += counts[c]; }
        offsets[C_CLS] = a;
    }
}

__global__ void scatter_kernel(const int* __restrict__ labels,
                               const int* __restrict__ offsets,
                               int* cursor, int* members) {
    int i = blockIdx.x * blockDim.x + threadIdx.x;
    if (i < N_SUP) {
        int c = labels[i];
        int p = atomicAdd(&cursor[c], 1);
        members[offsets[c] + p] = i;
    }
}

// ---------------------------------------------------------------------------
// ctx[c,:] = mean over class members of feat(fp16)[n,:]
// ---------------------------------------------------------------------------
__global__ __launch_bounds__(256)
void ctx_mean(const _Float16* __restrict__ feat, const int* __restrict__ members,
              const int* __restrict__ offsets, const int* __restrict__ counts,
              float* __restrict__ ctx) {
    const int c = blockIdx.x, chunk = blockIdx.y;
    const int tid = threadIdx.x;
    const int sub = tid >> 6, lane = tid & 63;
    const int col = chunk * 64 + lane;
    const int start = offsets[c], end = offsets[c + 1];
    float acc = 0.f;
    for (int i = start + sub; i < end; i += 4) {
        int n = members[i];
        acc += (float)feat[(size_t)n * E_DIM + col];
    }
    __shared__ float red[4][64];
    red[sub][lane] = acc;
    __syncthreads();
    if (sub == 0) {
        float t = red[0][lane] + red[1][lane] + red[2][lane] + red[3][lane];
        ctx[c * E_DIM + col] = t / (float)counts[c];
    }
}

// ---------------------------------------------------------------------------
// q[c,:] = ctx[c,:] @ Wq + bq   (fp32, tiny)
// ---------------------------------------------------------------------------
__global__ __launch_bounds__(256)
void row_gemm_q(const float* __restrict__ ctx, const float* __restrict__ Wq,
                const float* __restrict__ bq, float* __restrict__ q) {
    const int c = blockIdx.x;
    const int tid = threadIdx.x;
    __shared__ float xrow[E_DIM];
    xrow[tid]       = ctx[c * E_DIM + tid];
    xrow[tid + 256] = ctx[c * E_DIM + tid + 256];
    __syncthreads();
    float a0 = 0.f, a1 = 0.f;
#pragma unroll 8
    for (int k = 0; k < E_DIM; ++k) {
        float cv = xrow[k];
        a0 = fmaf(cv, Wq[(size_t)k * E_DIM + tid], a0);
        a1 = fmaf(cv, Wq[(size_t)k * E_DIM + tid + 256], a1);
    }
    q[c * E_DIM + tid]       = a0 + bq[tid];
    q[c * E_DIM + tid + 256] = a1 + bq[tid + 256];
}

// ---------------------------------------------------------------------------
// Segment attention, member-per-lane chunked flash.
// Block = (class c, head h), 4 waves. Wave processes chunks of 64 members:
//   score phase: lane i owns member ch0+i, vector-loads its K row (8x f16x8,
//     independent -> deep MLP), dot vs q (wave-uniform scalar regs).
//   chunk online-softmax: 6-shuffle max amortized over 64 members.
//   PV phase: dim-parallel; p_j from LDS broadcast, n_j via shfl, coalesced
//     128B V-row reads.
// Final: combine 4 wave-partials (m, l, out) via LDS.
// ---------------------------------------------------------------------------
__global__ __launch_bounds__(256)
void attn_kernel(const float* __restrict__ q, const _Float16* __restrict__ kbuf,
                 const _Float16* __restrict__ vbuf, const int* __restrict__ members,
                 const int* __restrict__ offsets, float* __restrict__ attn_out) {
    const int c = blockIdx.x, h = blockIdx.y;
    const int tid = threadIdx.x;
    const int wave = tid >> 6, lane = tid & 63;
    const int start = offsets[c], end = offsets[c + 1];

    // q row: wave-uniform loads -> scalar registers
    const float* qrow = q + c * E_DIM + h * DHD;
    float qv[64];
#pragma unroll
    for (int d = 0; d < 64; ++d) qv[d] = qrow[d];

    __shared__ float ps[4][64];
    float m = -INFINITY, lsum = 0.f, out = 0.f;   // lane owns output dim `lane`

    for (int ch0 = start + wave * 64; ch0 < end; ch0 += 256) {
        const int nvalid = min(64, end - ch0);
        // ---- scores: lane i -> member ch0+i
        const int idx = ch0 + lane;
        const int mi = members[idx < end ? idx : end - 1];
        const _Float16* krow = kbuf + (size_t)mi * E_DIM + h * DHD;
        float dot = 0.f;
#pragma unroll
        for (int j = 0; j < 8; ++j) {
            f16x8 kr = *(const f16x8*)(krow + j * 8);
#pragma unroll
            for (int e = 0; e < 8; ++e)
                dot = fmaf((float)kr[e], qv[j * 8 + e], dot);
        }
        float sc = (lane < nvalid) ? dot * 0.125f : -INFINITY;
        // chunk max (once per 64 members)
        float cm = sc;
#pragma unroll
        for (int off = 32; off; off >>= 1) cm = fmaxf(cm, __shfl_xor(cm, off));
        const float nm = fmaxf(m, cm);
        const float alpha = __expf(m - nm);     // m=-inf first chunk -> 0
        const float p = (lane < nvalid) ? __expf(sc - nm) : 0.f;
        ps[wave][lane] = p;
        out *= alpha;
        lsum *= alpha;
        m = nm;
        asm volatile("" ::: "memory");          // keep ds_write before ds_reads
        // ---- PV: dim-parallel, coalesced V rows
        for (int j = 0; j < nvalid; ++j) {
            const int nj = __shfl(mi, j);       // members[ch0+j]
            const float pj = ps[wave][j];
            const float vv = (float)vbuf[(size_t)nj * E_DIM + h * DHD + lane];
            out = fmaf(pj, vv, out);
            lsum += pj;
        }
    }

    __shared__ float rm[4], rl[4], racc[4][64];
    racc[wave][lane] = out;
    if (lane == 0) { rm[wave] = m; rl[wave] = lsum; }
    __syncthreads();
    if (wave == 0) {
        float M = fmaxf(fmaxf(rm[0], rm[1]), fmaxf(rm[2], rm[3]));
        float o = 0.f, Lt = 0.f;
#pragma unroll
        for (int w = 0; w < 4; ++w) {
            float al = __expf(rm[w] - M);       // empty wave (m=-inf) -> 0
            o  += al * racc[w][lane];
            Lt += al * rl[w];
        }
        attn_out[c * E_DIM + h * DHD + lane] = o / Lt;
    }
}

// ---------------------------------------------------------------------------
// proto = attn_out @ Wo + bo; out (+)= coef_l * proto
// ---------------------------------------------------------------------------
__global__ __launch_bounds__(256)
void proto_accum(const float* __restrict__ attn_out, const float* __restrict__ Wo,
                 const float* __restrict__ bo, const float* __restrict__ lvlw,
                 const float* __restrict__ lvlt, int l, float* __restrict__ out) {
    const int c = blockIdx.x;
    const int tid = threadIdx.x;
    __shared__ float xrow[E_DIM];
    xrow[tid]       = attn_out[c * E_DIM + tid];
    xrow[tid + 256] = attn_out[c * E_DIM + tid + 256];
    __syncthreads();
    float a0 = 0.f, a1 = 0.f;
#pragma unroll 8
    for (int k = 0; k < E_DIM; ++k) {
        float cv = xrow[k];
        a0 = fmaf(cv, Wo[(size_t)k * E_DIM + tid], a0);
        a1 = fmaf(cv, Wo[(size_t)k * E_DIM + tid + 256], a1);
    }
    float w0 = lvlw[0], w1 = lvlw[1], w2 = lvlw[2];
    float mx = fmaxf(w0, fmaxf(w1, w2));
    float e0 = expf(w0 - mx), e1 = expf(w1 - mx), e2 = expf(w2 - mx);
    float ssum = e0 + e1 + e2;
    float lw = (l == 0 ? e0 : (l == 1 ? e1 : e2)) / ssum;
    float coef = lw / lvlt[l];
    float r0 = (a0 + bo[tid]) * coef;
    float r1 = (a1 + bo[tid + 256]) * coef;
    if (l == 0) {
        out[c * E_DIM + tid]       = r0;
        out[c * E_DIM + tid + 256] = r1;
    } else {
        out[c * E_DIM + tid]       += r0;
        out[c * E_DIM + tid + 256] += r1;
    }
}

// ---------------------------------------------------------------------------
extern "C" void kernel_launch(void* const* d_in, const int* in_sizes, int n_in,
                              void* d_out, int out_size, void* d_ws, size_t ws_size,
                              hipStream_t stream) {
    const float* X      = (const float*)d_in[0];
    const int*   labels = (const int*)  d_in[1];
    const float* W1     = (const float*)d_in[2];
    const float* b1     = (const float*)d_in[3];
    const float* gamma  = (const float*)d_in[4];
    const float* beta   = (const float*)d_in[5];
    const float* W2     = (const float*)d_in[6];
    const float* b2     = (const float*)d_in[7];
    const float* Wq     = (const float*)d_in[8];
    const float* bq     = (const float*)d_in[9];
    const float* Wk     = (const float*)d_in[10];
    const float* bk     = (const float*)d_in[11];
    const float* Wv     = (const float*)d_in[12];
    const float* bv     = (const float*)d_in[13];
    const float* Wo     = (const float*)d_in[14];
    const float* bo     = (const float*)d_in[15];
    const float* lvlw   = (const float*)d_in[16];
    const float* lvlt   = (const float*)d_in[17];
    float* out = (float*)d_out;

    // Workspace carve
    char* p = (char*)d_ws;
    const size_t bigh = (size_t)N_SUP * E_DIM * sizeof(_Float16);   // 64 MB
    _Float16* Xh   = (_Float16*)p; p += bigh;
    _Float16* bufP = (_Float16*)p; p += bigh;
    _Float16* bufF = (_Float16*)p; p += bigh;
    _Float16* bufK = (_Float16*)p; p += bigh;
    _Float16* bufV = (_Float16*)p; p += bigh;
    _Float16* W1t  = (_Float16*)p; p += (size_t)E_DIM * E_DIM * sizeof(_Float16);
    _Float16* W2t  = (_Float16*)p; p += (size_t)E_DIM * E_DIM * sizeof(_Float16);
    _Float16* Wkt  = (_Float16*)p; p += (size_t)E_DIM * E_DIM * sizeof(_Float16);
    _Float16* Wvt  = (_Float16*)p; p += (size_t)E_DIM * E_DIM * sizeof(_Float16);
    float* ctx  = (float*)p; p += C_CLS * E_DIM * sizeof(float);
    float* qb   = (float*)p; p += C_CLS * E_DIM * sizeof(float);
    float* ao   = (float*)p; p += C_CLS * E_DIM * sizeof(float);
    int* counts = (int*)p; p += 256;
    int* cursor = (int*)p; p += 256;
    int* offs   = (int*)p; p += 512;
    int* members= (int*)p; p += (size_t)N_SUP * sizeof(int);

    // Class membership preprocessing
    init_counts<<<1, 64, 0, stream>>>(counts, cursor);
    hist_kernel<<<(N_SUP + 255) / 256, 256, 0, stream>>>(labels, counts);
    offsets_kernel<<<1, 1, 0, stream>>>(counts, offs);
    scatter_kernel<<<(N_SUP + 255) / 256, 256, 0, stream>>>(labels, offs, cursor, members);

    // One-time conversions
    const int n4 = N_SUP * E_DIM / 4;
    conv32to16<<<n4 / 256, 256, 0, stream>>>(X, Xh, n4);
    transpose_w_f16<<<dim3(16, 16), 256, 0, stream>>>(Wk, Wkt);
    transpose_w_f16<<<dim3(16, 16), 256, 0, stream>>>(Wv, Wvt);

    const dim3 gGemm(N_SUP / 128, E_DIM / 128);
    for (int l = 0; l < L_LEV; ++l) {
        const float* W1l = W1 + (size_t)l * E_DIM * E_DIM;
        const float* W2l = W2 + (size_t)l * E_DIM * E_DIM;
        transpose_w_f16<<<dim3(16, 16), 256, 0, stream>>>(W1l, W1t);
        transpose_w_f16<<<dim3(16, 16), 256, 0, stream>>>(W2l, W2t);
        hgemm_bt<<<gGemm, 256, 0, stream>>>(Xh, W1t, b1 + l * E_DIM, bufP);
        ln_relu_h<<<N_SUP, 256, 0, stream>>>(bufP, gamma + l * E_DIM, beta + l * E_DIM);
        hgemm_bt<<<gGemm, 256, 0, stream>>>(bufP, W2t, b2 + l * E_DIM, bufF);
        hgemm_bt<<<gGemm, 256, 0, stream>>>(bufF, Wkt, bk, bufK);
        hgemm_bt<<<gGemm, 256, 0, stream>>>(bufF, Wvt, bv, bufV);
        ctx_mean<<<dim3(C_CLS, 8), 256, 0, stream>>>(bufF, members, offs, counts, ctx);
        row_gemm_q<<<C_CLS, 256, 0, stream>>>(ctx, Wq, bq, qb);
        attn_kernel<<<dim3(C_CLS, H_HEADS), 256, 0, stream>>>(qb, bufK, bufV, members, offs, ao);
        proto_accum<<<C_CLS, 256, 0, stream>>>(ao, Wo, bo, lvlw, lvlt, l, out);
    }
}

// Round 4
// 1904.712 us; speedup vs baseline: 3.5062x; 1.1809x over previous
//
#include <hip/hip_runtime.h>
#include <math.h>

// Problem constants (fixed by the reference)
#define N_SUP 65536
#define E_DIM 512
#define H_HEADS 8
#define C_CLS 64
#define DHD 64
#define L_LEV 3
#define LN_EPS 1e-5f

typedef _Float16 f16x8 __attribute__((ext_vector_type(8)));
typedef _Float16 f16x4 __attribute__((ext_vector_type(4)));
typedef float f32x4 __attribute__((ext_vector_type(4)));

// ---------------------------------------------------------------------------
// async global->LDS copy, 16B per lane. LDS dest must be wave-uniform;
// HW deposits at ldsbase + lane*16.
// ---------------------------------------------------------------------------
__device__ __forceinline__ void gload_lds16(const void* g, void* lds) {
    __builtin_amdgcn_global_load_lds((const __attribute__((address_space(1))) void*)g,
                                     (__attribute__((address_space(3))) void*)lds,
                                     16, 0, 0);
}

// ---------------------------------------------------------------------------
// fp16 GEMM: C[M x 512] = A[M x 512] @ B + bias, Bt = B^T [512 x 512].
// 128x128 tile, BK=32, 4 waves in 2x2, each wave 4x4 grid of 16x16x32 MFMA.
// ---------------------------------------------------------------------------
__global__ __launch_bounds__(256)
void hgemm_bt(const _Float16* __restrict__ A, const _Float16* __restrict__ Bt,
              const float* __restrict__ bias, _Float16* __restrict__ C) {
    __shared__ _Float16 As[128][32];
    __shared__ _Float16 Bs[128][32];
    const int tid = threadIdx.x;
    const int wave = tid >> 6, lane = tid & 63;
    const int row0 = blockIdx.x * 128, col0 = blockIdx.y * 128;
    const int wm = (wave & 1) * 64, wn = (wave >> 1) * 64;

    const int ci0 = wave * 128 + lane, ci1 = ci0 + 64;
    const int r0 = ci0 >> 2, gc0 = (ci0 & 3) ^ ((r0 >> 1) & 3);
    const int r1 = ci1 >> 2, gc1 = (ci1 & 3) ^ ((r1 >> 1) & 3);
    const _Float16* Ar0 = A + (size_t)(row0 + r0) * E_DIM + gc0 * 8;
    const _Float16* Ar1 = A + (size_t)(row0 + r1) * E_DIM + gc1 * 8;
    const _Float16* Br0 = Bt + (size_t)(col0 + r0) * E_DIM + gc0 * 8;
    const _Float16* Br1 = Bt + (size_t)(col0 + r1) * E_DIM + gc1 * 8;
    char* ldsA = (char*)&As[0][0] + wave * 2048;
    char* ldsB = (char*)&Bs[0][0] + wave * 2048;

    const int m = lane & 15, q = lane >> 4;
    const int koff = ((q ^ ((m >> 1) & 3))) * 8;

    f32x4 acc[4][4];
#pragma unroll
    for (int i = 0; i < 4; ++i)
#pragma unroll
        for (int j = 0; j < 4; ++j) acc[i][j] = (f32x4){0.f, 0.f, 0.f, 0.f};

    for (int k0 = 0; k0 < E_DIM; k0 += 32) {
        gload_lds16(Ar0 + k0, ldsA);
        gload_lds16(Ar1 + k0, ldsA + 1024);
        gload_lds16(Br0 + k0, ldsB);
        gload_lds16(Br1 + k0, ldsB + 1024);
        __syncthreads();

        f16x8 af[4], bf[4];
#pragma unroll
        for (int i = 0; i < 4; ++i)
            af[i] = *(const f16x8*)&As[wm + i * 16 + m][koff];
#pragma unroll
        for (int j = 0; j < 4; ++j)
            bf[j] = *(const f16x8*)&Bs[wn + j * 16 + m][koff];
#pragma unroll
        for (int i = 0; i < 4; ++i)
#pragma unroll
            for (int j = 0; j < 4; ++j)
                acc[i][j] = __builtin_amdgcn_mfma_f32_16x16x32_f16(af[i], bf[j], acc[i][j], 0, 0, 0);
        __syncthreads();
    }

    // C/D layout: col = lane&15, row = (lane>>4)*4 + reg
#pragma unroll
    for (int i = 0; i < 4; ++i) {
        const int rbase = row0 + wm + i * 16 + q * 4;
#pragma unroll
        for (int j = 0; j < 4; ++j) {
            const int col = col0 + wn + j * 16 + m;
            const float bv = bias[col];
#pragma unroll
            for (int r = 0; r < 4; ++r)
                C[(size_t)(rbase + r) * E_DIM + col] = (_Float16)(acc[i][j][r] + bv);
        }
    }
}

// ---------------------------------------------------------------------------
// fp32 -> fp16 elementwise (vectorized x4)
// ---------------------------------------------------------------------------
__global__ __launch_bounds__(256)
void conv32to16(const float* __restrict__ in, _Float16* __restrict__ out, int n4) {
    int i = blockIdx.x * 256 + threadIdx.x;
    if (i < n4) {
        f32x4 v = ((const f32x4*)in)[i];
        f16x4 o = {(_Float16)v[0], (_Float16)v[1], (_Float16)v[2], (_Float16)v[3]};
        ((f16x4*)out)[i] = o;
    }
}

// ---------------------------------------------------------------------------
// W[512x512] fp32 (k-major) -> Wt[512x512] fp16 (n-major), LDS-tiled transpose
// ---------------------------------------------------------------------------
__global__ __launch_bounds__(256)
void transpose_w_f16(const float* __restrict__ W, _Float16* __restrict__ Wt) {
    __shared__ float t[32][33];
    const int k0 = blockIdx.x * 32, n0 = blockIdx.y * 32;
    const int tx = threadIdx.x & 31, ty = threadIdx.x >> 5;
#pragma unroll
    for (int r = 0; r < 32; r += 8)
        t[ty + r][tx] = W[(size_t)(k0 + ty + r) * E_DIM + n0 + tx];
    __syncthreads();
#pragma unroll
    for (int r = 0; r < 32; r += 8)
        Wt[(size_t)(n0 + ty + r) * E_DIM + k0 + tx] = (_Float16)t[tx][ty + r];
}

// ---------------------------------------------------------------------------
// In-place LayerNorm (biased var) + ReLU on fp16 rows of 512, fp32 stats.
// ---------------------------------------------------------------------------
__global__ __launch_bounds__(256)
void ln_relu_h(_Float16* __restrict__ P, const float* __restrict__ gamma,
               const float* __restrict__ beta) {
    const int row = blockIdx.x;
    const int tid = threadIdx.x;
    const size_t base = (size_t)row * E_DIM;
    float x0 = (float)P[base + tid];
    float x1 = (float)P[base + tid + 256];
    float s = x0 + x1;
    float s2 = x0 * x0 + x1 * x1;
#pragma unroll
    for (int off = 32; off; off >>= 1) {
        s  += __shfl_xor(s, off);
        s2 += __shfl_xor(s2, off);
    }
    __shared__ float red[8];
    const int wave = tid >> 6, lane = tid & 63;
    if (lane == 0) { red[wave] = s; red[wave + 4] = s2; }
    __syncthreads();
    s  = red[0] + red[1] + red[2] + red[3];
    s2 = red[4] + red[5] + red[6] + red[7];
    const float mean = s * (1.f / E_DIM);
    const float var  = s2 * (1.f / E_DIM) - mean * mean;
    const float rstd = rsqrtf(var + LN_EPS);
    float y0 = (x0 - mean) * rstd * gamma[tid] + beta[tid];
    float y1 = (x1 - mean) * rstd * gamma[tid + 256] + beta[tid + 256];
    P[base + tid]       = (_Float16)fmaxf(y0, 0.f);
    P[base + tid + 256] = (_Float16)fmaxf(y1, 0.f);
}

// ---------------------------------------------------------------------------
// Class-membership preprocessing
// ---------------------------------------------------------------------------
__global__ void init_counts(int* counts, int* cursor) {
    int t = threadIdx.x;
    if (t < C_CLS) { counts[t] = 0; cursor[t] = 0; }
}

__global__ void hist_kernel(const int* __restrict__ labels, int* counts) {
    int i = blockIdx.x * blockDim.x + threadIdx.x;
    if (i < N_SUP) atomicAdd(&counts[labels[i]], 1);
}

__global__ void offsets_kernel(const int* __restrict__ counts, int* offsets) {
    if (threadIdx.x == 0) {
        int a = 0;
        for (int c = 0; c < C_CLS; ++c) { offsets[c] = a; a += counts[c]; }
        offsets[C_CLS] = a;
    }
}

__global__ void scatter_kernel(const int* __restrict__ labels,
                               const int* __restrict__ offsets,
                               int* cursor, int* members) {
    int i = blockIdx.x * blockDim.x + threadIdx.x;
    if (i < N_SUP) {
        int c = labels[i];
        int p = atomicAdd(&cursor[c], 1);
        members[offsets[c] + p] = i;
    }
}

__global__ __launch_bounds__(256)
void zero_f32(float* __restrict__ p, int n) {
    int i = blockIdx.x * 256 + threadIdx.x;
    if (i < n) p[i] = 0.f;
}

// ---------------------------------------------------------------------------
// ctx_sum[c,:] += sum over class members of feat(fp16)[n,:]  (fp32 atomics)
// Wave-per-member-row: lane l holds cols [l*8, l*8+8); one f16x8 = the wave
// covers the whole 512-col row in a single coalesced 1KB read. Grid
// (C, SPLITS); 32 waves/class, 2-deep independent unroll for MLP.
// ---------------------------------------------------------------------------
#define CTX_SPLITS 8
__global__ __launch_bounds__(256)
void ctx_sum_kernel(const _Float16* __restrict__ feat, const int* __restrict__ members,
                    const int* __restrict__ offsets, float* __restrict__ ctx_sum) {
    const int c = blockIdx.x, split = blockIdx.y;
    const int tid = threadIdx.x;
    const int wave = tid >> 6, lane = tid & 63;
    const int start = offsets[c], end = offsets[c + 1];
    const int wg = split * 4 + wave;              // 0..31 within class
    const int stride = 4 * CTX_SPLITS;            // 32 waves per class

    float acc[8];
#pragma unroll
    for (int e = 0; e < 8; ++e) acc[e] = 0.f;

    int i = start + wg;
    for (; i + stride < end; i += 2 * stride) {
        const int n0 = members[i];                // same addr across wave -> bcast
        const int n1 = members[i + stride];
        f16x8 r0 = *(const f16x8*)(feat + (size_t)n0 * E_DIM + lane * 8);
        f16x8 r1 = *(const f16x8*)(feat + (size_t)n1 * E_DIM + lane * 8);
#pragma unroll
        for (int e = 0; e < 8; ++e) acc[e] += (float)r0[e] + (float)r1[e];
    }
    if (i < end) {
        const int n0 = members[i];
        f16x8 r0 = *(const f16x8*)(feat + (size_t)n0 * E_DIM + lane * 8);
#pragma unroll
        for (int e = 0; e < 8; ++e) acc[e] += (float)r0[e];
    }

    // Cross-wave reduce in LDS, then one atomicAdd per column per block.
    __shared__ float red[4][64][8];
#pragma unroll
    for (int e = 0; e < 8; ++e) red[wave][lane][e] = acc[e];
    __syncthreads();
    // 256 threads cover 512 cols: each thread reduces 2 cols over 4 waves.
#pragma unroll
    for (int t = 0; t < 2; ++t) {
        const int col = tid * 2 + t;              // 0..511
        const int ln = col >> 3, e = col & 7;
        float s = red[0][ln][e] + red[1][ln][e] + red[2][ln][e] + red[3][ln][e];
        atomicAdd(&ctx_sum[c * E_DIM + col], s);
    }
}

// ---------------------------------------------------------------------------
// q[c,:] = (ctx_sum[c,:]/count) @ Wq + bq   (fp32, tiny)
// ---------------------------------------------------------------------------
__global__ __launch_bounds__(256)
void row_gemm_q(const float* __restrict__ ctx_sum, const int* __restrict__ counts,
                const float* __restrict__ Wq, const float* __restrict__ bq,
                float* __restrict__ q) {
    const int c = blockIdx.x;
    const int tid = threadIdx.x;
    const float inv = 1.f / (float)counts[c];
    __shared__ float xrow[E_DIM];
    xrow[tid]       = ctx_sum[c * E_DIM + tid] * inv;
    xrow[tid + 256] = ctx_sum[c * E_DIM + tid + 256] * inv;
    __syncthreads();
    float a0 = 0.f, a1 = 0.f;
#pragma unroll 8
    for (int k = 0; k < E_DIM; ++k) {
        float cv = xrow[k];
        a0 = fmaf(cv, Wq[(size_t)k * E_DIM + tid], a0);
        a1 = fmaf(cv, Wq[(size_t)k * E_DIM + tid + 256], a1);
    }
    q[c * E_DIM + tid]       = a0 + bq[tid];
    q[c * E_DIM + tid + 256] = a1 + bq[tid + 256];
}

// ---------------------------------------------------------------------------
// Segment attention, member-per-lane chunked flash (see R3 notes).
// ---------------------------------------------------------------------------
__global__ __launch_bounds__(256)
void attn_kernel(const float* __restrict__ q, const _Float16* __restrict__ kbuf,
                 const _Float16* __restrict__ vbuf, const int* __restrict__ members,
                 const int* __restrict__ offsets, float* __restrict__ attn_out) {
    const int c = blockIdx.x, h = blockIdx.y;
    const int tid = threadIdx.x;
    const int wave = tid >> 6, lane = tid & 63;
    const int start = offsets[c], end = offsets[c + 1];

    const float* qrow = q + c * E_DIM + h * DHD;
    float qv[64];
#pragma unroll
    for (int d = 0; d < 64; ++d) qv[d] = qrow[d];

    __shared__ float ps[4][64];
    float m = -INFINITY, lsum = 0.f, out = 0.f;   // lane owns output dim `lane`

    for (int ch0 = start + wave * 64; ch0 < end; ch0 += 256) {
        const int nvalid = min(64, end - ch0);
        const int idx = ch0 + lane;
        const int mi = members[idx < end ? idx : end - 1];
        const _Float16* krow = kbuf + (size_t)mi * E_DIM + h * DHD;
        float dot = 0.f;
#pragma unroll
        for (int j = 0; j < 8; ++j) {
            f16x8 kr = *(const f16x8*)(krow + j * 8);
#pragma unroll
            for (int e = 0; e < 8; ++e)
                dot = fmaf((float)kr[e], qv[j * 8 + e], dot);
        }
        float sc = (lane < nvalid) ? dot * 0.125f : -INFINITY;
        float cm = sc;
#pragma unroll
        for (int off = 32; off; off >>= 1) cm = fmaxf(cm, __shfl_xor(cm, off));
        const float nm = fmaxf(m, cm);
        const float alpha = __expf(m - nm);
        const float p = (lane < nvalid) ? __expf(sc - nm) : 0.f;
        ps[wave][lane] = p;
        out *= alpha;
        lsum *= alpha;
        m = nm;
        asm volatile("" ::: "memory");
        for (int j = 0; j < nvalid; ++j) {
            const int nj = __shfl(mi, j);
            const float pj = ps[wave][j];
            const float vv = (float)vbuf[(size_t)nj * E_DIM + h * DHD + lane];
            out = fmaf(pj, vv, out);
            lsum += pj;
        }
    }

    __shared__ float rm[4], rl[4], racc[4][64];
    racc[wave][lane] = out;
    if (lane == 0) { rm[wave] = m; rl[wave] = lsum; }
    __syncthreads();
    if (wave == 0) {
        float M = fmaxf(fmaxf(rm[0], rm[1]), fmaxf(rm[2], rm[3]));
        float o = 0.f, Lt = 0.f;
#pragma unroll
        for (int w = 0; w < 4; ++w) {
            float al = __expf(rm[w] - M);
            o  += al * racc[w][lane];
            Lt += al * rl[w];
        }
        attn_out[c * E_DIM + h * DHD + lane] = o / Lt;
    }
}

// ---------------------------------------------------------------------------
// proto = attn_out @ Wo + bo; out (+)= coef_l * proto
// ---------------------------------------------------------------------------
__global__ __launch_bounds__(256)
void proto_accum(const float* __restrict__ attn_out, const float* __restrict__ Wo,
                 const float* __restrict__ bo, const float* __restrict__ lvlw,
                 const float* __restrict__ lvlt, int l, float* __restrict__ out) {
    const int c = blockIdx.x;
    const int tid = threadIdx.x;
    __shared__ float xrow[E_DIM];
    xrow[tid]       = attn_out[c * E_DIM + tid];
    xrow[tid + 256] = attn_out[c * E_DIM + tid + 256];
    __syncthreads();
    float a0 = 0.f, a1 = 0.f;
#pragma unroll 8
    for (int k = 0; k < E_DIM; ++k) {
        float cv = xrow[k];
        a0 = fmaf(cv, Wo[(size_t)k * E_DIM + tid], a0);
        a1 = fmaf(cv, Wo[(size_t)k * E_DIM + tid + 256], a1);
    }
    float w0 = lvlw[0], w1 = lvlw[1], w2 = lvlw[2];
    float mx = fmaxf(w0, fmaxf(w1, w2));
    float e0 = expf(w0 - mx), e1 = expf(w1 - mx), e2 = expf(w2 - mx);
    float ssum = e0 + e1 + e2;
    float lw = (l == 0 ? e0 : (l == 1 ? e1 : e2)) / ssum;
    float coef = lw / lvlt[l];
    float r0 = (a0 + bo[tid]) * coef;
    float r1 = (a1 + bo[tid + 256]) * coef;
    if (l == 0) {
        out[c * E_DIM + tid]       = r0;
        out[c * E_DIM + tid + 256] = r1;
    } else {
        out[c * E_DIM + tid]       += r0;
        out[c * E_DIM + tid + 256] += r1;
    }
}

// ---------------------------------------------------------------------------
extern "C" void kernel_launch(void* const* d_in, const int* in_sizes, int n_in,
                              void* d_out, int out_size, void* d_ws, size_t ws_size,
                              hipStream_t stream) {
    const float* X      = (const float*)d_in[0];
    const int*   labels = (const int*)  d_in[1];
    const float* W1     = (const float*)d_in[2];
    const float* b1     = (const float*)d_in[3];
    const float* gamma  = (const float*)d_in[4];
    const float* beta   = (const float*)d_in[5];
    const float* W2     = (const float*)d_in[6];
    const float* b2     = (const float*)d_in[7];
    const float* Wq     = (const float*)d_in[8];
    const float* bq     = (const float*)d_in[9];
    const float* Wk     = (const float*)d_in[10];
    const float* bk     = (const float*)d_in[11];
    const float* Wv     = (const float*)d_in[12];
    const float* bv     = (const float*)d_in[13];
    const float* Wo     = (const float*)d_in[14];
    const float* bo     = (const float*)d_in[15];
    const float* lvlw   = (const float*)d_in[16];
    const float* lvlt   = (const float*)d_in[17];
    float* out = (float*)d_out;

    // Workspace carve
    char* p = (char*)d_ws;
    const size_t bigh = (size_t)N_SUP * E_DIM * sizeof(_Float16);   // 64 MB
    _Float16* Xh   = (_Float16*)p; p += bigh;
    _Float16* bufP = (_Float16*)p; p += bigh;
    _Float16* bufF = (_Float16*)p; p += bigh;
    _Float16* bufK = (_Float16*)p; p += bigh;
    _Float16* bufV = (_Float16*)p; p += bigh;
    _Float16* W1t  = (_Float16*)p; p += (size_t)E_DIM * E_DIM * sizeof(_Float16);
    _Float16* W2t  = (_Float16*)p; p += (size_t)E_DIM * E_DIM * sizeof(_Float16);
    _Float16* Wkt  = (_Float16*)p; p += (size_t)E_DIM * E_DIM * sizeof(_Float16);
    _Float16* Wvt  = (_Float16*)p; p += (size_t)E_DIM * E_DIM * sizeof(_Float16);
    float* ctxs = (float*)p; p += C_CLS * E_DIM * sizeof(float);
    float* qb   = (float*)p; p += C_CLS * E_DIM * sizeof(float);
    float* ao   = (float*)p; p += C_CLS * E_DIM * sizeof(float);
    int* counts = (int*)p; p += 256;
    int* cursor = (int*)p; p += 256;
    int* offs   = (int*)p; p += 512;
    int* members= (int*)p; p += (size_t)N_SUP * sizeof(int);

    // Class membership preprocessing
    init_counts<<<1, 64, 0, stream>>>(counts, cursor);
    hist_kernel<<<(N_SUP + 255) / 256, 256, 0, stream>>>(labels, counts);
    offsets_kernel<<<1, 1, 0, stream>>>(counts, offs);
    scatter_kernel<<<(N_SUP + 255) / 256, 256, 0, stream>>>(labels, offs, cursor, members);

    // One-time conversions
    const int n4 = N_SUP * E_DIM / 4;
    conv32to16<<<n4 / 256, 256, 0, stream>>>(X, Xh, n4);
    transpose_w_f16<<<dim3(16, 16), 256, 0, stream>>>(Wk, Wkt);
    transpose_w_f16<<<dim3(16, 16), 256, 0, stream>>>(Wv, Wvt);

    const dim3 gGemm(N_SUP / 128, E_DIM / 128);
    for (int l = 0; l < L_LEV; ++l) {
        const float* W1l = W1 + (size_t)l * E_DIM * E_DIM;
        const float* W2l = W2 + (size_t)l * E_DIM * E_DIM;
        transpose_w_f16<<<dim3(16, 16), 256, 0, stream>>>(W1l, W1t);
        transpose_w_f16<<<dim3(16, 16), 256, 0, stream>>>(W2l, W2t);
        hgemm_bt<<<gGemm, 256, 0, stream>>>(Xh, W1t, b1 + l * E_DIM, bufP);
        ln_relu_h<<<N_SUP, 256, 0, stream>>>(bufP, gamma + l * E_DIM, beta + l * E_DIM);
        hgemm_bt<<<gGemm, 256, 0, stream>>>(bufP, W2t, b2 + l * E_DIM, bufF);
        hgemm_bt<<<gGemm, 256, 0, stream>>>(bufF, Wkt, bk, bufK);
        hgemm_bt<<<gGemm, 256, 0, stream>>>(bufF, Wvt, bv, bufV);
        zero_f32<<<(C_CLS * E_DIM) / 256, 256, 0, stream>>>(ctxs, C_CLS * E_DIM);
        ctx_sum_kernel<<<dim3(C_CLS, CTX_SPLITS), 256, 0, stream>>>(bufF, members, offs, ctxs);
        row_gemm_q<<<C_CLS, 256, 0, stream>>>(ctxs, counts, Wq, bq, qb);
        attn_kernel<<<dim3(C_CLS, H_HEADS), 256, 0, stream>>>(qb, bufK, bufV, members, offs, ao);
        proto_accum<<<C_CLS, 256, 0, stream>>>(ao, Wo, bo, lvlw, lvlt, l, out);
    }
}

// Round 5
// 1680.805 us; speedup vs baseline: 3.9732x; 1.1332x over previous
//
#include <hip/hip_runtime.h>
#include <math.h>

// Problem constants (fixed by the reference)
#define N_SUP 65536
#define E_DIM 512
#define H_HEADS 8
#define C_CLS 64
#define DHD 64
#define L_LEV 3
#define LN_EPS 1e-5f
#define ATTN_SPLITS 4

typedef _Float16 f16x8 __attribute__((ext_vector_type(8)));
typedef _Float16 f16x4 __attribute__((ext_vector_type(4)));
typedef float f32x4 __attribute__((ext_vector_type(4)));

// ---------------------------------------------------------------------------
// async global->LDS copy, 16B per lane. LDS dest must be wave-uniform;
// HW deposits at ldsbase + lane*16.
// ---------------------------------------------------------------------------
__device__ __forceinline__ void gload_lds16(const void* g, void* lds) {
    __builtin_amdgcn_global_load_lds((const __attribute__((address_space(1))) void*)g,
                                     (__attribute__((address_space(3))) void*)lds,
                                     16, 0, 0);
}

// ---------------------------------------------------------------------------
// fp16 GEMM: C[M x 512] = A[M x 512] @ B + bias, Bt = B^T [512 x 512].
// 128x128 tile, BK=32, 4 waves in 2x2, each wave 4x4 grid of 16x16x32 MFMA.
// ---------------------------------------------------------------------------
__global__ __launch_bounds__(256)
void hgemm_bt(const _Float16* __restrict__ A, const _Float16* __restrict__ Bt,
              const float* __restrict__ bias, _Float16* __restrict__ C) {
    __shared__ _Float16 As[128][32];
    __shared__ _Float16 Bs[128][32];
    const int tid = threadIdx.x;
    const int wave = tid >> 6, lane = tid & 63;
    const int row0 = blockIdx.x * 128, col0 = blockIdx.y * 128;
    const int wm = (wave & 1) * 64, wn = (wave >> 1) * 64;

    const int ci0 = wave * 128 + lane, ci1 = ci0 + 64;
    const int r0 = ci0 >> 2, gc0 = (ci0 & 3) ^ ((r0 >> 1) & 3);
    const int r1 = ci1 >> 2, gc1 = (ci1 & 3) ^ ((r1 >> 1) & 3);
    const _Float16* Ar0 = A + (size_t)(row0 + r0) * E_DIM + gc0 * 8;
    const _Float16* Ar1 = A + (size_t)(row0 + r1) * E_DIM + gc1 * 8;
    const _Float16* Br0 = Bt + (size_t)(col0 + r0) * E_DIM + gc0 * 8;
    const _Float16* Br1 = Bt + (size_t)(col0 + r1) * E_DIM + gc1 * 8;
    char* ldsA = (char*)&As[0][0] + wave * 2048;
    char* ldsB = (char*)&Bs[0][0] + wave * 2048;

    const int m = lane & 15, q = lane >> 4;
    const int koff = ((q ^ ((m >> 1) & 3))) * 8;

    f32x4 acc[4][4];
#pragma unroll
    for (int i = 0; i < 4; ++i)
#pragma unroll
        for (int j = 0; j < 4; ++j) acc[i][j] = (f32x4){0.f, 0.f, 0.f, 0.f};

    for (int k0 = 0; k0 < E_DIM; k0 += 32) {
        gload_lds16(Ar0 + k0, ldsA);
        gload_lds16(Ar1 + k0, ldsA + 1024);
        gload_lds16(Br0 + k0, ldsB);
        gload_lds16(Br1 + k0, ldsB + 1024);
        __syncthreads();

        f16x8 af[4], bf[4];
#pragma unroll
        for (int i = 0; i < 4; ++i)
            af[i] = *(const f16x8*)&As[wm + i * 16 + m][koff];
#pragma unroll
        for (int j = 0; j < 4; ++j)
            bf[j] = *(const f16x8*)&Bs[wn + j * 16 + m][koff];
#pragma unroll
        for (int i = 0; i < 4; ++i)
#pragma unroll
            for (int j = 0; j < 4; ++j)
                acc[i][j] = __builtin_amdgcn_mfma_f32_16x16x32_f16(af[i], bf[j], acc[i][j], 0, 0, 0);
        __syncthreads();
    }

    // C/D layout: col = lane&15, row = (lane>>4)*4 + reg
#pragma unroll
    for (int i = 0; i < 4; ++i) {
        const int rbase = row0 + wm + i * 16 + q * 4;
#pragma unroll
        for (int j = 0; j < 4; ++j) {
            const int col = col0 + wn + j * 16 + m;
            const float bv = bias[col];
#pragma unroll
            for (int r = 0; r < 4; ++r)
                C[(size_t)(rbase + r) * E_DIM + col] = (_Float16)(acc[i][j][r] + bv);
        }
    }
}

// ---------------------------------------------------------------------------
// fp32 -> fp16 elementwise (vectorized x4)
// ---------------------------------------------------------------------------
__global__ __launch_bounds__(256)
void conv32to16(const float* __restrict__ in, _Float16* __restrict__ out, int n4) {
    int i = blockIdx.x * 256 + threadIdx.x;
    if (i < n4) {
        f32x4 v = ((const f32x4*)in)[i];
        f16x4 o = {(_Float16)v[0], (_Float16)v[1], (_Float16)v[2], (_Float16)v[3]};
        ((f16x4*)out)[i] = o;
    }
}

// ---------------------------------------------------------------------------
// W[512x512] fp32 (k-major) -> Wt[512x512] fp16 (n-major), LDS-tiled transpose
// ---------------------------------------------------------------------------
__global__ __launch_bounds__(256)
void transpose_w_f16(const float* __restrict__ W, _Float16* __restrict__ Wt) {
    __shared__ float t[32][33];
    const int k0 = blockIdx.x * 32, n0 = blockIdx.y * 32;
    const int tx = threadIdx.x & 31, ty = threadIdx.x >> 5;
#pragma unroll
    for (int r = 0; r < 32; r += 8)
        t[ty + r][tx] = W[(size_t)(k0 + ty + r) * E_DIM + n0 + tx];
    __syncthreads();
#pragma unroll
    for (int r = 0; r < 32; r += 8)
        Wt[(size_t)(n0 + ty + r) * E_DIM + k0 + tx] = (_Float16)t[tx][ty + r];
}

// ---------------------------------------------------------------------------
// In-place LayerNorm (biased var) + ReLU on fp16 rows of 512, fp32 stats.
// ---------------------------------------------------------------------------
__global__ __launch_bounds__(256)
void ln_relu_h(_Float16* __restrict__ P, const float* __restrict__ gamma,
               const float* __restrict__ beta) {
    const int row = blockIdx.x;
    const int tid = threadIdx.x;
    const size_t base = (size_t)row * E_DIM;
    float x0 = (float)P[base + tid];
    float x1 = (float)P[base + tid + 256];
    float s = x0 + x1;
    float s2 = x0 * x0 + x1 * x1;
#pragma unroll
    for (int off = 32; off; off >>= 1) {
        s  += __shfl_xor(s, off);
        s2 += __shfl_xor(s2, off);
    }
    __shared__ float red[8];
    const int wave = tid >> 6, lane = tid & 63;
    if (lane == 0) { red[wave] = s; red[wave + 4] = s2; }
    __syncthreads();
    s  = red[0] + red[1] + red[2] + red[3];
    s2 = red[4] + red[5] + red[6] + red[7];
    const float mean = s * (1.f / E_DIM);
    const float var  = s2 * (1.f / E_DIM) - mean * mean;
    const float rstd = rsqrtf(var + LN_EPS);
    float y0 = (x0 - mean) * rstd * gamma[tid] + beta[tid];
    float y1 = (x1 - mean) * rstd * gamma[tid + 256] + beta[tid + 256];
    P[base + tid]       = (_Float16)fmaxf(y0, 0.f);
    P[base + tid + 256] = (_Float16)fmaxf(y1, 0.f);
}

// ---------------------------------------------------------------------------
// Class-membership preprocessing
// ---------------------------------------------------------------------------
__global__ void init_counts(int* counts, int* cursor) {
    int t = threadIdx.x;
    if (t < C_CLS) { counts[t] = 0; cursor[t] = 0; }
}

__global__ void hist_kernel(const int* __restrict__ labels, int* counts) {
    int i = blockIdx.x * blockDim.x + threadIdx.x;
    if (i < N_SUP) atomicAdd(&counts[labels[i]], 1);
}

__global__ void offsets_kernel(const int* __restrict__ counts, int* offsets) {
    if (threadIdx.x == 0) {
        int a = 0;
        for (int c = 0; c < C_CLS; ++c) { offsets[c] = a; a += counts[c]; }
        offsets[C_CLS] = a;
    }
}

__global__ void scatter_kernel(const int* __restrict__ labels,
                               const int* __restrict__ offsets,
                               int* cursor, int* members) {
    int i = blockIdx.x * blockDim.x + threadIdx.x;
    if (i < N_SUP) {
        int c = labels[i];
        int p = atomicAdd(&cursor[c], 1);
        members[offsets[c] + p] = i;
    }
}

__global__ __launch_bounds__(256)
void zero_f32(float* __restrict__ p, int n) {
    int i = blockIdx.x * 256 + threadIdx.x;
    if (i < n) p[i] = 0.f;
}

// ---------------------------------------------------------------------------
// ctx_sum[c,:] += sum over class members of feat(fp16)[n,:]  (fp32 atomics)
// ---------------------------------------------------------------------------
#define CTX_SPLITS 8
__global__ __launch_bounds__(256)
void ctx_sum_kernel(const _Float16* __restrict__ feat, const int* __restrict__ members,
                    const int* __restrict__ offsets, float* __restrict__ ctx_sum) {
    const int c = blockIdx.x, split = blockIdx.y;
    const int tid = threadIdx.x;
    const int wave = tid >> 6, lane = tid & 63;
    const int start = offsets[c], end = offsets[c + 1];
    const int wg = split * 4 + wave;
    const int stride = 4 * CTX_SPLITS;

    float acc[8];
#pragma unroll
    for (int e = 0; e < 8; ++e) acc[e] = 0.f;

    int i = start + wg;
    for (; i + stride < end; i += 2 * stride) {
        const int n0 = members[i];
        const int n1 = members[i + stride];
        f16x8 r0 = *(const f16x8*)(feat + (size_t)n0 * E_DIM + lane * 8);
        f16x8 r1 = *(const f16x8*)(feat + (size_t)n1 * E_DIM + lane * 8);
#pragma unroll
        for (int e = 0; e < 8; ++e) acc[e] += (float)r0[e] + (float)r1[e];
    }
    if (i < end) {
        const int n0 = members[i];
        f16x8 r0 = *(const f16x8*)(feat + (size_t)n0 * E_DIM + lane * 8);
#pragma unroll
        for (int e = 0; e < 8; ++e) acc[e] += (float)r0[e];
    }

    __shared__ float red[4][64][8];
#pragma unroll
    for (int e = 0; e < 8; ++e) red[wave][lane][e] = acc[e];
    __syncthreads();
#pragma unroll
    for (int t = 0; t < 2; ++t) {
        const int col = tid * 2 + t;
        const int ln = col >> 3, e = col & 7;
        float s = red[0][ln][e] + red[1][ln][e] + red[2][ln][e] + red[3][ln][e];
        atomicAdd(&ctx_sum[c * E_DIM + col], s);
    }
}

// ---------------------------------------------------------------------------
// q[c,:] = (ctx_sum[c,:]/count) @ Wq + bq   (fp32, tiny)
// ---------------------------------------------------------------------------
__global__ __launch_bounds__(256)
void row_gemm_q(const float* __restrict__ ctx_sum, const int* __restrict__ counts,
                const float* __restrict__ Wq, const float* __restrict__ bq,
                float* __restrict__ q) {
    const int c = blockIdx.x;
    const int tid = threadIdx.x;
    const float inv = 1.f / (float)counts[c];
    __shared__ float xrow[E_DIM];
    xrow[tid]       = ctx_sum[c * E_DIM + tid] * inv;
    xrow[tid + 256] = ctx_sum[c * E_DIM + tid + 256] * inv;
    __syncthreads();
    float a0 = 0.f, a1 = 0.f;
#pragma unroll 8
    for (int k = 0; k < E_DIM; ++k) {
        float cv = xrow[k];
        a0 = fmaf(cv, Wq[(size_t)k * E_DIM + tid], a0);
        a1 = fmaf(cv, Wq[(size_t)k * E_DIM + tid + 256], a1);
    }
    q[c * E_DIM + tid]       = a0 + bq[tid];
    q[c * E_DIM + tid + 256] = a1 + bq[tid + 256];
}

// ---------------------------------------------------------------------------
// Segment attention, phase 1: partials per (class, head, split).
// Grid (C, H, ATTN_SPLITS), 4 waves/block -> 16 wave-streams per (c,h).
// Wave w of split s owns chunks starting at start + (s*4+w)*64, stride 1024.
// PV loop is fixed-64-trip, unroll 16, p=0 on invalid lanes.
// Partials: pm/pl [C*H*S], po [C*H*S][64].
// ---------------------------------------------------------------------------
__global__ __launch_bounds__(256)
void attn_partial(const float* __restrict__ q, const _Float16* __restrict__ kbuf,
                  const _Float16* __restrict__ vbuf, const int* __restrict__ members,
                  const int* __restrict__ offsets, float* __restrict__ pm,
                  float* __restrict__ pl, float* __restrict__ po) {
    const int c = blockIdx.x, h = blockIdx.y, s = blockIdx.z;
    const int tid = threadIdx.x;
    const int wave = tid >> 6, lane = tid & 63;
    const int start = offsets[c], end = offsets[c + 1];
    const int g = s * 4 + wave;                 // 0..15

    const float* qrow = q + c * E_DIM + h * DHD;
    float qv[64];
#pragma unroll
    for (int d = 0; d < 64; ++d) qv[d] = qrow[d];

    __shared__ float ps[4][64];
    float m = -INFINITY, lsum = 0.f, out = 0.f; // lane owns output dim `lane`

    for (int ch0 = start + g * 64; ch0 < end; ch0 += 16 * 64) {
        const int nvalid = min(64, end - ch0);
        const int idx = ch0 + lane;
        const int mi = members[idx < end ? idx : end - 1];
        const _Float16* krow = kbuf + (size_t)mi * E_DIM + h * DHD;
        float dot = 0.f;
#pragma unroll
        for (int j = 0; j < 8; ++j) {
            f16x8 kr = *(const f16x8*)(krow + j * 8);
#pragma unroll
            for (int e = 0; e < 8; ++e)
                dot = fmaf((float)kr[e], qv[j * 8 + e], dot);
        }
        float sc = (lane < nvalid) ? dot * 0.125f : -INFINITY;
        float cm = sc;
#pragma unroll
        for (int off = 32; off; off >>= 1) cm = fmaxf(cm, __shfl_xor(cm, off));
        const float nm = fmaxf(m, cm);
        const float alpha = __expf(m - nm);
        const float p = (lane < nvalid) ? __expf(sc - nm) : 0.f;
        ps[wave][lane] = p;
        out *= alpha;
        lsum *= alpha;
        m = nm;
        asm volatile("" ::: "memory");
        // fixed-trip PV, 16 loads in flight
#pragma unroll 16
        for (int j = 0; j < 64; ++j) {
            const int nj = __shfl(mi, j);
            const float pj = ps[wave][j];
            const float vv = (float)vbuf[(size_t)nj * E_DIM + h * DHD + lane];
            out = fmaf(pj, vv, out);
            lsum += pj;
        }
    }

    __shared__ float rm[4], rl[4], racc[4][64];
    racc[wave][lane] = out;
    if (lane == 0) { rm[wave] = m; rl[wave] = lsum; }
    __syncthreads();
    if (wave == 0) {
        float M = fmaxf(fmaxf(rm[0], rm[1]), fmaxf(rm[2], rm[3]));
        float o = 0.f, Lt = 0.f;
#pragma unroll
        for (int w = 0; w < 4; ++w) {
            float al = __expf(rm[w] - M);   // all-empty wave -> 0
            o  += al * racc[w][lane];
            Lt += al * rl[w];
        }
        const int pidx = (c * H_HEADS + h) * ATTN_SPLITS + s;
        po[pidx * 64 + lane] = o;
        if (lane == 0) { pm[pidx] = M; pl[pidx] = Lt; }
    }
}

// ---------------------------------------------------------------------------
// Segment attention, phase 2: merge ATTN_SPLITS partials per (c,h).
// Grid C*H blocks of 64 threads.
// ---------------------------------------------------------------------------
__global__ __launch_bounds__(64)
void attn_combine(const float* __restrict__ pm, const float* __restrict__ pl,
                  const float* __restrict__ po, float* __restrict__ attn_out) {
    const int ch = blockIdx.x;          // c*H + h
    const int lane = threadIdx.x;
    float M = -INFINITY;
#pragma unroll
    for (int s = 0; s < ATTN_SPLITS; ++s) M = fmaxf(M, pm[ch * ATTN_SPLITS + s]);
    float o = 0.f, Lt = 0.f;
#pragma unroll
    for (int s = 0; s < ATTN_SPLITS; ++s) {
        const int pidx = ch * ATTN_SPLITS + s;
        float al = __expf(pm[pidx] - M);    // empty split (m=-inf) -> 0
        o  += al * po[pidx * 64 + lane];
        Lt += al * pl[pidx];
    }
    attn_out[ch * DHD + lane] = o / Lt;
}

// ---------------------------------------------------------------------------
// proto = attn_out @ Wo + bo; out (+)= coef_l * proto
// ---------------------------------------------------------------------------
__global__ __launch_bounds__(256)
void proto_accum(const float* __restrict__ attn_out, const float* __restrict__ Wo,
                 const float* __restrict__ bo, const float* __restrict__ lvlw,
                 const float* __restrict__ lvlt, int l, float* __restrict__ out) {
    const int c = blockIdx.x;
    const int tid = threadIdx.x;
    __shared__ float xrow[E_DIM];
    xrow[tid]       = attn_out[c * E_DIM + tid];
    xrow[tid + 256] = attn_out[c * E_DIM + tid + 256];
    __syncthreads();
    float a0 = 0.f, a1 = 0.f;
#pragma unroll 8
    for (int k = 0; k < E_DIM; ++k) {
        float cv = xrow[k];
        a0 = fmaf(cv, Wo[(size_t)k * E_DIM + tid], a0);
        a1 = fmaf(cv, Wo[(size_t)k * E_DIM + tid + 256], a1);
    }
    float w0 = lvlw[0], w1 = lvlw[1], w2 = lvlw[2];
    float mx = fmaxf(w0, fmaxf(w1, w2));
    float e0 = expf(w0 - mx), e1 = expf(w1 - mx), e2 = expf(w2 - mx);
    float ssum = e0 + e1 + e2;
    float lw = (l == 0 ? e0 : (l == 1 ? e1 : e2)) / ssum;
    float coef = lw / lvlt[l];
    float r0 = (a0 + bo[tid]) * coef;
    float r1 = (a1 + bo[tid + 256]) * coef;
    if (l == 0) {
        out[c * E_DIM + tid]       = r0;
        out[c * E_DIM + tid + 256] = r1;
    } else {
        out[c * E_DIM + tid]       += r0;
        out[c * E_DIM + tid + 256] += r1;
    }
}

// ---------------------------------------------------------------------------
extern "C" void kernel_launch(void* const* d_in, const int* in_sizes, int n_in,
                              void* d_out, int out_size, void* d_ws, size_t ws_size,
                              hipStream_t stream) {
    const float* X      = (const float*)d_in[0];
    const int*   labels = (const int*)  d_in[1];
    const float* W1     = (const float*)d_in[2];
    const float* b1     = (const float*)d_in[3];
    const float* gamma  = (const float*)d_in[4];
    const float* beta   = (const float*)d_in[5];
    const float* W2     = (const float*)d_in[6];
    const float* b2     = (const float*)d_in[7];
    const float* Wq     = (const float*)d_in[8];
    const float* bq     = (const float*)d_in[9];
    const float* Wk     = (const float*)d_in[10];
    const float* bk     = (const float*)d_in[11];
    const float* Wv     = (const float*)d_in[12];
    const float* bv     = (const float*)d_in[13];
    const float* Wo     = (const float*)d_in[14];
    const float* bo     = (const float*)d_in[15];
    const float* lvlw   = (const float*)d_in[16];
    const float* lvlt   = (const float*)d_in[17];
    float* out = (float*)d_out;

    // Workspace carve
    char* p = (char*)d_ws;
    const size_t bigh = (size_t)N_SUP * E_DIM * sizeof(_Float16);   // 64 MB
    _Float16* Xh   = (_Float16*)p; p += bigh;
    _Float16* bufP = (_Float16*)p; p += bigh;
    _Float16* bufF = (_Float16*)p; p += bigh;
    _Float16* bufK = (_Float16*)p; p += bigh;
    _Float16* bufV = (_Float16*)p; p += bigh;
    _Float16* W1t  = (_Float16*)p; p += (size_t)E_DIM * E_DIM * sizeof(_Float16);
    _Float16* W2t  = (_Float16*)p; p += (size_t)E_DIM * E_DIM * sizeof(_Float16);
    _Float16* Wkt  = (_Float16*)p; p += (size_t)E_DIM * E_DIM * sizeof(_Float16);
    _Float16* Wvt  = (_Float16*)p; p += (size_t)E_DIM * E_DIM * sizeof(_Float16);
    float* ctxs = (float*)p; p += C_CLS * E_DIM * sizeof(float);
    float* qb   = (float*)p; p += C_CLS * E_DIM * sizeof(float);
    float* ao   = (float*)p; p += C_CLS * E_DIM * sizeof(float);
    float* pm   = (float*)p; p += C_CLS * H_HEADS * ATTN_SPLITS * sizeof(float);
    float* pl   = (float*)p; p += C_CLS * H_HEADS * ATTN_SPLITS * sizeof(float);
    float* po   = (float*)p; p += C_CLS * H_HEADS * ATTN_SPLITS * 64 * sizeof(float);
    int* counts = (int*)p; p += 256;
    int* cursor = (int*)p; p += 256;
    int* offs   = (int*)p; p += 512;
    int* members= (int*)p; p += (size_t)N_SUP * sizeof(int);

    // Class membership preprocessing
    init_counts<<<1, 64, 0, stream>>>(counts, cursor);
    hist_kernel<<<(N_SUP + 255) / 256, 256, 0, stream>>>(labels, counts);
    offsets_kernel<<<1, 1, 0, stream>>>(counts, offs);
    scatter_kernel<<<(N_SUP + 255) / 256, 256, 0, stream>>>(labels, offs, cursor, members);

    // One-time conversions
    const int n4 = N_SUP * E_DIM / 4;
    conv32to16<<<n4 / 256, 256, 0, stream>>>(X, Xh, n4);
    transpose_w_f16<<<dim3(16, 16), 256, 0, stream>>>(Wk, Wkt);
    transpose_w_f16<<<dim3(16, 16), 256, 0, stream>>>(Wv, Wvt);

    const dim3 gGemm(N_SUP / 128, E_DIM / 128);
    for (int l = 0; l < L_LEV; ++l) {
        const float* W1l = W1 + (size_t)l * E_DIM * E_DIM;
        const float* W2l = W2 + (size_t)l * E_DIM * E_DIM;
        transpose_w_f16<<<dim3(16, 16), 256, 0, stream>>>(W1l, W1t);
        transpose_w_f16<<<dim3(16, 16), 256, 0, stream>>>(W2l, W2t);
        hgemm_bt<<<gGemm, 256, 0, stream>>>(Xh, W1t, b1 + l * E_DIM, bufP);
        ln_relu_h<<<N_SUP, 256, 0, stream>>>(bufP, gamma + l * E_DIM, beta + l * E_DIM);
        hgemm_bt<<<gGemm, 256, 0, stream>>>(bufP, W2t, b2 + l * E_DIM, bufF);
        hgemm_bt<<<gGemm, 256, 0, stream>>>(bufF, Wkt, bk, bufK);
        hgemm_bt<<<gGemm, 256, 0, stream>>>(bufF, Wvt, bv, bufV);
        zero_f32<<<(C_CLS * E_DIM) / 256, 256, 0, stream>>>(ctxs, C_CLS * E_DIM);
        ctx_sum_kernel<<<dim3(C_CLS, CTX_SPLITS), 256, 0, stream>>>(bufF, members, offs, ctxs);
        row_gemm_q<<<C_CLS, 256, 0, stream>>>(ctxs, counts, Wq, bq, qb);
        attn_partial<<<dim3(C_CLS, H_HEADS, ATTN_SPLITS), 256, 0, stream>>>(
            qb, bufK, bufV, members, offs, pm, pl, po);
        attn_combine<<<C_CLS * H_HEADS, 64, 0, stream>>>(pm, pl, po, ao);
        proto_accum<<<C_CLS, 256, 0, stream>>>(ao, Wo, bo, lvlw, lvlt, l, out);
    }
}

// Round 6
// 1419.073 us; speedup vs baseline: 4.7061x; 1.1844x over previous
//
#include <hip/hip_runtime.h>
#include <math.h>

// Problem constants (fixed by the reference)
#define N_SUP 65536
#define E_DIM 512
#define H_HEADS 8
#define C_CLS 64
#define DHD 64
#define L_LEV 3
#define LN_EPS 1e-5f
#define ATTN_SPLITS 4
#define SCAT_BLOCKS 256        // N_SUP / 256

typedef _Float16 f16x8 __attribute__((ext_vector_type(8)));
typedef _Float16 f16x4 __attribute__((ext_vector_type(4)));
typedef float f32x4 __attribute__((ext_vector_type(4)));

// ---------------------------------------------------------------------------
// async global->LDS copy, 16B per lane. LDS dest must be wave-uniform;
// HW deposits at ldsbase + lane*16.
// ---------------------------------------------------------------------------
__device__ __forceinline__ void gload_lds16(const void* g, void* lds) {
    __builtin_amdgcn_global_load_lds((const __attribute__((address_space(1))) void*)g,
                                     (__attribute__((address_space(3))) void*)lds,
                                     16, 0, 0);
}

// ---------------------------------------------------------------------------
// fp16 GEMM: C[M x 512] = A[M x 512] @ B + bias, Bt = B^T [512 x 512].
// 128x128 tile, BK=32, 4 waves in 2x2, each wave 4x4 grid of 16x16x32 MFMA.
// ---------------------------------------------------------------------------
__global__ __launch_bounds__(256)
void hgemm_bt(const _Float16* __restrict__ A, const _Float16* __restrict__ Bt,
              const float* __restrict__ bias, _Float16* __restrict__ C) {
    __shared__ _Float16 As[128][32];
    __shared__ _Float16 Bs[128][32];
    const int tid = threadIdx.x;
    const int wave = tid >> 6, lane = tid & 63;
    const int row0 = blockIdx.x * 128, col0 = blockIdx.y * 128;
    const int wm = (wave & 1) * 64, wn = (wave >> 1) * 64;

    const int ci0 = wave * 128 + lane, ci1 = ci0 + 64;
    const int r0 = ci0 >> 2, gc0 = (ci0 & 3) ^ ((r0 >> 1) & 3);
    const int r1 = ci1 >> 2, gc1 = (ci1 & 3) ^ ((r1 >> 1) & 3);
    const _Float16* Ar0 = A + (size_t)(row0 + r0) * E_DIM + gc0 * 8;
    const _Float16* Ar1 = A + (size_t)(row0 + r1) * E_DIM + gc1 * 8;
    const _Float16* Br0 = Bt + (size_t)(col0 + r0) * E_DIM + gc0 * 8;
    const _Float16* Br1 = Bt + (size_t)(col0 + r1) * E_DIM + gc1 * 8;
    char* ldsA = (char*)&As[0][0] + wave * 2048;
    char* ldsB = (char*)&Bs[0][0] + wave * 2048;

    const int m = lane & 15, q = lane >> 4;
    const int koff = ((q ^ ((m >> 1) & 3))) * 8;

    f32x4 acc[4][4];
#pragma unroll
    for (int i = 0; i < 4; ++i)
#pragma unroll
        for (int j = 0; j < 4; ++j) acc[i][j] = (f32x4){0.f, 0.f, 0.f, 0.f};

    for (int k0 = 0; k0 < E_DIM; k0 += 32) {
        gload_lds16(Ar0 + k0, ldsA);
        gload_lds16(Ar1 + k0, ldsA + 1024);
        gload_lds16(Br0 + k0, ldsB);
        gload_lds16(Br1 + k0, ldsB + 1024);
        __syncthreads();

        f16x8 af[4], bf[4];
#pragma unroll
        for (int i = 0; i < 4; ++i)
            af[i] = *(const f16x8*)&As[wm + i * 16 + m][koff];
#pragma unroll
        for (int j = 0; j < 4; ++j)
            bf[j] = *(const f16x8*)&Bs[wn + j * 16 + m][koff];
#pragma unroll
        for (int i = 0; i < 4; ++i)
#pragma unroll
            for (int j = 0; j < 4; ++j)
                acc[i][j] = __builtin_amdgcn_mfma_f32_16x16x32_f16(af[i], bf[j], acc[i][j], 0, 0, 0);
        __syncthreads();
    }

    // C/D layout: col = lane&15, row = (lane>>4)*4 + reg
#pragma unroll
    for (int i = 0; i < 4; ++i) {
        const int rbase = row0 + wm + i * 16 + q * 4;
#pragma unroll
        for (int j = 0; j < 4; ++j) {
            const int col = col0 + wn + j * 16 + m;
            const float bv = bias[col];
#pragma unroll
            for (int r = 0; r < 4; ++r)
                C[(size_t)(rbase + r) * E_DIM + col] = (_Float16)(acc[i][j][r] + bv);
        }
    }
}

// ---------------------------------------------------------------------------
// fp32 -> fp16 elementwise (vectorized x4)
// ---------------------------------------------------------------------------
__global__ __launch_bounds__(256)
void conv32to16(const float* __restrict__ in, _Float16* __restrict__ out, int n4) {
    int i = blockIdx.x * 256 + threadIdx.x;
    if (i < n4) {
        f32x4 v = ((const f32x4*)in)[i];
        f16x4 o = {(_Float16)v[0], (_Float16)v[1], (_Float16)v[2], (_Float16)v[3]};
        ((f16x4*)out)[i] = o;
    }
}

// ---------------------------------------------------------------------------
// W[512x512] fp32 (k-major) -> Wt[512x512] fp16 (n-major), LDS-tiled transpose
// ---------------------------------------------------------------------------
__global__ __launch_bounds__(256)
void transpose_w_f16(const float* __restrict__ W, _Float16* __restrict__ Wt) {
    __shared__ float t[32][33];
    const int k0 = blockIdx.x * 32, n0 = blockIdx.y * 32;
    const int tx = threadIdx.x & 31, ty = threadIdx.x >> 5;
#pragma unroll
    for (int r = 0; r < 32; r += 8)
        t[ty + r][tx] = W[(size_t)(k0 + ty + r) * E_DIM + n0 + tx];
    __syncthreads();
#pragma unroll
    for (int r = 0; r < 32; r += 8)
        Wt[(size_t)(n0 + ty + r) * E_DIM + k0 + tx] = (_Float16)t[tx][ty + r];
}

// ---------------------------------------------------------------------------
// LayerNorm + ReLU, wave-per-row: lane holds cols [lane*8, lane*8+8) as one
// f16x8 (one coalesced 1KB read per wave). Stats via 64-lane shuffles only.
// 4 rows per block.
// ---------------------------------------------------------------------------
__global__ __launch_bounds__(256)
void ln_relu_h(_Float16* __restrict__ P, const float* __restrict__ gamma,
               const float* __restrict__ beta) {
    const int row = blockIdx.x * 4 + (threadIdx.x >> 6);
    const int lane = threadIdx.x & 63;
    _Float16* prow = P + (size_t)row * E_DIM + lane * 8;
    f16x8 v = *(const f16x8*)prow;
    float x[8];
    float s = 0.f, s2 = 0.f;
#pragma unroll
    for (int e = 0; e < 8; ++e) {
        x[e] = (float)v[e];
        s += x[e];
        s2 = fmaf(x[e], x[e], s2);
    }
#pragma unroll
    for (int off = 32; off; off >>= 1) {
        s  += __shfl_xor(s, off);
        s2 += __shfl_xor(s2, off);
    }
    const float mean = s * (1.f / E_DIM);
    const float var  = s2 * (1.f / E_DIM) - mean * mean;
    const float rstd = rsqrtf(var + LN_EPS);
    f32x4 g0 = *(const f32x4*)(gamma + lane * 8);
    f32x4 g1 = *(const f32x4*)(gamma + lane * 8 + 4);
    f32x4 b0 = *(const f32x4*)(beta + lane * 8);
    f32x4 b1 = *(const f32x4*)(beta + lane * 8 + 4);
    f16x8 o;
#pragma unroll
    for (int e = 0; e < 4; ++e) {
        o[e]     = (_Float16)fmaxf(fmaf((x[e]     - mean) * rstd, g0[e], b0[e]), 0.f);
        o[e + 4] = (_Float16)fmaxf(fmaf((x[e + 4] - mean) * rstd, g1[e], b1[e]), 0.f);
    }
    *(f16x8*)prow = o;
}

// ---------------------------------------------------------------------------
// Contention-free counting sort (replaces global-atomic hist/scatter).
// Phase A: per-block LDS histogram of 256 labels.
// ---------------------------------------------------------------------------
__global__ __launch_bounds__(256)
void label_block_hist(const int* __restrict__ labels, int* __restrict__ blockCounts) {
    __shared__ int h[C_CLS];
    const int tid = threadIdx.x;
    if (tid < C_CLS) h[tid] = 0;
    __syncthreads();
    atomicAdd(&h[labels[blockIdx.x * 256 + tid]], 1);
    __syncthreads();
    if (tid < C_CLS) blockCounts[blockIdx.x * C_CLS + tid] = h[tid];
}

// Phase B: one block, 64 threads; thread c owns class c. Produces counts,
// offs (exclusive scan over classes), and per-block start offsets.
__global__ __launch_bounds__(64)
void scan_offsets(const int* __restrict__ blockCounts, int* __restrict__ counts,
                  int* __restrict__ offs, int* __restrict__ blockOffs) {
    const int c = threadIdx.x;
    int total = 0;
    for (int b = 0; b < SCAT_BLOCKS; ++b) total += blockCounts[b * C_CLS + c];
    counts[c] = total;
    __shared__ int tot[C_CLS];
    tot[c] = total;
    __syncthreads();
    int off = 0;
    for (int cc = 0; cc < c; ++cc) off += tot[cc];
    offs[c] = off;
    if (c == C_CLS - 1) offs[C_CLS] = off + total;
    int run = off;
    for (int b = 0; b < SCAT_BLOCKS; ++b) {
        blockOffs[b * C_CLS + c] = run;
        run += blockCounts[b * C_CLS + c];
    }
}

// Phase C: scatter with per-block LDS cursors (members near-sorted by index).
__global__ __launch_bounds__(256)
void scatter_sorted(const int* __restrict__ labels, const int* __restrict__ blockOffs,
                    int* __restrict__ members) {
    __shared__ int cur[C_CLS];
    const int tid = threadIdx.x;
    if (tid < C_CLS) cur[tid] = blockOffs[blockIdx.x * C_CLS + tid];
    __syncthreads();
    const int i = blockIdx.x * 256 + tid;
    const int c = labels[i];
    const int p = atomicAdd(&cur[c], 1);
    members[p] = i;
}

__global__ __launch_bounds__(256)
void zero_f32(float* __restrict__ p, int n) {
    int i = blockIdx.x * 256 + threadIdx.x;
    if (i < n) p[i] = 0.f;
}

// ---------------------------------------------------------------------------
// ctx_sum[c,:] += sum over class members of feat(fp16)[n,:]  (fp32 atomics)
// ---------------------------------------------------------------------------
#define CTX_SPLITS 8
__global__ __launch_bounds__(256)
void ctx_sum_kernel(const _Float16* __restrict__ feat, const int* __restrict__ members,
                    const int* __restrict__ offsets, float* __restrict__ ctx_sum) {
    const int c = blockIdx.x, split = blockIdx.y;
    const int tid = threadIdx.x;
    const int wave = tid >> 6, lane = tid & 63;
    const int start = offsets[c], end = offsets[c + 1];
    const int wg = split * 4 + wave;
    const int stride = 4 * CTX_SPLITS;

    float acc[8];
#pragma unroll
    for (int e = 0; e < 8; ++e) acc[e] = 0.f;

    int i = start + wg;
    for (; i + stride < end; i += 2 * stride) {
        const int n0 = members[i];
        const int n1 = members[i + stride];
        f16x8 r0 = *(const f16x8*)(feat + (size_t)n0 * E_DIM + lane * 8);
        f16x8 r1 = *(const f16x8*)(feat + (size_t)n1 * E_DIM + lane * 8);
#pragma unroll
        for (int e = 0; e < 8; ++e) acc[e] += (float)r0[e] + (float)r1[e];
    }
    if (i < end) {
        const int n0 = members[i];
        f16x8 r0 = *(const f16x8*)(feat + (size_t)n0 * E_DIM + lane * 8);
#pragma unroll
        for (int e = 0; e < 8; ++e) acc[e] += (float)r0[e];
    }

    __shared__ float red[4][64][8];
#pragma unroll
    for (int e = 0; e < 8; ++e) red[wave][lane][e] = acc[e];
    __syncthreads();
#pragma unroll
    for (int t = 0; t < 2; ++t) {
        const int col = tid * 2 + t;
        const int ln = col >> 3, e = col & 7;
        float s = red[0][ln][e] + red[1][ln][e] + red[2][ln][e] + red[3][ln][e];
        atomicAdd(&ctx_sum[c * E_DIM + col], s);
    }
}

// ---------------------------------------------------------------------------
// q[c,:] = (ctx_sum[c,:]/count) @ Wq + bq   (fp32, tiny)
// ---------------------------------------------------------------------------
__global__ __launch_bounds__(256)
void row_gemm_q(const float* __restrict__ ctx_sum, const int* __restrict__ counts,
                const float* __restrict__ Wq, const float* __restrict__ bq,
                float* __restrict__ q) {
    const int c = blockIdx.x;
    const int tid = threadIdx.x;
    const float inv = 1.f / (float)counts[c];
    __shared__ float xrow[E_DIM];
    xrow[tid]       = ctx_sum[c * E_DIM + tid] * inv;
    xrow[tid + 256] = ctx_sum[c * E_DIM + tid + 256] * inv;
    __syncthreads();
    float a0 = 0.f, a1 = 0.f;
#pragma unroll 8
    for (int k = 0; k < E_DIM; ++k) {
        float cv = xrow[k];
        a0 = fmaf(cv, Wq[(size_t)k * E_DIM + tid], a0);
        a1 = fmaf(cv, Wq[(size_t)k * E_DIM + tid + 256], a1);
    }
    q[c * E_DIM + tid]       = a0 + bq[tid];
    q[c * E_DIM + tid + 256] = a1 + bq[tid + 256];
}

// ---------------------------------------------------------------------------
// Segment attention, phase 1: partials per (class, head, split).
// ---------------------------------------------------------------------------
__global__ __launch_bounds__(256)
void attn_partial(const float* __restrict__ q, const _Float16* __restrict__ kbuf,
                  const _Float16* __restrict__ vbuf, const int* __restrict__ members,
                  const int* __restrict__ offsets, float* __restrict__ pm,
                  float* __restrict__ pl, float* __restrict__ po) {
    const int c = blockIdx.x, h = blockIdx.y, s = blockIdx.z;
    const int tid = threadIdx.x;
    const int wave = tid >> 6, lane = tid & 63;
    const int start = offsets[c], end = offsets[c + 1];
    const int g = s * 4 + wave;                 // 0..15

    const float* qrow = q + c * E_DIM + h * DHD;
    float qv[64];
#pragma unroll
    for (int d = 0; d < 64; ++d) qv[d] = qrow[d];

    __shared__ float ps[4][64];
    float m = -INFINITY, lsum = 0.f, out = 0.f; // lane owns output dim `lane`

    for (int ch0 = start + g * 64; ch0 < end; ch0 += 16 * 64) {
        const int nvalid = min(64, end - ch0);
        const int idx = ch0 + lane;
        const int mi = members[idx < end ? idx : end - 1];
        const _Float16* krow = kbuf + (size_t)mi * E_DIM + h * DHD;
        float dot = 0.f;
#pragma unroll
        for (int j = 0; j < 8; ++j) {
            f16x8 kr = *(const f16x8*)(krow + j * 8);
#pragma unroll
            for (int e = 0; e < 8; ++e)
                dot = fmaf((float)kr[e], qv[j * 8 + e], dot);
        }
        float sc = (lane < nvalid) ? dot * 0.125f : -INFINITY;
        float cm = sc;
#pragma unroll
        for (int off = 32; off; off >>= 1) cm = fmaxf(cm, __shfl_xor(cm, off));
        const float nm = fmaxf(m, cm);
        const float alpha = __expf(m - nm);
        const float p = (lane < nvalid) ? __expf(sc - nm) : 0.f;
        ps[wave][lane] = p;
        out *= alpha;
        lsum *= alpha;
        m = nm;
        asm volatile("" ::: "memory");
#pragma unroll 16
        for (int j = 0; j < 64; ++j) {
            const int nj = __shfl(mi, j);
            const float pj = ps[wave][j];
            const float vv = (float)vbuf[(size_t)nj * E_DIM + h * DHD + lane];
            out = fmaf(pj, vv, out);
            lsum += pj;
        }
    }

    __shared__ float rm[4], rl[4], racc[4][64];
    racc[wave][lane] = out;
    if (lane == 0) { rm[wave] = m; rl[wave] = lsum; }
    __syncthreads();
    if (wave == 0) {
        float M = fmaxf(fmaxf(rm[0], rm[1]), fmaxf(rm[2], rm[3]));
        float o = 0.f, Lt = 0.f;
#pragma unroll
        for (int w = 0; w < 4; ++w) {
            float al = __expf(rm[w] - M);   // all-empty wave -> 0
            o  += al * racc[w][lane];
            Lt += al * rl[w];
        }
        const int pidx = (c * H_HEADS + h) * ATTN_SPLITS + s;
        po[pidx * 64 + lane] = o;
        if (lane == 0) { pm[pidx] = M; pl[pidx] = Lt; }
    }
}

// ---------------------------------------------------------------------------
// Segment attention, phase 2: merge ATTN_SPLITS partials per (c,h).
// ---------------------------------------------------------------------------
__global__ __launch_bounds__(64)
void attn_combine(const float* __restrict__ pm, const float* __restrict__ pl,
                  const float* __restrict__ po, float* __restrict__ attn_out) {
    const int ch = blockIdx.x;          // c*H + h
    const int lane = threadIdx.x;
    float M = -INFINITY;
#pragma unroll
    for (int s = 0; s < ATTN_SPLITS; ++s) M = fmaxf(M, pm[ch * ATTN_SPLITS + s]);
    float o = 0.f, Lt = 0.f;
#pragma unroll
    for (int s = 0; s < ATTN_SPLITS; ++s) {
        const int pidx = ch * ATTN_SPLITS + s;
        float al = __expf(pm[pidx] - M);
        o  += al * po[pidx * 64 + lane];
        Lt += al * pl[pidx];
    }
    attn_out[ch * DHD + lane] = o / Lt;
}

// ---------------------------------------------------------------------------
// proto = attn_out @ Wo + bo; out (+)= coef_l * proto
// ---------------------------------------------------------------------------
__global__ __launch_bounds__(256)
void proto_accum(const float* __restrict__ attn_out, const float* __restrict__ Wo,
                 const float* __restrict__ bo, const float* __restrict__ lvlw,
                 const float* __restrict__ lvlt, int l, float* __restrict__ out) {
    const int c = blockIdx.x;
    const int tid = threadIdx.x;
    __shared__ float xrow[E_DIM];
    xrow[tid]       = attn_out[c * E_DIM + tid];
    xrow[tid + 256] = attn_out[c * E_DIM + tid + 256];
    __syncthreads();
    float a0 = 0.f, a1 = 0.f;
#pragma unroll 8
    for (int k = 0; k < E_DIM; ++k) {
        float cv = xrow[k];
        a0 = fmaf(cv, Wo[(size_t)k * E_DIM + tid], a0);
        a1 = fmaf(cv, Wo[(size_t)k * E_DIM + tid + 256], a1);
    }
    float w0 = lvlw[0], w1 = lvlw[1], w2 = lvlw[2];
    float mx = fmaxf(w0, fmaxf(w1, w2));
    float e0 = expf(w0 - mx), e1 = expf(w1 - mx), e2 = expf(w2 - mx);
    float ssum = e0 + e1 + e2;
    float lw = (l == 0 ? e0 : (l == 1 ? e1 : e2)) / ssum;
    float coef = lw / lvlt[l];
    float r0 = (a0 + bo[tid]) * coef;
    float r1 = (a1 + bo[tid + 256]) * coef;
    if (l == 0) {
        out[c * E_DIM + tid]       = r0;
        out[c * E_DIM + tid + 256] = r1;
    } else {
        out[c * E_DIM + tid]       += r0;
        out[c * E_DIM + tid + 256] += r1;
    }
}

// ---------------------------------------------------------------------------
extern "C" void kernel_launch(void* const* d_in, const int* in_sizes, int n_in,
                              void* d_out, int out_size, void* d_ws, size_t ws_size,
                              hipStream_t stream) {
    const float* X      = (const float*)d_in[0];
    const int*   labels = (const int*)  d_in[1];
    const float* W1     = (const float*)d_in[2];
    const float* b1     = (const float*)d_in[3];
    const float* gamma  = (const float*)d_in[4];
    const float* beta   = (const float*)d_in[5];
    const float* W2     = (const float*)d_in[6];
    const float* b2     = (const float*)d_in[7];
    const float* Wq     = (const float*)d_in[8];
    const float* bq     = (const float*)d_in[9];
    const float* Wk     = (const float*)d_in[10];
    const float* bk     = (const float*)d_in[11];
    const float* Wv     = (const float*)d_in[12];
    const float* bv     = (const float*)d_in[13];
    const float* Wo     = (const float*)d_in[14];
    const float* bo     = (const float*)d_in[15];
    const float* lvlw   = (const float*)d_in[16];
    const float* lvlt   = (const float*)d_in[17];
    float* out = (float*)d_out;

    // Workspace carve
    char* p = (char*)d_ws;
    const size_t bigh = (size_t)N_SUP * E_DIM * sizeof(_Float16);   // 64 MB
    _Float16* Xh   = (_Float16*)p; p += bigh;
    _Float16* bufP = (_Float16*)p; p += bigh;
    _Float16* bufF = (_Float16*)p; p += bigh;
    _Float16* bufK = (_Float16*)p; p += bigh;
    _Float16* bufV = (_Float16*)p; p += bigh;
    _Float16* W1t  = (_Float16*)p; p += (size_t)E_DIM * E_DIM * sizeof(_Float16);
    _Float16* W2t  = (_Float16*)p; p += (size_t)E_DIM * E_DIM * sizeof(_Float16);
    _Float16* Wkt  = (_Float16*)p; p += (size_t)E_DIM * E_DIM * sizeof(_Float16);
    _Float16* Wvt  = (_Float16*)p; p += (size_t)E_DIM * E_DIM * sizeof(_Float16);
    float* ctxs = (float*)p; p += C_CLS * E_DIM * sizeof(float);
    float* qb   = (float*)p; p += C_CLS * E_DIM * sizeof(float);
    float* ao   = (float*)p; p += C_CLS * E_DIM * sizeof(float);
    float* pm   = (float*)p; p += C_CLS * H_HEADS * ATTN_SPLITS * sizeof(float);
    float* pl   = (float*)p; p += C_CLS * H_HEADS * ATTN_SPLITS * sizeof(float);
    float* po   = (float*)p; p += C_CLS * H_HEADS * ATTN_SPLITS * 64 * sizeof(float);
    int* counts      = (int*)p; p += 256;
    int* offs        = (int*)p; p += 512;
    int* members     = (int*)p; p += (size_t)N_SUP * sizeof(int);
    int* blockCounts = (int*)p; p += (size_t)SCAT_BLOCKS * C_CLS * sizeof(int);
    int* blockOffs   = (int*)p; p += (size_t)SCAT_BLOCKS * C_CLS * sizeof(int);

    // Class membership preprocessing: contention-free counting sort
    label_block_hist<<<SCAT_BLOCKS, 256, 0, stream>>>(labels, blockCounts);
    scan_offsets<<<1, 64, 0, stream>>>(blockCounts, counts, offs, blockOffs);
    scatter_sorted<<<SCAT_BLOCKS, 256, 0, stream>>>(labels, blockOffs, members);

    // One-time conversions
    const int n4 = N_SUP * E_DIM / 4;
    conv32to16<<<n4 / 256, 256, 0, stream>>>(X, Xh, n4);
    transpose_w_f16<<<dim3(16, 16), 256, 0, stream>>>(Wk, Wkt);
    transpose_w_f16<<<dim3(16, 16), 256, 0, stream>>>(Wv, Wvt);

    const dim3 gGemm(N_SUP / 128, E_DIM / 128);
    for (int l = 0; l < L_LEV; ++l) {
        const float* W1l = W1 + (size_t)l * E_DIM * E_DIM;
        const float* W2l = W2 + (size_t)l * E_DIM * E_DIM;
        transpose_w_f16<<<dim3(16, 16), 256, 0, stream>>>(W1l, W1t);
        transpose_w_f16<<<dim3(16, 16), 256, 0, stream>>>(W2l, W2t);
        hgemm_bt<<<gGemm, 256, 0, stream>>>(Xh, W1t, b1 + l * E_DIM, bufP);
        ln_relu_h<<<N_SUP / 4, 256, 0, stream>>>(bufP, gamma + l * E_DIM, beta + l * E_DIM);
        hgemm_bt<<<gGemm, 256, 0, stream>>>(bufP, W2t, b2 + l * E_DIM, bufF);
        hgemm_bt<<<gGemm, 256, 0, stream>>>(bufF, Wkt, bk, bufK);
        hgemm_bt<<<gGemm, 256, 0, stream>>>(bufF, Wvt, bv, bufV);
        zero_f32<<<(C_CLS * E_DIM) / 256, 256, 0, stream>>>(ctxs, C_CLS * E_DIM);
        ctx_sum_kernel<<<dim3(C_CLS, CTX_SPLITS), 256, 0, stream>>>(bufF, members, offs, ctxs);
        row_gemm_q<<<C_CLS, 256, 0, stream>>>(ctxs, counts, Wq, bq, qb);
        attn_partial<<<dim3(C_CLS, H_HEADS, ATTN_SPLITS), 256, 0, stream>>>(
            qb, bufK, bufV, members, offs, pm, pl, po);
        attn_combine<<<C_CLS * H_HEADS, 64, 0, stream>>>(pm, pl, po, ao);
        proto_accum<<<C_CLS, 256, 0, stream>>>(ao, Wo, bo, lvlw, lvlt, l, out);
    }
}

// Round 7
// 1386.639 us; speedup vs baseline: 4.8161x; 1.0234x over previous
//
#include <hip/hip_runtime.h>
#include <math.h>

// Problem constants (fixed by the reference)
#define N_SUP 65536
#define E_DIM 512
#define H_HEADS 8
#define C_CLS 64
#define DHD 64
#define L_LEV 3
#define LN_EPS 1e-5f
#define ATTN_SPLITS 4
#define SCAT_BLOCKS 256        // N_SUP / 256

typedef _Float16 f16x8 __attribute__((ext_vector_type(8)));
typedef _Float16 f16x4 __attribute__((ext_vector_type(4)));
typedef float f32x4 __attribute__((ext_vector_type(4)));

// ---------------------------------------------------------------------------
// async global->LDS copy, 16B per lane. LDS dest must be wave-uniform;
// HW deposits at ldsbase + lane*16.
// ---------------------------------------------------------------------------
__device__ __forceinline__ void gload_lds16(const void* g, void* lds) {
    __builtin_amdgcn_global_load_lds((const __attribute__((address_space(1))) void*)g,
                                     (__attribute__((address_space(3))) void*)lds,
                                     16, 0, 0);
}

// ---------------------------------------------------------------------------
// fp16 GEMM: C[M x Ncols] = A[M x 512] @ B + bias; Bt is B^T [Ncols x 512]
// (row j = output column j, k-contiguous). lda/ldc = row strides of A/C.
// 128x128 tile, BK=32, 4 waves in 2x2, each wave 4x4 grid of 16x16x32 MFMA.
// Ncols = gridDim.y * 128.
// ---------------------------------------------------------------------------
__global__ __launch_bounds__(256)
void hgemm_bt(const _Float16* __restrict__ A, int lda,
              const _Float16* __restrict__ Bt, const float* __restrict__ bias,
              _Float16* __restrict__ C, int ldc) {
    __shared__ _Float16 As[128][32];
    __shared__ _Float16 Bs[128][32];
    const int tid = threadIdx.x;
    const int wave = tid >> 6, lane = tid & 63;
    const int row0 = blockIdx.x * 128, col0 = blockIdx.y * 128;
    const int wm = (wave & 1) * 64, wn = (wave >> 1) * 64;

    const int ci0 = wave * 128 + lane, ci1 = ci0 + 64;
    const int r0 = ci0 >> 2, gc0 = (ci0 & 3) ^ ((r0 >> 1) & 3);
    const int r1 = ci1 >> 2, gc1 = (ci1 & 3) ^ ((r1 >> 1) & 3);
    const _Float16* Ar0 = A + (size_t)(row0 + r0) * lda + gc0 * 8;
    const _Float16* Ar1 = A + (size_t)(row0 + r1) * lda + gc1 * 8;
    const _Float16* Br0 = Bt + (size_t)(col0 + r0) * E_DIM + gc0 * 8;
    const _Float16* Br1 = Bt + (size_t)(col0 + r1) * E_DIM + gc1 * 8;
    char* ldsA = (char*)&As[0][0] + wave * 2048;
    char* ldsB = (char*)&Bs[0][0] + wave * 2048;

    const int m = lane & 15, q = lane >> 4;
    const int koff = ((q ^ ((m >> 1) & 3))) * 8;

    f32x4 acc[4][4];
#pragma unroll
    for (int i = 0; i < 4; ++i)
#pragma unroll
        for (int j = 0; j < 4; ++j) acc[i][j] = (f32x4){0.f, 0.f, 0.f, 0.f};

    for (int k0 = 0; k0 < E_DIM; k0 += 32) {
        gload_lds16(Ar0 + k0, ldsA);
        gload_lds16(Ar1 + k0, ldsA + 1024);
        gload_lds16(Br0 + k0, ldsB);
        gload_lds16(Br1 + k0, ldsB + 1024);
        __syncthreads();

        f16x8 af[4], bf[4];
#pragma unroll
        for (int i = 0; i < 4; ++i)
            af[i] = *(const f16x8*)&As[wm + i * 16 + m][koff];
#pragma unroll
        for (int j = 0; j < 4; ++j)
            bf[j] = *(const f16x8*)&Bs[wn + j * 16 + m][koff];
#pragma unroll
        for (int i = 0; i < 4; ++i)
#pragma unroll
            for (int j = 0; j < 4; ++j)
                acc[i][j] = __builtin_amdgcn_mfma_f32_16x16x32_f16(af[i], bf[j], acc[i][j], 0, 0, 0);
        __syncthreads();
    }

    // C/D layout: col = lane&15, row = (lane>>4)*4 + reg
#pragma unroll
    for (int i = 0; i < 4; ++i) {
        const int rbase = row0 + wm + i * 16 + q * 4;
#pragma unroll
        for (int j = 0; j < 4; ++j) {
            const int col = col0 + wn + j * 16 + m;
            const float bv = bias[col];
#pragma unroll
            for (int r = 0; r < 4; ++r)
                C[(size_t)(rbase + r) * ldc + col] = (_Float16)(acc[i][j][r] + bv);
        }
    }
}

// ---------------------------------------------------------------------------
// fp32 -> fp16 elementwise (vectorized x4)
// ---------------------------------------------------------------------------
__global__ __launch_bounds__(256)
void conv32to16(const float* __restrict__ in, _Float16* __restrict__ out, int n4) {
    int i = blockIdx.x * 256 + threadIdx.x;
    if (i < n4) {
        f32x4 v = ((const f32x4*)in)[i];
        f16x4 o = {(_Float16)v[0], (_Float16)v[1], (_Float16)v[2], (_Float16)v[3]};
        ((f16x4*)out)[i] = o;
    }
}

// ---------------------------------------------------------------------------
// Batched weight transpose: all 8 [512x512] fp32 k-major -> fp16 n-major.
// z 0..2: W1[l] -> W1allT rows l*512..; z 3..5: W2[l] -> W2allT rows l*512..;
// z 6: Wk -> WkvT rows 0..; z 7: Wv -> WkvT rows 512..
// ---------------------------------------------------------------------------
__global__ __launch_bounds__(256)
void transpose_all(const float* __restrict__ W1, const float* __restrict__ W2,
                   const float* __restrict__ Wk, const float* __restrict__ Wv,
                   _Float16* __restrict__ W1allT, _Float16* __restrict__ W2allT,
                   _Float16* __restrict__ WkvT) {
    const int z = blockIdx.z;
    const float* src;
    _Float16* dst;
    const size_t MSZ = (size_t)E_DIM * E_DIM;
    if (z < 3)      { src = W1 + z * MSZ;       dst = W1allT + z * MSZ; }
    else if (z < 6) { src = W2 + (z - 3) * MSZ; dst = W2allT + (z - 3) * MSZ; }
    else if (z == 6){ src = Wk;                 dst = WkvT; }
    else            { src = Wv;                 dst = WkvT + MSZ; }

    __shared__ float t[32][33];
    const int k0 = blockIdx.x * 32, n0 = blockIdx.y * 32;
    const int tx = threadIdx.x & 31, ty = threadIdx.x >> 5;
#pragma unroll
    for (int r = 0; r < 32; r += 8)
        t[ty + r][tx] = src[(size_t)(k0 + ty + r) * E_DIM + n0 + tx];
    __syncthreads();
#pragma unroll
    for (int r = 0; r < 32; r += 8)
        dst[(size_t)(n0 + ty + r) * E_DIM + k0 + tx] = (_Float16)t[tx][ty + r];
}

// bkv = concat(bk, bv)
__global__ __launch_bounds__(256)
void concat_bias(const float* __restrict__ bk, const float* __restrict__ bv,
                 float* __restrict__ bkv) {
    int i = blockIdx.x * 256 + threadIdx.x;   // 0..1023
    bkv[i] = (i < E_DIM) ? bk[i] : bv[i - E_DIM];
}

// ---------------------------------------------------------------------------
// LayerNorm + ReLU over bufPall [N x 1536], all 3 levels in one dispatch.
// grid.y = level; wave-per-row-segment; lane holds 8 cols as one f16x8.
// ---------------------------------------------------------------------------
__global__ __launch_bounds__(256)
void ln_relu_all(_Float16* __restrict__ P, const float* __restrict__ gamma,
                 const float* __restrict__ beta) {
    const int row = blockIdx.x * 4 + (threadIdx.x >> 6);
    const int l = blockIdx.y;
    const int lane = threadIdx.x & 63;
    _Float16* prow = P + (size_t)row * (L_LEV * E_DIM) + l * E_DIM + lane * 8;
    const float* g = gamma + l * E_DIM + lane * 8;
    const float* b = beta  + l * E_DIM + lane * 8;
    f16x8 v = *(const f16x8*)prow;
    float x[8];
    float s = 0.f, s2 = 0.f;
#pragma unroll
    for (int e = 0; e < 8; ++e) {
        x[e] = (float)v[e];
        s += x[e];
        s2 = fmaf(x[e], x[e], s2);
    }
#pragma unroll
    for (int off = 32; off; off >>= 1) {
        s  += __shfl_xor(s, off);
        s2 += __shfl_xor(s2, off);
    }
    const float mean = s * (1.f / E_DIM);
    const float var  = s2 * (1.f / E_DIM) - mean * mean;
    const float rstd = rsqrtf(var + LN_EPS);
    f32x4 g0 = *(const f32x4*)g;
    f32x4 g1 = *(const f32x4*)(g + 4);
    f32x4 b0 = *(const f32x4*)b;
    f32x4 b1 = *(const f32x4*)(b + 4);
    f16x8 o;
#pragma unroll
    for (int e = 0; e < 4; ++e) {
        o[e]     = (_Float16)fmaxf(fmaf((x[e]     - mean) * rstd, g0[e], b0[e]), 0.f);
        o[e + 4] = (_Float16)fmaxf(fmaf((x[e + 4] - mean) * rstd, g1[e], b1[e]), 0.f);
    }
    *(f16x8*)prow = o;
}

// ---------------------------------------------------------------------------
// Contention-free counting sort
// ---------------------------------------------------------------------------
__global__ __launch_bounds__(256)
void label_block_hist(const int* __restrict__ labels, int* __restrict__ blockCounts) {
    __shared__ int h[C_CLS];
    const int tid = threadIdx.x;
    if (tid < C_CLS) h[tid] = 0;
    __syncthreads();
    atomicAdd(&h[labels[blockIdx.x * 256 + tid]], 1);
    __syncthreads();
    if (tid < C_CLS) blockCounts[blockIdx.x * C_CLS + tid] = h[tid];
}

__global__ __launch_bounds__(64)
void scan_offsets(const int* __restrict__ blockCounts, int* __restrict__ counts,
                  int* __restrict__ offs, int* __restrict__ blockOffs) {
    const int c = threadIdx.x;
    int total = 0;
    for (int b = 0; b < SCAT_BLOCKS; ++b) total += blockCounts[b * C_CLS + c];
    counts[c] = total;
    __shared__ int tot[C_CLS];
    tot[c] = total;
    __syncthreads();
    int off = 0;
    for (int cc = 0; cc < c; ++cc) off += tot[cc];
    offs[c] = off;
    if (c == C_CLS - 1) offs[C_CLS] = off + total;
    int run = off;
    for (int b = 0; b < SCAT_BLOCKS; ++b) {
        blockOffs[b * C_CLS + c] = run;
        run += blockCounts[b * C_CLS + c];
    }
}

__global__ __launch_bounds__(256)
void scatter_sorted(const int* __restrict__ labels, const int* __restrict__ blockOffs,
                    int* __restrict__ members) {
    __shared__ int cur[C_CLS];
    const int tid = threadIdx.x;
    if (tid < C_CLS) cur[tid] = blockOffs[blockIdx.x * C_CLS + tid];
    __syncthreads();
    const int i = blockIdx.x * 256 + tid;
    const int c = labels[i];
    const int p = atomicAdd(&cur[c], 1);
    members[p] = i;
}

__global__ __launch_bounds__(256)
void zero_f32(float* __restrict__ p, int n) {
    int i = blockIdx.x * 256 + threadIdx.x;
    if (i < n) p[i] = 0.f;
}

// ---------------------------------------------------------------------------
// ctx_sum[c,:] += sum over class members of feat(fp16)[n,:]  (fp32 atomics)
// ---------------------------------------------------------------------------
#define CTX_SPLITS 8
__global__ __launch_bounds__(256)
void ctx_sum_kernel(const _Float16* __restrict__ feat, const int* __restrict__ members,
                    const int* __restrict__ offsets, float* __restrict__ ctx_sum) {
    const int c = blockIdx.x, split = blockIdx.y;
    const int tid = threadIdx.x;
    const int wave = tid >> 6, lane = tid & 63;
    const int start = offsets[c], end = offsets[c + 1];
    const int wg = split * 4 + wave;
    const int stride = 4 * CTX_SPLITS;

    float acc[8];
#pragma unroll
    for (int e = 0; e < 8; ++e) acc[e] = 0.f;

    int i = start + wg;
    for (; i + stride < end; i += 2 * stride) {
        const int n0 = members[i];
        const int n1 = members[i + stride];
        f16x8 r0 = *(const f16x8*)(feat + (size_t)n0 * E_DIM + lane * 8);
        f16x8 r1 = *(const f16x8*)(feat + (size_t)n1 * E_DIM + lane * 8);
#pragma unroll
        for (int e = 0; e < 8; ++e) acc[e] += (float)r0[e] + (float)r1[e];
    }
    if (i < end) {
        const int n0 = members[i];
        f16x8 r0 = *(const f16x8*)(feat + (size_t)n0 * E_DIM + lane * 8);
#pragma unroll
        for (int e = 0; e < 8; ++e) acc[e] += (float)r0[e];
    }

    __shared__ float red[4][64][8];
#pragma unroll
    for (int e = 0; e < 8; ++e) red[wave][lane][e] = acc[e];
    __syncthreads();
#pragma unroll
    for (int t = 0; t < 2; ++t) {
        const int col = tid * 2 + t;
        const int ln = col >> 3, e = col & 7;
        float s = red[0][ln][e] + red[1][ln][e] + red[2][ln][e] + red[3][ln][e];
        atomicAdd(&ctx_sum[c * E_DIM + col], s);
    }
}

// ---------------------------------------------------------------------------
// q[c,:] = (ctx_sum[c,:]/count) @ Wq + bq   (fp32, tiny)
// ---------------------------------------------------------------------------
__global__ __launch_bounds__(256)
void row_gemm_q(const float* __restrict__ ctx_sum, const int* __restrict__ counts,
                const float* __restrict__ Wq, const float* __restrict__ bq,
                float* __restrict__ q) {
    const int c = blockIdx.x;
    const int tid = threadIdx.x;
    const float inv = 1.f / (float)counts[c];
    __shared__ float xrow[E_DIM];
    xrow[tid]       = ctx_sum[c * E_DIM + tid] * inv;
    xrow[tid + 256] = ctx_sum[c * E_DIM + tid + 256] * inv;
    __syncthreads();
    float a0 = 0.f, a1 = 0.f;
#pragma unroll 8
    for (int k = 0; k < E_DIM; ++k) {
        float cv = xrow[k];
        a0 = fmaf(cv, Wq[(size_t)k * E_DIM + tid], a0);
        a1 = fmaf(cv, Wq[(size_t)k * E_DIM + tid + 256], a1);
    }
    q[c * E_DIM + tid]       = a0 + bq[tid];
    q[c * E_DIM + tid + 256] = a1 + bq[tid + 256];
}

// ---------------------------------------------------------------------------
// Segment attention, phase 1. K/V packed: row n = [K(512) | V(512)] in bufKV.
// ---------------------------------------------------------------------------
#define KV_LD 1024
__global__ __launch_bounds__(256)
void attn_partial(const float* __restrict__ q, const _Float16* __restrict__ kv,
                  const int* __restrict__ members, const int* __restrict__ offsets,
                  float* __restrict__ pm, float* __restrict__ pl,
                  float* __restrict__ po) {
    const int c = blockIdx.x, h = blockIdx.y, s = blockIdx.z;
    const int tid = threadIdx.x;
    const int wave = tid >> 6, lane = tid & 63;
    const int start = offsets[c], end = offsets[c + 1];
    const int g = s * 4 + wave;                 // 0..15

    const float* qrow = q + c * E_DIM + h * DHD;
    float qv[64];
#pragma unroll
    for (int d = 0; d < 64; ++d) qv[d] = qrow[d];

    __shared__ float ps[4][64];
    float m = -INFINITY, lsum = 0.f, out = 0.f; // lane owns output dim `lane`

    for (int ch0 = start + g * 64; ch0 < end; ch0 += 16 * 64) {
        const int nvalid = min(64, end - ch0);
        const int idx = ch0 + lane;
        const int mi = members[idx < end ? idx : end - 1];
        const _Float16* krow = kv + (size_t)mi * KV_LD + h * DHD;
        float dot = 0.f;
#pragma unroll
        for (int j = 0; j < 8; ++j) {
            f16x8 kr = *(const f16x8*)(krow + j * 8);
#pragma unroll
            for (int e = 0; e < 8; ++e)
                dot = fmaf((float)kr[e], qv[j * 8 + e], dot);
        }
        float sc = (lane < nvalid) ? dot * 0.125f : -INFINITY;
        float cm = sc;
#pragma unroll
        for (int off = 32; off; off >>= 1) cm = fmaxf(cm, __shfl_xor(cm, off));
        const float nm = fmaxf(m, cm);
        const float alpha = __expf(m - nm);
        const float p = (lane < nvalid) ? __expf(sc - nm) : 0.f;
        ps[wave][lane] = p;
        out *= alpha;
        lsum *= alpha;
        m = nm;
        asm volatile("" ::: "memory");
#pragma unroll 16
        for (int j = 0; j < 64; ++j) {
            const int nj = __shfl(mi, j);
            const float pj = ps[wave][j];
            const float vv = (float)kv[(size_t)nj * KV_LD + E_DIM + h * DHD + lane];
            out = fmaf(pj, vv, out);
            lsum += pj;
        }
    }

    __shared__ float rm[4], rl[4], racc[4][64];
    racc[wave][lane] = out;
    if (lane == 0) { rm[wave] = m; rl[wave] = lsum; }
    __syncthreads();
    if (wave == 0) {
        float M = fmaxf(fmaxf(rm[0], rm[1]), fmaxf(rm[2], rm[3]));
        float o = 0.f, Lt = 0.f;
#pragma unroll
        for (int w = 0; w < 4; ++w) {
            float al = __expf(rm[w] - M);   // all-empty wave -> 0
            o  += al * racc[w][lane];
            Lt += al * rl[w];
        }
        const int pidx = (c * H_HEADS + h) * ATTN_SPLITS + s;
        po[pidx * 64 + lane] = o;
        if (lane == 0) { pm[pidx] = M; pl[pidx] = Lt; }
    }
}

// ---------------------------------------------------------------------------
// Segment attention, phase 2: merge ATTN_SPLITS partials per (c,h).
// ---------------------------------------------------------------------------
__global__ __launch_bounds__(64)
void attn_combine(const float* __restrict__ pm, const float* __restrict__ pl,
                  const float* __restrict__ po, float* __restrict__ attn_out) {
    const int ch = blockIdx.x;          // c*H + h
    const int lane = threadIdx.x;
    float M = -INFINITY;
#pragma unroll
    for (int s = 0; s < ATTN_SPLITS; ++s) M = fmaxf(M, pm[ch * ATTN_SPLITS + s]);
    float o = 0.f, Lt = 0.f;
#pragma unroll
    for (int s = 0; s < ATTN_SPLITS; ++s) {
        const int pidx = ch * ATTN_SPLITS + s;
        float al = __expf(pm[pidx] - M);
        o  += al * po[pidx * 64 + lane];
        Lt += al * pl[pidx];
    }
    attn_out[ch * DHD + lane] = o / Lt;
}

// ---------------------------------------------------------------------------
// proto = attn_out @ Wo + bo; out (+)= coef_l * proto
// ---------------------------------------------------------------------------
__global__ __launch_bounds__(256)
void proto_accum(const float* __restrict__ attn_out, const float* __restrict__ Wo,
                 const float* __restrict__ bo, const float* __restrict__ lvlw,
                 const float* __restrict__ lvlt, int l, float* __restrict__ out) {
    const int c = blockIdx.x;
    const int tid = threadIdx.x;
    __shared__ float xrow[E_DIM];
    xrow[tid]       = attn_out[c * E_DIM + tid];
    xrow[tid + 256] = attn_out[c * E_DIM + tid + 256];
    __syncthreads();
    float a0 = 0.f, a1 = 0.f;
#pragma unroll 8
    for (int k = 0; k < E_DIM; ++k) {
        float cv = xrow[k];
        a0 = fmaf(cv, Wo[(size_t)k * E_DIM + tid], a0);
        a1 = fmaf(cv, Wo[(size_t)k * E_DIM + tid + 256], a1);
    }
    float w0 = lvlw[0], w1 = lvlw[1], w2 = lvlw[2];
    float mx = fmaxf(w0, fmaxf(w1, w2));
    float e0 = expf(w0 - mx), e1 = expf(w1 - mx), e2 = expf(w2 - mx);
    float ssum = e0 + e1 + e2;
    float lw = (l == 0 ? e0 : (l == 1 ? e1 : e2)) / ssum;
    float coef = lw / lvlt[l];
    float r0 = (a0 + bo[tid]) * coef;
    float r1 = (a1 + bo[tid + 256]) * coef;
    if (l == 0) {
        out[c * E_DIM + tid]       = r0;
        out[c * E_DIM + tid + 256] = r1;
    } else {
        out[c * E_DIM + tid]       += r0;
        out[c * E_DIM + tid + 256] += r1;
    }
}

// ---------------------------------------------------------------------------
extern "C" void kernel_launch(void* const* d_in, const int* in_sizes, int n_in,
                              void* d_out, int out_size, void* d_ws, size_t ws_size,
                              hipStream_t stream) {
    const float* X      = (const float*)d_in[0];
    const int*   labels = (const int*)  d_in[1];
    const float* W1     = (const float*)d_in[2];
    const float* b1     = (const float*)d_in[3];   // [3,512] flat == fused bias
    const float* gamma  = (const float*)d_in[4];
    const float* beta   = (const float*)d_in[5];
    const float* W2     = (const float*)d_in[6];
    const float* b2     = (const float*)d_in[7];
    const float* Wq     = (const float*)d_in[8];
    const float* bq     = (const float*)d_in[9];
    const float* Wk     = (const float*)d_in[10];
    const float* bk     = (const float*)d_in[11];
    const float* Wv     = (const float*)d_in[12];
    const float* bv     = (const float*)d_in[13];
    const float* Wo     = (const float*)d_in[14];
    const float* bo     = (const float*)d_in[15];
    const float* lvlw   = (const float*)d_in[16];
    const float* lvlt   = (const float*)d_in[17];
    float* out = (float*)d_out;

    // Workspace carve (~453 MB of the 512 MiB ws)
    char* p = (char*)d_ws;
    const size_t MSZ = (size_t)E_DIM * E_DIM;                       // 262144
    _Float16* Xh     = (_Float16*)p; p += (size_t)N_SUP * E_DIM * 2;        // 64 MB
    _Float16* bufPall= (_Float16*)p; p += (size_t)N_SUP * E_DIM * L_LEV * 2;// 192 MB
    _Float16* bufF   = (_Float16*)p; p += (size_t)N_SUP * E_DIM * 2;        // 64 MB
    _Float16* bufKV  = (_Float16*)p; p += (size_t)N_SUP * KV_LD * 2;        // 128 MB
    _Float16* W1allT = (_Float16*)p; p += L_LEV * MSZ * 2;
    _Float16* W2allT = (_Float16*)p; p += L_LEV * MSZ * 2;
    _Float16* WkvT   = (_Float16*)p; p += 2 * MSZ * 2;
    float* bkv  = (float*)p; p += KV_LD * sizeof(float);
    float* ctxs = (float*)p; p += C_CLS * E_DIM * sizeof(float);
    float* qb   = (float*)p; p += C_CLS * E_DIM * sizeof(float);
    float* ao   = (float*)p; p += C_CLS * E_DIM * sizeof(float);
    float* pm   = (float*)p; p += C_CLS * H_HEADS * ATTN_SPLITS * sizeof(float);
    float* pl   = (float*)p; p += C_CLS * H_HEADS * ATTN_SPLITS * sizeof(float);
    float* po   = (float*)p; p += C_CLS * H_HEADS * ATTN_SPLITS * 64 * sizeof(float);
    int* counts      = (int*)p; p += 256;
    int* offs        = (int*)p; p += 512;
    int* members     = (int*)p; p += (size_t)N_SUP * sizeof(int);
    int* blockCounts = (int*)p; p += (size_t)SCAT_BLOCKS * C_CLS * sizeof(int);
    int* blockOffs   = (int*)p; p += (size_t)SCAT_BLOCKS * C_CLS * sizeof(int);

    // Class membership: contention-free counting sort
    label_block_hist<<<SCAT_BLOCKS, 256, 0, stream>>>(labels, blockCounts);
    scan_offsets<<<1, 64, 0, stream>>>(blockCounts, counts, offs, blockOffs);
    scatter_sorted<<<SCAT_BLOCKS, 256, 0, stream>>>(labels, blockOffs, members);

    // One-time conversions (single dispatches)
    const int n4 = N_SUP * E_DIM / 4;
    conv32to16<<<n4 / 256, 256, 0, stream>>>(X, Xh, n4);
    transpose_all<<<dim3(16, 16, 8), 256, 0, stream>>>(W1, W2, Wk, Wv,
                                                       W1allT, W2allT, WkvT);
    concat_bias<<<KV_LD / 256, 256, 0, stream>>>(bk, bv, bkv);

    // Fused pre = X @ [W1_0|W1_1|W1_2] + b1  -> bufPall [N x 1536]
    hgemm_bt<<<dim3(N_SUP / 128, (L_LEV * E_DIM) / 128), 256, 0, stream>>>(
        Xh, E_DIM, W1allT, b1, bufPall, L_LEV * E_DIM);
    // LN+ReLU for all 3 levels in one dispatch
    ln_relu_all<<<dim3(N_SUP / 4, L_LEV), 256, 0, stream>>>(bufPall, gamma, beta);

    for (int l = 0; l < L_LEV; ++l) {
        // feat = h_l @ W2_l + b2_l  (A strided within bufPall)
        hgemm_bt<<<dim3(N_SUP / 128, E_DIM / 128), 256, 0, stream>>>(
            bufPall + (size_t)l * E_DIM, L_LEV * E_DIM,
            W2allT + (size_t)l * MSZ, b2 + l * E_DIM, bufF, E_DIM);
        // [K|V] = feat @ [Wk|Wv] + [bk|bv]  -> bufKV [N x 1024]
        hgemm_bt<<<dim3(N_SUP / 128, KV_LD / 128), 256, 0, stream>>>(
            bufF, E_DIM, WkvT, bkv, bufKV, KV_LD);
        zero_f32<<<(C_CLS * E_DIM) / 256, 256, 0, stream>>>(ctxs, C_CLS * E_DIM);
        ctx_sum_kernel<<<dim3(C_CLS, CTX_SPLITS), 256, 0, stream>>>(bufF, members, offs, ctxs);
        row_gemm_q<<<C_CLS, 256, 0, stream>>>(ctxs, counts, Wq, bq, qb);
        attn_partial<<<dim3(C_CLS, H_HEADS, ATTN_SPLITS), 256, 0, stream>>>(
            qb, bufKV, members, offs, pm, pl, po);
        attn_combine<<<C_CLS * H_HEADS, 64, 0, stream>>>(pm, pl, po, ao);
        proto_accum<<<C_CLS, 256, 0, stream>>>(ao, Wo, bo, lvlw, lvlt, l, out);
    }
}

// Round 8
// 1236.737 us; speedup vs baseline: 5.3999x; 1.1212x over previous
//
#include <hip/hip_runtime.h>
#include <math.h>

// Problem constants (fixed by the reference)
#define N_SUP 65536
#define E_DIM 512
#define H_HEADS 8
#define C_CLS 64
#define DHD 64
#define L_LEV 3
#define LN_EPS 1e-5f
#define ATTN_SPLITS 4
#define SCAT_BLOCKS 256        // N_SUP / 256

typedef _Float16 f16x8 __attribute__((ext_vector_type(8)));
typedef _Float16 f16x4 __attribute__((ext_vector_type(4)));
typedef float f32x4 __attribute__((ext_vector_type(4)));

// ---------------------------------------------------------------------------
// async global->LDS copy, 16B per lane. LDS dest must be wave-uniform;
// HW deposits at ldsbase + lane*16.
// ---------------------------------------------------------------------------
__device__ __forceinline__ void gload_lds16(const void* g, void* lds) {
    __builtin_amdgcn_global_load_lds((const __attribute__((address_space(1))) void*)g,
                                     (__attribute__((address_space(3))) void*)lds,
                                     16, 0, 0);
}

// ---------------------------------------------------------------------------
// fp16 GEMM: C[M x Ncols] = A[M x 512] @ B + bias; Bt is B^T [Ncols x 512].
// 1D grid = nRow*nCol tiles of 128x128, band-swizzled so that all col-tiles
// of one row-tile are (a) 64 dispatches apart (1MB/XCD footprint, L2-hot) and
// (b) bid%8 == row%8 -> same XCD under round-robin => A fetched once from HBM.
// ---------------------------------------------------------------------------
__global__ __launch_bounds__(256)
void hgemm_bt(const _Float16* __restrict__ A, int lda,
              const _Float16* __restrict__ Bt, const float* __restrict__ bias,
              _Float16* __restrict__ C, int ldc, int nCol) {
    // band swizzle (nRow assumed multiple of 64)
    const int bid = blockIdx.x;
    const int bandSz = 64 * nCol;
    const int band = bid / bandSz;
    const int rem = bid % bandSz;
    const int colT = rem / 64;
    const int rowT = band * 64 + (rem % 64);

    __shared__ _Float16 As[128][32];
    __shared__ _Float16 Bs[128][32];
    const int tid = threadIdx.x;
    const int wave = tid >> 6, lane = tid & 63;
    const int row0 = rowT * 128, col0 = colT * 128;
    const int wm = (wave & 1) * 64, wn = (wave >> 1) * 64;

    const int ci0 = wave * 128 + lane, ci1 = ci0 + 64;
    const int r0 = ci0 >> 2, gc0 = (ci0 & 3) ^ ((r0 >> 1) & 3);
    const int r1 = ci1 >> 2, gc1 = (ci1 & 3) ^ ((r1 >> 1) & 3);
    const _Float16* Ar0 = A + (size_t)(row0 + r0) * lda + gc0 * 8;
    const _Float16* Ar1 = A + (size_t)(row0 + r1) * lda + gc1 * 8;
    const _Float16* Br0 = Bt + (size_t)(col0 + r0) * E_DIM + gc0 * 8;
    const _Float16* Br1 = Bt + (size_t)(col0 + r1) * E_DIM + gc1 * 8;
    char* ldsA = (char*)&As[0][0] + wave * 2048;
    char* ldsB = (char*)&Bs[0][0] + wave * 2048;

    const int m = lane & 15, q = lane >> 4;
    const int koff = ((q ^ ((m >> 1) & 3))) * 8;

    f32x4 acc[4][4];
#pragma unroll
    for (int i = 0; i < 4; ++i)
#pragma unroll
        for (int j = 0; j < 4; ++j) acc[i][j] = (f32x4){0.f, 0.f, 0.f, 0.f};

    for (int k0 = 0; k0 < E_DIM; k0 += 32) {
        gload_lds16(Ar0 + k0, ldsA);
        gload_lds16(Ar1 + k0, ldsA + 1024);
        gload_lds16(Br0 + k0, ldsB);
        gload_lds16(Br1 + k0, ldsB + 1024);
        __syncthreads();

        f16x8 af[4], bf[4];
#pragma unroll
        for (int i = 0; i < 4; ++i)
            af[i] = *(const f16x8*)&As[wm + i * 16 + m][koff];
#pragma unroll
        for (int j = 0; j < 4; ++j)
            bf[j] = *(const f16x8*)&Bs[wn + j * 16 + m][koff];
#pragma unroll
        for (int i = 0; i < 4; ++i)
#pragma unroll
            for (int j = 0; j < 4; ++j)
                acc[i][j] = __builtin_amdgcn_mfma_f32_16x16x32_f16(af[i], bf[j], acc[i][j], 0, 0, 0);
        __syncthreads();
    }

    // C/D layout: col = lane&15, row = (lane>>4)*4 + reg
#pragma unroll
    for (int i = 0; i < 4; ++i) {
        const int rbase = row0 + wm + i * 16 + q * 4;
#pragma unroll
        for (int j = 0; j < 4; ++j) {
            const int col = col0 + wn + j * 16 + m;
            const float bv = bias[col];
#pragma unroll
            for (int r = 0; r < 4; ++r)
                C[(size_t)(rbase + r) * ldc + col] = (_Float16)(acc[i][j][r] + bv);
        }
    }
}

// ---------------------------------------------------------------------------
// fp32 -> fp16 elementwise (vectorized x4)
// ---------------------------------------------------------------------------
__global__ __launch_bounds__(256)
void conv32to16(const float* __restrict__ in, _Float16* __restrict__ out, int n4) {
    int i = blockIdx.x * 256 + threadIdx.x;
    if (i < n4) {
        f32x4 v = ((const f32x4*)in)[i];
        f16x4 o = {(_Float16)v[0], (_Float16)v[1], (_Float16)v[2], (_Float16)v[3]};
        ((f16x4*)out)[i] = o;
    }
}

// ---------------------------------------------------------------------------
// Batched weight transpose: all 8 [512x512] fp32 k-major -> fp16 n-major.
// ---------------------------------------------------------------------------
__global__ __launch_bounds__(256)
void transpose_all(const float* __restrict__ W1, const float* __restrict__ W2,
                   const float* __restrict__ Wk, const float* __restrict__ Wv,
                   _Float16* __restrict__ W1allT, _Float16* __restrict__ W2allT,
                   _Float16* __restrict__ WkvT) {
    const int z = blockIdx.z;
    const float* src;
    _Float16* dst;
    const size_t MSZ = (size_t)E_DIM * E_DIM;
    if (z < 3)      { src = W1 + z * MSZ;       dst = W1allT + z * MSZ; }
    else if (z < 6) { src = W2 + (z - 3) * MSZ; dst = W2allT + (z - 3) * MSZ; }
    else if (z == 6){ src = Wk;                 dst = WkvT; }
    else            { src = Wv;                 dst = WkvT + MSZ; }

    __shared__ float t[32][33];
    const int k0 = blockIdx.x * 32, n0 = blockIdx.y * 32;
    const int tx = threadIdx.x & 31, ty = threadIdx.x >> 5;
#pragma unroll
    for (int r = 0; r < 32; r += 8)
        t[ty + r][tx] = src[(size_t)(k0 + ty + r) * E_DIM + n0 + tx];
    __syncthreads();
#pragma unroll
    for (int r = 0; r < 32; r += 8)
        dst[(size_t)(n0 + ty + r) * E_DIM + k0 + tx] = (_Float16)t[tx][ty + r];
}

// bkv = concat(bk, bv)
__global__ __launch_bounds__(256)
void concat_bias(const float* __restrict__ bk, const float* __restrict__ bv,
                 float* __restrict__ bkv) {
    int i = blockIdx.x * 256 + threadIdx.x;   // 0..1023
    bkv[i] = (i < E_DIM) ? bk[i] : bv[i - E_DIM];
}

// ---------------------------------------------------------------------------
// LayerNorm + ReLU over bufPall [N x 1536], all 3 levels in one dispatch.
// ---------------------------------------------------------------------------
__global__ __launch_bounds__(256)
void ln_relu_all(_Float16* __restrict__ P, const float* __restrict__ gamma,
                 const float* __restrict__ beta) {
    const int row = blockIdx.x * 4 + (threadIdx.x >> 6);
    const int l = blockIdx.y;
    const int lane = threadIdx.x & 63;
    _Float16* prow = P + (size_t)row * (L_LEV * E_DIM) + l * E_DIM + lane * 8;
    const float* g = gamma + l * E_DIM + lane * 8;
    const float* b = beta  + l * E_DIM + lane * 8;
    f16x8 v = *(const f16x8*)prow;
    float x[8];
    float s = 0.f, s2 = 0.f;
#pragma unroll
    for (int e = 0; e < 8; ++e) {
        x[e] = (float)v[e];
        s += x[e];
        s2 = fmaf(x[e], x[e], s2);
    }
#pragma unroll
    for (int off = 32; off; off >>= 1) {
        s  += __shfl_xor(s, off);
        s2 += __shfl_xor(s2, off);
    }
    const float mean = s * (1.f / E_DIM);
    const float var  = s2 * (1.f / E_DIM) - mean * mean;
    const float rstd = rsqrtf(var + LN_EPS);
    f32x4 g0 = *(const f32x4*)g;
    f32x4 g1 = *(const f32x4*)(g + 4);
    f32x4 b0 = *(const f32x4*)b;
    f32x4 b1 = *(const f32x4*)(b + 4);
    f16x8 o;
#pragma unroll
    for (int e = 0; e < 4; ++e) {
        o[e]     = (_Float16)fmaxf(fmaf((x[e]     - mean) * rstd, g0[e], b0[e]), 0.f);
        o[e + 4] = (_Float16)fmaxf(fmaf((x[e + 4] - mean) * rstd, g1[e], b1[e]), 0.f);
    }
    *(f16x8*)prow = o;
}

// ---------------------------------------------------------------------------
// Contention-free counting sort
// ---------------------------------------------------------------------------
__global__ __launch_bounds__(256)
void label_block_hist(const int* __restrict__ labels, int* __restrict__ blockCounts) {
    __shared__ int h[C_CLS];
    const int tid = threadIdx.x;
    if (tid < C_CLS) h[tid] = 0;
    __syncthreads();
    atomicAdd(&h[labels[blockIdx.x * 256 + tid]], 1);
    __syncthreads();
    if (tid < C_CLS) blockCounts[blockIdx.x * C_CLS + tid] = h[tid];
}

__global__ __launch_bounds__(64)
void scan_offsets(const int* __restrict__ blockCounts, int* __restrict__ counts,
                  int* __restrict__ offs, int* __restrict__ blockOffs) {
    const int c = threadIdx.x;
    int total = 0;
    for (int b = 0; b < SCAT_BLOCKS; ++b) total += blockCounts[b * C_CLS + c];
    counts[c] = total;
    __shared__ int tot[C_CLS];
    tot[c] = total;
    __syncthreads();
    int off = 0;
    for (int cc = 0; cc < c; ++cc) off += tot[cc];
    offs[c] = off;
    if (c == C_CLS - 1) offs[C_CLS] = off + total;
    int run = off;
    for (int b = 0; b < SCAT_BLOCKS; ++b) {
        blockOffs[b * C_CLS + c] = run;
        run += blockCounts[b * C_CLS + c];
    }
}

__global__ __launch_bounds__(256)
void scatter_sorted(const int* __restrict__ labels, const int* __restrict__ blockOffs,
                    int* __restrict__ members) {
    __shared__ int cur[C_CLS];
    const int tid = threadIdx.x;
    if (tid < C_CLS) cur[tid] = blockOffs[blockIdx.x * C_CLS + tid];
    __syncthreads();
    const int i = blockIdx.x * 256 + tid;
    const int c = labels[i];
    const int p = atomicAdd(&cur[c], 1);
    members[p] = i;
}

__global__ __launch_bounds__(256)
void zero_f32(float* __restrict__ p, int n) {
    int i = blockIdx.x * 256 + threadIdx.x;
    if (i < n) p[i] = 0.f;
}

// ---------------------------------------------------------------------------
// ctx_sum[c,:] += sum over class members of feat(fp16)[n,:]  (fp32 atomics)
// ---------------------------------------------------------------------------
#define CTX_SPLITS 8
__global__ __launch_bounds__(256)
void ctx_sum_kernel(const _Float16* __restrict__ feat, const int* __restrict__ members,
                    const int* __restrict__ offsets, float* __restrict__ ctx_sum) {
    const int c = blockIdx.x, split = blockIdx.y;
    const int tid = threadIdx.x;
    const int wave = tid >> 6, lane = tid & 63;
    const int start = offsets[c], end = offsets[c + 1];
    const int wg = split * 4 + wave;
    const int stride = 4 * CTX_SPLITS;

    float acc[8];
#pragma unroll
    for (int e = 0; e < 8; ++e) acc[e] = 0.f;

    int i = start + wg;
    for (; i + stride < end; i += 2 * stride) {
        const int n0 = members[i];
        const int n1 = members[i + stride];
        f16x8 r0 = *(const f16x8*)(feat + (size_t)n0 * E_DIM + lane * 8);
        f16x8 r1 = *(const f16x8*)(feat + (size_t)n1 * E_DIM + lane * 8);
#pragma unroll
        for (int e = 0; e < 8; ++e) acc[e] += (float)r0[e] + (float)r1[e];
    }
    if (i < end) {
        const int n0 = members[i];
        f16x8 r0 = *(const f16x8*)(feat + (size_t)n0 * E_DIM + lane * 8);
#pragma unroll
        for (int e = 0; e < 8; ++e) acc[e] += (float)r0[e];
    }

    __shared__ float red[4][64][8];
#pragma unroll
    for (int e = 0; e < 8; ++e) red[wave][lane][e] = acc[e];
    __syncthreads();
#pragma unroll
    for (int t = 0; t < 2; ++t) {
        const int col = tid * 2 + t;
        const int ln = col >> 3, e = col & 7;
        float s = red[0][ln][e] + red[1][ln][e] + red[2][ln][e] + red[3][ln][e];
        atomicAdd(&ctx_sum[c * E_DIM + col], s);
    }
}

// ---------------------------------------------------------------------------
// q[c,:] = (ctx_sum[c,:]/count) @ Wq + bq   (fp32, tiny)
// ---------------------------------------------------------------------------
__global__ __launch_bounds__(256)
void row_gemm_q(const float* __restrict__ ctx_sum, const int* __restrict__ counts,
                const float* __restrict__ Wq, const float* __restrict__ bq,
                float* __restrict__ q) {
    const int c = blockIdx.x;
    const int tid = threadIdx.x;
    const float inv = 1.f / (float)counts[c];
    __shared__ float xrow[E_DIM];
    xrow[tid]       = ctx_sum[c * E_DIM + tid] * inv;
    xrow[tid + 256] = ctx_sum[c * E_DIM + tid + 256] * inv;
    __syncthreads();
    float a0 = 0.f, a1 = 0.f;
#pragma unroll 8
    for (int k = 0; k < E_DIM; ++k) {
        float cv = xrow[k];
        a0 = fmaf(cv, Wq[(size_t)k * E_DIM + tid], a0);
        a1 = fmaf(cv, Wq[(size_t)k * E_DIM + tid + 256], a1);
    }
    q[c * E_DIM + tid]       = a0 + bq[tid];
    q[c * E_DIM + tid + 256] = a1 + bq[tid + 256];
}

// ---------------------------------------------------------------------------
// Segment attention, phase 1. K/V packed: row n = [K(512) | V(512)] in bufKV.
// ---------------------------------------------------------------------------
#define KV_LD 1024
__global__ __launch_bounds__(256)
void attn_partial(const float* __restrict__ q, const _Float16* __restrict__ kv,
                  const int* __restrict__ members, const int* __restrict__ offsets,
                  float* __restrict__ pm, float* __restrict__ pl,
                  float* __restrict__ po) {
    const int c = blockIdx.x, h = blockIdx.y, s = blockIdx.z;
    const int tid = threadIdx.x;
    const int wave = tid >> 6, lane = tid & 63;
    const int start = offsets[c], end = offsets[c + 1];
    const int g = s * 4 + wave;                 // 0..15

    const float* qrow = q + c * E_DIM + h * DHD;
    float qv[64];
#pragma unroll
    for (int d = 0; d < 64; ++d) qv[d] = qrow[d];

    __shared__ float ps[4][64];
    float m = -INFINITY, lsum = 0.f, out = 0.f; // lane owns output dim `lane`

    for (int ch0 = start + g * 64; ch0 < end; ch0 += 16 * 64) {
        const int nvalid = min(64, end - ch0);
        const int idx = ch0 + lane;
        const int mi = members[idx < end ? idx : end - 1];
        const _Float16* krow = kv + (size_t)mi * KV_LD + h * DHD;
        float dot = 0.f;
#pragma unroll
        for (int j = 0; j < 8; ++j) {
            f16x8 kr = *(const f16x8*)(krow + j * 8);
#pragma unroll
            for (int e = 0; e < 8; ++e)
                dot = fmaf((float)kr[e], qv[j * 8 + e], dot);
        }
        float sc = (lane < nvalid) ? dot * 0.125f : -INFINITY;
        float cm = sc;
#pragma unroll
        for (int off = 32; off; off >>= 1) cm = fmaxf(cm, __shfl_xor(cm, off));
        const float nm = fmaxf(m, cm);
        const float alpha = __expf(m - nm);
        const float p = (lane < nvalid) ? __expf(sc - nm) : 0.f;
        ps[wave][lane] = p;
        out *= alpha;
        lsum *= alpha;
        m = nm;
        asm volatile("" ::: "memory");
#pragma unroll 16
        for (int j = 0; j < 64; ++j) {
            const int nj = __shfl(mi, j);
            const float pj = ps[wave][j];
            const float vv = (float)kv[(size_t)nj * KV_LD + E_DIM + h * DHD + lane];
            out = fmaf(pj, vv, out);
            lsum += pj;
        }
    }

    __shared__ float rm[4], rl[4], racc[4][64];
    racc[wave][lane] = out;
    if (lane == 0) { rm[wave] = m; rl[wave] = lsum; }
    __syncthreads();
    if (wave == 0) {
        float M = fmaxf(fmaxf(rm[0], rm[1]), fmaxf(rm[2], rm[3]));
        float o = 0.f, Lt = 0.f;
#pragma unroll
        for (int w = 0; w < 4; ++w) {
            float al = __expf(rm[w] - M);   // all-empty wave -> 0
            o  += al * racc[w][lane];
            Lt += al * rl[w];
        }
        const int pidx = (c * H_HEADS + h) * ATTN_SPLITS + s;
        po[pidx * 64 + lane] = o;
        if (lane == 0) { pm[pidx] = M; pl[pidx] = Lt; }
    }
}

// ---------------------------------------------------------------------------
// Segment attention, phase 2: merge ATTN_SPLITS partials per (c,h).
// ---------------------------------------------------------------------------
__global__ __launch_bounds__(64)
void attn_combine(const float* __restrict__ pm, const float* __restrict__ pl,
                  const float* __restrict__ po, float* __restrict__ attn_out) {
    const int ch = blockIdx.x;          // c*H + h
    const int lane = threadIdx.x;
    float M = -INFINITY;
#pragma unroll
    for (int s = 0; s < ATTN_SPLITS; ++s) M = fmaxf(M, pm[ch * ATTN_SPLITS + s]);
    float o = 0.f, Lt = 0.f;
#pragma unroll
    for (int s = 0; s < ATTN_SPLITS; ++s) {
        const int pidx = ch * ATTN_SPLITS + s;
        float al = __expf(pm[pidx] - M);
        o  += al * po[pidx * 64 + lane];
        Lt += al * pl[pidx];
    }
    attn_out[ch * DHD + lane] = o / Lt;
}

// ---------------------------------------------------------------------------
// proto = attn_out @ Wo + bo; out (+)= coef_l * proto
// ---------------------------------------------------------------------------
__global__ __launch_bounds__(256)
void proto_accum(const float* __restrict__ attn_out, const float* __restrict__ Wo,
                 const float* __restrict__ bo, const float* __restrict__ lvlw,
                 const float* __restrict__ lvlt, int l, float* __restrict__ out) {
    const int c = blockIdx.x;
    const int tid = threadIdx.x;
    __shared__ float xrow[E_DIM];
    xrow[tid]       = attn_out[c * E_DIM + tid];
    xrow[tid + 256] = attn_out[c * E_DIM + tid + 256];
    __syncthreads();
    float a0 = 0.f, a1 = 0.f;
#pragma unroll 8
    for (int k = 0; k < E_DIM; ++k) {
        float cv = xrow[k];
        a0 = fmaf(cv, Wo[(size_t)k * E_DIM + tid], a0);
        a1 = fmaf(cv, Wo[(size_t)k * E_DIM + tid + 256], a1);
    }
    float w0 = lvlw[0], w1 = lvlw[1], w2 = lvlw[2];
    float mx = fmaxf(w0, fmaxf(w1, w2));
    float e0 = expf(w0 - mx), e1 = expf(w1 - mx), e2 = expf(w2 - mx);
    float ssum = e0 + e1 + e2;
    float lw = (l == 0 ? e0 : (l == 1 ? e1 : e2)) / ssum;
    float coef = lw / lvlt[l];
    float r0 = (a0 + bo[tid]) * coef;
    float r1 = (a1 + bo[tid + 256]) * coef;
    if (l == 0) {
        out[c * E_DIM + tid]       = r0;
        out[c * E_DIM + tid + 256] = r1;
    } else {
        out[c * E_DIM + tid]       += r0;
        out[c * E_DIM + tid + 256] += r1;
    }
}

// ---------------------------------------------------------------------------
extern "C" void kernel_launch(void* const* d_in, const int* in_sizes, int n_in,
                              void* d_out, int out_size, void* d_ws, size_t ws_size,
                              hipStream_t stream) {
    const float* X      = (const float*)d_in[0];
    const int*   labels = (const int*)  d_in[1];
    const float* W1     = (const float*)d_in[2];
    const float* b1     = (const float*)d_in[3];   // [3,512] flat == fused bias
    const float* gamma  = (const float*)d_in[4];
    const float* beta   = (const float*)d_in[5];
    const float* W2     = (const float*)d_in[6];
    const float* b2     = (const float*)d_in[7];
    const float* Wq     = (const float*)d_in[8];
    const float* bq     = (const float*)d_in[9];
    const float* Wk     = (const float*)d_in[10];
    const float* bk     = (const float*)d_in[11];
    const float* Wv     = (const float*)d_in[12];
    const float* bv     = (const float*)d_in[13];
    const float* Wo     = (const float*)d_in[14];
    const float* bo     = (const float*)d_in[15];
    const float* lvlw   = (const float*)d_in[16];
    const float* lvlt   = (const float*)d_in[17];
    float* out = (float*)d_out;

    // Workspace carve (~453 MB of the 512 MiB ws)
    char* p = (char*)d_ws;
    const size_t MSZ = (size_t)E_DIM * E_DIM;                       // 262144
    _Float16* Xh     = (_Float16*)p; p += (size_t)N_SUP * E_DIM * 2;        // 64 MB
    _Float16* bufPall= (_Float16*)p; p += (size_t)N_SUP * E_DIM * L_LEV * 2;// 192 MB
    _Float16* bufF   = (_Float16*)p; p += (size_t)N_SUP * E_DIM * 2;        // 64 MB
    _Float16* bufKV  = (_Float16*)p; p += (size_t)N_SUP * KV_LD * 2;        // 128 MB
    _Float16* W1allT = (_Float16*)p; p += L_LEV * MSZ * 2;
    _Float16* W2allT = (_Float16*)p; p += L_LEV * MSZ * 2;
    _Float16* WkvT   = (_Float16*)p; p += 2 * MSZ * 2;
    float* bkv  = (float*)p; p += KV_LD * sizeof(float);
    float* ctxs = (float*)p; p += C_CLS * E_DIM * sizeof(float);
    float* qb   = (float*)p; p += C_CLS * E_DIM * sizeof(float);
    float* ao   = (float*)p; p += C_CLS * E_DIM * sizeof(float);
    float* pm   = (float*)p; p += C_CLS * H_HEADS * ATTN_SPLITS * sizeof(float);
    float* pl   = (float*)p; p += C_CLS * H_HEADS * ATTN_SPLITS * sizeof(float);
    float* po   = (float*)p; p += C_CLS * H_HEADS * ATTN_SPLITS * 64 * sizeof(float);
    int* counts      = (int*)p; p += 256;
    int* offs        = (int*)p; p += 512;
    int* members     = (int*)p; p += (size_t)N_SUP * sizeof(int);
    int* blockCounts = (int*)p; p += (size_t)SCAT_BLOCKS * C_CLS * sizeof(int);
    int* blockOffs   = (int*)p; p += (size_t)SCAT_BLOCKS * C_CLS * sizeof(int);

    // Class membership: contention-free counting sort
    label_block_hist<<<SCAT_BLOCKS, 256, 0, stream>>>(labels, blockCounts);
    scan_offsets<<<1, 64, 0, stream>>>(blockCounts, counts, offs, blockOffs);
    scatter_sorted<<<SCAT_BLOCKS, 256, 0, stream>>>(labels, blockOffs, members);

    // One-time conversions (single dispatches)
    const int n4 = N_SUP * E_DIM / 4;
    conv32to16<<<n4 / 256, 256, 0, stream>>>(X, Xh, n4);
    transpose_all<<<dim3(16, 16, 8), 256, 0, stream>>>(W1, W2, Wk, Wv,
                                                       W1allT, W2allT, WkvT);
    concat_bias<<<KV_LD / 256, 256, 0, stream>>>(bk, bv, bkv);

    const int nRow = N_SUP / 128;
    // Fused pre = X @ [W1_0|W1_1|W1_2] + b1  -> bufPall [N x 1536]
    {
        const int nCol = (L_LEV * E_DIM) / 128;   // 12
        hgemm_bt<<<nRow * nCol, 256, 0, stream>>>(
            Xh, E_DIM, W1allT, b1, bufPall, L_LEV * E_DIM, nCol);
    }
    // LN+ReLU for all 3 levels in one dispatch
    ln_relu_all<<<dim3(N_SUP / 4, L_LEV), 256, 0, stream>>>(bufPall, gamma, beta);

    for (int l = 0; l < L_LEV; ++l) {
        // feat = h_l @ W2_l + b2_l  (A strided within bufPall)
        {
            const int nCol = E_DIM / 128;         // 4
            hgemm_bt<<<nRow * nCol, 256, 0, stream>>>(
                bufPall + (size_t)l * E_DIM, L_LEV * E_DIM,
                W2allT + (size_t)l * MSZ, b2 + l * E_DIM, bufF, E_DIM, nCol);
        }
        // [K|V] = feat @ [Wk|Wv] + [bk|bv]  -> bufKV [N x 1024]
        {
            const int nCol = KV_LD / 128;         // 8
            hgemm_bt<<<nRow * nCol, 256, 0, stream>>>(
                bufF, E_DIM, WkvT, bkv, bufKV, KV_LD, nCol);
        }
        zero_f32<<<(C_CLS * E_DIM) / 256, 256, 0, stream>>>(ctxs, C_CLS * E_DIM);
        ctx_sum_kernel<<<dim3(C_CLS, CTX_SPLITS), 256, 0, stream>>>(bufF, members, offs, ctxs);
        row_gemm_q<<<C_CLS, 256, 0, stream>>>(ctxs, counts, Wq, bq, qb);
        attn_partial<<<dim3(C_CLS, H_HEADS, ATTN_SPLITS), 256, 0, stream>>>(
            qb, bufKV, members, offs, pm, pl, po);
        attn_combine<<<C_CLS * H_HEADS, 64, 0, stream>>>(pm, pl, po, ao);
        proto_accum<<<C_CLS, 256, 0, stream>>>(ao, Wo, bo, lvlw, lvlt, l, out);
    }
}

// Round 9
// 1086.206 us; speedup vs baseline: 6.1482x; 1.1386x over previous
//
#include <hip/hip_runtime.h>
#include <math.h>

// Problem constants (fixed by the reference)
#define N_SUP 65536
#define E_DIM 512
#define H_HEADS 8
#define C_CLS 64
#define DHD 64
#define L_LEV 3
#define LN_EPS 1e-5f
#define ATTN_SPLITS 4
#define SCAT_BLOCKS 256        // N_SUP / 256
#define KV_LD 1024

typedef _Float16 f16x8 __attribute__((ext_vector_type(8)));
typedef _Float16 f16x4 __attribute__((ext_vector_type(4)));
typedef float f32x4 __attribute__((ext_vector_type(4)));

// ---------------------------------------------------------------------------
// async global->LDS copy, 16B per lane (wave-uniform base + lane*16).
// ---------------------------------------------------------------------------
__device__ __forceinline__ void gload_lds16(const void* g, void* lds) {
    __builtin_amdgcn_global_load_lds((const __attribute__((address_space(1))) void*)g,
                                     (__attribute__((address_space(3))) void*)lds,
                                     16, 0, 0);
}

// ---------------------------------------------------------------------------
// fp16 GEMM: C[M x Ncols] = A[M x 512] @ B + bias; Bt is B^T [Ncols x 512].
// 1D grid.x = nRow*nCol 128x128 tiles, band-swizzled (all col-tiles of a row
// 64-dispatches apart & same XCD under round-robin -> A fetched once).
// grid.y = batch; per-batch strides for A/Bt/bias/C.
// ---------------------------------------------------------------------------
__global__ __launch_bounds__(256)
void hgemm_bt(const _Float16* __restrict__ A, int lda, size_t aStride,
              const _Float16* __restrict__ Bt, size_t btStride,
              const float* __restrict__ bias, size_t biasStride,
              _Float16* __restrict__ C, int ldc, size_t cStride, int nCol) {
    const int z = blockIdx.y;
    A += z * aStride; Bt += z * btStride; bias += z * biasStride; C += z * cStride;

    const int nRow = gridDim.x / nCol;
    const int R = nRow < 64 ? nRow : 64;
    const int bid = blockIdx.x;
    const int bandSz = R * nCol;
    const int band = bid / bandSz;
    const int rem = bid % bandSz;
    const int colT = rem / R;
    const int rowT = band * R + (rem % R);

    __shared__ _Float16 As[128][32];
    __shared__ _Float16 Bs[128][32];
    const int tid = threadIdx.x;
    const int wave = tid >> 6, lane = tid & 63;
    const int row0 = rowT * 128, col0 = colT * 128;
    const int wm = (wave & 1) * 64, wn = (wave >> 1) * 64;

    const int ci0 = wave * 128 + lane, ci1 = ci0 + 64;
    const int r0 = ci0 >> 2, gc0 = (ci0 & 3) ^ ((r0 >> 1) & 3);
    const int r1 = ci1 >> 2, gc1 = (ci1 & 3) ^ ((r1 >> 1) & 3);
    const _Float16* Ar0 = A + (size_t)(row0 + r0) * lda + gc0 * 8;
    const _Float16* Ar1 = A + (size_t)(row0 + r1) * lda + gc1 * 8;
    const _Float16* Br0 = Bt + (size_t)(col0 + r0) * E_DIM + gc0 * 8;
    const _Float16* Br1 = Bt + (size_t)(col0 + r1) * E_DIM + gc1 * 8;
    char* ldsA = (char*)&As[0][0] + wave * 2048;
    char* ldsB = (char*)&Bs[0][0] + wave * 2048;

    const int m = lane & 15, q = lane >> 4;
    const int koff = ((q ^ ((m >> 1) & 3))) * 8;

    f32x4 acc[4][4];
#pragma unroll
    for (int i = 0; i < 4; ++i)
#pragma unroll
        for (int j = 0; j < 4; ++j) acc[i][j] = (f32x4){0.f, 0.f, 0.f, 0.f};

    for (int k0 = 0; k0 < E_DIM; k0 += 32) {
        gload_lds16(Ar0 + k0, ldsA);
        gload_lds16(Ar1 + k0, ldsA + 1024);
        gload_lds16(Br0 + k0, ldsB);
        gload_lds16(Br1 + k0, ldsB + 1024);
        __syncthreads();

        f16x8 af[4], bf[4];
#pragma unroll
        for (int i = 0; i < 4; ++i)
            af[i] = *(const f16x8*)&As[wm + i * 16 + m][koff];
#pragma unroll
        for (int j = 0; j < 4; ++j)
            bf[j] = *(const f16x8*)&Bs[wn + j * 16 + m][koff];
#pragma unroll
        for (int i = 0; i < 4; ++i)
#pragma unroll
            for (int j = 0; j < 4; ++j)
                acc[i][j] = __builtin_amdgcn_mfma_f32_16x16x32_f16(af[i], bf[j], acc[i][j], 0, 0, 0);
        __syncthreads();
    }

    // C/D layout: col = lane&15, row = (lane>>4)*4 + reg
#pragma unroll
    for (int i = 0; i < 4; ++i) {
        const int rbase = row0 + wm + i * 16 + q * 4;
#pragma unroll
        for (int j = 0; j < 4; ++j) {
            const int col = col0 + wn + j * 16 + m;
            const float bv = bias[col];
#pragma unroll
            for (int r = 0; r < 4; ++r)
                C[(size_t)(rbase + r) * ldc + col] = (_Float16)(acc[i][j][r] + bv);
        }
    }
}

// ---------------------------------------------------------------------------
// fp32 -> fp16 elementwise (vectorized x4)
// ---------------------------------------------------------------------------
__global__ __launch_bounds__(256)
void conv32to16(const float* __restrict__ in, _Float16* __restrict__ out, int n4) {
    int i = blockIdx.x * 256 + threadIdx.x;
    if (i < n4) {
        f32x4 v = ((const f32x4*)in)[i];
        f16x4 o = {(_Float16)v[0], (_Float16)v[1], (_Float16)v[2], (_Float16)v[3]};
        ((f16x4*)out)[i] = o;
    }
}

// ---------------------------------------------------------------------------
// Batched weight transpose fp32->fp16: z 0..2: W1[l]->W1allT; z 3..5:
// Wk,Wv,Wq -> WkvqT rows 0/512/1024.
// ---------------------------------------------------------------------------
__global__ __launch_bounds__(256)
void transpose_all(const float* __restrict__ W1, const float* __restrict__ Wk,
                   const float* __restrict__ Wv, const float* __restrict__ Wq,
                   _Float16* __restrict__ W1allT, _Float16* __restrict__ WkvqT) {
    const int z = blockIdx.z;
    const float* src;
    _Float16* dst;
    const size_t MSZ = (size_t)E_DIM * E_DIM;
    if (z < 3)       { src = W1 + z * MSZ; dst = W1allT + z * MSZ; }
    else if (z == 3) { src = Wk;           dst = WkvqT; }
    else if (z == 4) { src = Wv;           dst = WkvqT + MSZ; }
    else             { src = Wq;           dst = WkvqT + 2 * MSZ; }

    __shared__ float t[32][33];
    const int k0 = blockIdx.x * 32, n0 = blockIdx.y * 32;
    const int tx = threadIdx.x & 31, ty = threadIdx.x >> 5;
#pragma unroll
    for (int r = 0; r < 32; r += 8)
        t[ty + r][tx] = src[(size_t)(k0 + ty + r) * E_DIM + n0 + tx];
    __syncthreads();
#pragma unroll
    for (int r = 0; r < 32; r += 8)
        dst[(size_t)(n0 + ty + r) * E_DIM + k0 + tx] = (_Float16)t[tx][ty + r];
}

// ---------------------------------------------------------------------------
// Composed biases: bcomp[l][n] for n<512: b2_l@Wk + bk; [512,1024): Wv/bv;
// [1024,1536): Wq/bq.
// ---------------------------------------------------------------------------
__global__ __launch_bounds__(256)
void bias_compose(const float* __restrict__ b2, const float* __restrict__ Wk,
                  const float* __restrict__ Wv, const float* __restrict__ Wq,
                  const float* __restrict__ bk, const float* __restrict__ bv,
                  const float* __restrict__ bq, float* __restrict__ bcomp) {
    const int l = blockIdx.y;
    const int n = blockIdx.x * 256 + threadIdx.x;   // 0..1535
    const float* W; const float* bb; int nn;
    if (n < 512)       { W = Wk; bb = bk; nn = n; }
    else if (n < 1024) { W = Wv; bb = bv; nn = n - 512; }
    else               { W = Wq; bb = bq; nn = n - 1024; }
    float acc = 0.f;
    for (int j = 0; j < E_DIM; ++j)
        acc = fmaf(b2[l * E_DIM + j], W[(size_t)j * E_DIM + nn], acc);
    bcomp[l * 1536 + n] = acc + bb[nn];
}

// ---------------------------------------------------------------------------
// LayerNorm + ReLU over bufPall [N x 1536], all 3 levels in one dispatch.
// ---------------------------------------------------------------------------
__global__ __launch_bounds__(256)
void ln_relu_all(_Float16* __restrict__ P, const float* __restrict__ gamma,
                 const float* __restrict__ beta) {
    const int row = blockIdx.x * 4 + (threadIdx.x >> 6);
    const int l = blockIdx.y;
    const int lane = threadIdx.x & 63;
    _Float16* prow = P + (size_t)row * (L_LEV * E_DIM) + l * E_DIM + lane * 8;
    const float* g = gamma + l * E_DIM + lane * 8;
    const float* b = beta  + l * E_DIM + lane * 8;
    f16x8 v = *(const f16x8*)prow;
    float x[8];
    float s = 0.f, s2 = 0.f;
#pragma unroll
    for (int e = 0; e < 8; ++e) {
        x[e] = (float)v[e];
        s += x[e];
        s2 = fmaf(x[e], x[e], s2);
    }
#pragma unroll
    for (int off = 32; off; off >>= 1) {
        s  += __shfl_xor(s, off);
        s2 += __shfl_xor(s2, off);
    }
    const float mean = s * (1.f / E_DIM);
    const float var  = s2 * (1.f / E_DIM) - mean * mean;
    const float rstd = rsqrtf(var + LN_EPS);
    f32x4 g0 = *(const f32x4*)g;
    f32x4 g1 = *(const f32x4*)(g + 4);
    f32x4 b0 = *(const f32x4*)b;
    f32x4 b1 = *(const f32x4*)(b + 4);
    f16x8 o;
#pragma unroll
    for (int e = 0; e < 4; ++e) {
        o[e]     = (_Float16)fmaxf(fmaf((x[e]     - mean) * rstd, g0[e], b0[e]), 0.f);
        o[e + 4] = (_Float16)fmaxf(fmaf((x[e + 4] - mean) * rstd, g1[e], b1[e]), 0.f);
    }
    *(f16x8*)prow = o;
}

// ---------------------------------------------------------------------------
// Contention-free counting sort
// ---------------------------------------------------------------------------
__global__ __launch_bounds__(256)
void label_block_hist(const int* __restrict__ labels, int* __restrict__ blockCounts) {
    __shared__ int h[C_CLS];
    const int tid = threadIdx.x;
    if (tid < C_CLS) h[tid] = 0;
    __syncthreads();
    atomicAdd(&h[labels[blockIdx.x * 256 + tid]], 1);
    __syncthreads();
    if (tid < C_CLS) blockCounts[blockIdx.x * C_CLS + tid] = h[tid];
}

__global__ __launch_bounds__(64)
void scan_offsets(const int* __restrict__ blockCounts, int* __restrict__ counts,
                  int* __restrict__ offs, int* __restrict__ blockOffs) {
    const int c = threadIdx.x;
    int total = 0;
    for (int b = 0; b < SCAT_BLOCKS; ++b) total += blockCounts[b * C_CLS + c];
    counts[c] = total;
    __shared__ int tot[C_CLS];
    tot[c] = total;
    __syncthreads();
    int off = 0;
    for (int cc = 0; cc < c; ++cc) off += tot[cc];
    offs[c] = off;
    if (c == C_CLS - 1) offs[C_CLS] = off + total;
    int run = off;
    for (int b = 0; b < SCAT_BLOCKS; ++b) {
        blockOffs[b * C_CLS + c] = run;
        run += blockCounts[b * C_CLS + c];
    }
}

__global__ __launch_bounds__(256)
void scatter_sorted(const int* __restrict__ labels, const int* __restrict__ blockOffs,
                    int* __restrict__ members) {
    __shared__ int cur[C_CLS];
    const int tid = threadIdx.x;
    if (tid < C_CLS) cur[tid] = blockOffs[blockIdx.x * C_CLS + tid];
    __syncthreads();
    const int i = blockIdx.x * 256 + tid;
    const int c = labels[i];
    const int p = atomicAdd(&cur[c], 1);
    members[p] = i;
}

__global__ __launch_bounds__(256)
void zero_f32(float* __restrict__ p, int n) {
    int i = blockIdx.x * 256 + threadIdx.x;
    if (i < n) p[i] = 0.f;
}

// ---------------------------------------------------------------------------
// hsum[c,:] += sum over class members of src(fp16)[n, coff..coff+512)
// src row stride ld. (fp32 atomics into hsum)
// ---------------------------------------------------------------------------
#define CTX_SPLITS 8
__global__ __launch_bounds__(256)
void ctx_sum_kernel(const _Float16* __restrict__ src, int ld,
                    const int* __restrict__ members, const int* __restrict__ offsets,
                    float* __restrict__ hsum) {
    const int c = blockIdx.x, split = blockIdx.y;
    const int tid = threadIdx.x;
    const int wave = tid >> 6, lane = tid & 63;
    const int start = offsets[c], end = offsets[c + 1];
    const int wg = split * 4 + wave;
    const int stride = 4 * CTX_SPLITS;

    float acc[8];
#pragma unroll
    for (int e = 0; e < 8; ++e) acc[e] = 0.f;

    int i = start + wg;
    for (; i + stride < end; i += 2 * stride) {
        const int n0 = members[i];
        const int n1 = members[i + stride];
        f16x8 r0 = *(const f16x8*)(src + (size_t)n0 * ld + lane * 8);
        f16x8 r1 = *(const f16x8*)(src + (size_t)n1 * ld + lane * 8);
#pragma unroll
        for (int e = 0; e < 8; ++e) acc[e] += (float)r0[e] + (float)r1[e];
    }
    if (i < end) {
        const int n0 = members[i];
        f16x8 r0 = *(const f16x8*)(src + (size_t)n0 * ld + lane * 8);
#pragma unroll
        for (int e = 0; e < 8; ++e) acc[e] += (float)r0[e];
    }

    __shared__ float red[4][64][8];
#pragma unroll
    for (int e = 0; e < 8; ++e) red[wave][lane][e] = acc[e];
    __syncthreads();
#pragma unroll
    for (int t = 0; t < 2; ++t) {
        const int col = tid * 2 + t;
        const int ln = col >> 3, e = col & 7;
        float s = red[0][ln][e] + red[1][ln][e] + red[2][ln][e] + red[3][ln][e];
        atomicAdd(&hsum[c * E_DIM + col], s);
    }
}

// ---------------------------------------------------------------------------
// q[c,:] = (hsum[c,:]/count) @ W2q + bias, W2qT fp16 n-major [512][512].
// ---------------------------------------------------------------------------
__global__ __launch_bounds__(256)
void row_gemm_q(const float* __restrict__ hsum, const int* __restrict__ counts,
                const _Float16* __restrict__ W2qT, const float* __restrict__ bias,
                float* __restrict__ q) {
    const int c = blockIdx.x;
    const int tid = threadIdx.x;
    const float inv = 1.f / (float)counts[c];
    __shared__ float xrow[E_DIM];
    xrow[tid]       = hsum[c * E_DIM + tid] * inv;
    xrow[tid + 256] = hsum[c * E_DIM + tid + 256] * inv;
    __syncthreads();
    const int n0 = tid, n1 = tid + 256;
    float a0 = 0.f, a1 = 0.f;
#pragma unroll 4
    for (int k0 = 0; k0 < E_DIM; k0 += 8) {
        f16x8 w0 = *(const f16x8*)(W2qT + (size_t)n0 * E_DIM + k0);
        f16x8 w1 = *(const f16x8*)(W2qT + (size_t)n1 * E_DIM + k0);
#pragma unroll
        for (int e = 0; e < 8; ++e) {
            const float xv = xrow[k0 + e];
            a0 = fmaf(xv, (float)w0[e], a0);
            a1 = fmaf(xv, (float)w1[e], a1);
        }
    }
    q[c * E_DIM + n0] = a0 + bias[n0];
    q[c * E_DIM + n1] = a1 + bias[n1];
}

// ---------------------------------------------------------------------------
// Segment attention, phase 1. K/V packed: row n = [K(512) | V(512)] in bufKV.
// ---------------------------------------------------------------------------
__global__ __launch_bounds__(256)
void attn_partial(const float* __restrict__ q, const _Float16* __restrict__ kv,
                  const int* __restrict__ members, const int* __restrict__ offsets,
                  float* __restrict__ pm, float* __restrict__ pl,
                  float* __restrict__ po) {
    const int c = blockIdx.x, h = blockIdx.y, s = blockIdx.z;
    const int tid = threadIdx.x;
    const int wave = tid >> 6, lane = tid & 63;
    const int start = offsets[c], end = offsets[c + 1];
    const int g = s * 4 + wave;                 // 0..15

    const float* qrow = q + c * E_DIM + h * DHD;
    float qv[64];
#pragma unroll
    for (int d = 0; d < 64; ++d) qv[d] = qrow[d];

    __shared__ float ps[4][64];
    float m = -INFINITY, lsum = 0.f, out = 0.f; // lane owns output dim `lane`

    for (int ch0 = start + g * 64; ch0 < end; ch0 += 16 * 64) {
        const int nvalid = min(64, end - ch0);
        const int idx = ch0 + lane;
        const int mi = members[idx < end ? idx : end - 1];
        const _Float16* krow = kv + (size_t)mi * KV_LD + h * DHD;
        float dot = 0.f;
#pragma unroll
        for (int j = 0; j < 8; ++j) {
            f16x8 kr = *(const f16x8*)(krow + j * 8);
#pragma unroll
            for (int e = 0; e < 8; ++e)
                dot = fmaf((float)kr[e], qv[j * 8 + e], dot);
        }
        float sc = (lane < nvalid) ? dot * 0.125f : -INFINITY;
        float cm = sc;
#pragma unroll
        for (int off = 32; off; off >>= 1) cm = fmaxf(cm, __shfl_xor(cm, off));
        const float nm = fmaxf(m, cm);
        const float alpha = __expf(m - nm);
        const float p = (lane < nvalid) ? __expf(sc - nm) : 0.f;
        ps[wave][lane] = p;
        out *= alpha;
        lsum *= alpha;
        m = nm;
        asm volatile("" ::: "memory");
#pragma unroll 16
        for (int j = 0; j < 64; ++j) {
            const int nj = __shfl(mi, j);
            const float pj = ps[wave][j];
            const float vv = (float)kv[(size_t)nj * KV_LD + E_DIM + h * DHD + lane];
            out = fmaf(pj, vv, out);
            lsum += pj;
        }
    }

    __shared__ float rm[4], rl[4], racc[4][64];
    racc[wave][lane] = out;
    if (lane == 0) { rm[wave] = m; rl[wave] = lsum; }
    __syncthreads();
    if (wave == 0) {
        float M = fmaxf(fmaxf(rm[0], rm[1]), fmaxf(rm[2], rm[3]));
        float o = 0.f, Lt = 0.f;
#pragma unroll
        for (int w = 0; w < 4; ++w) {
            float al = __expf(rm[w] - M);   // all-empty wave -> 0
            o  += al * racc[w][lane];
            Lt += al * rl[w];
        }
        const int pidx = (c * H_HEADS + h) * ATTN_SPLITS + s;
        po[pidx * 64 + lane] = o;
        if (lane == 0) { pm[pidx] = M; pl[pidx] = Lt; }
    }
}

// ---------------------------------------------------------------------------
// Segment attention, phase 2: merge ATTN_SPLITS partials per (c,h).
// ---------------------------------------------------------------------------
__global__ __launch_bounds__(64)
void attn_combine(const float* __restrict__ pm, const float* __restrict__ pl,
                  const float* __restrict__ po, float* __restrict__ attn_out) {
    const int ch = blockIdx.x;          // c*H + h
    const int lane = threadIdx.x;
    float M = -INFINITY;
#pragma unroll
    for (int s = 0; s < ATTN_SPLITS; ++s) M = fmaxf(M, pm[ch * ATTN_SPLITS + s]);
    float o = 0.f, Lt = 0.f;
#pragma unroll
    for (int s = 0; s < ATTN_SPLITS; ++s) {
        const int pidx = ch * ATTN_SPLITS + s;
        float al = __expf(pm[pidx] - M);
        o  += al * po[pidx * 64 + lane];
        Lt += al * pl[pidx];
    }
    attn_out[ch * DHD + lane] = o / Lt;
}

// ---------------------------------------------------------------------------
// proto = attn_out @ Wo + bo; out (+)= coef_l * proto
// ---------------------------------------------------------------------------
__global__ __launch_bounds__(256)
void proto_accum(const float* __restrict__ attn_out, const float* __restrict__ Wo,
                 const float* __restrict__ bo, const float* __restrict__ lvlw,
                 const float* __restrict__ lvlt, int l, float* __restrict__ out) {
    const int c = blockIdx.x;
    const int tid = threadIdx.x;
    __shared__ float xrow[E_DIM];
    xrow[tid]       = attn_out[c * E_DIM + tid];
    xrow[tid + 256] = attn_out[c * E_DIM + tid + 256];
    __syncthreads();
    float a0 = 0.f, a1 = 0.f;
#pragma unroll 8
    for (int k = 0; k < E_DIM; ++k) {
        float cv = xrow[k];
        a0 = fmaf(cv, Wo[(size_t)k * E_DIM + tid], a0);
        a1 = fmaf(cv, Wo[(size_t)k * E_DIM + tid + 256], a1);
    }
    float w0 = lvlw[0], w1 = lvlw[1], w2 = lvlw[2];
    float mx = fmaxf(w0, fmaxf(w1, w2));
    float e0 = expf(w0 - mx), e1 = expf(w1 - mx), e2 = expf(w2 - mx);
    float ssum = e0 + e1 + e2;
    float lw = (l == 0 ? e0 : (l == 1 ? e1 : e2)) / ssum;
    float coef = lw / lvlt[l];
    float r0 = (a0 + bo[tid]) * coef;
    float r1 = (a1 + bo[tid + 256]) * coef;
    if (l == 0) {
        out[c * E_DIM + tid]       = r0;
        out[c * E_DIM + tid + 256] = r1;
    } else {
        out[c * E_DIM + tid]       += r0;
        out[c * E_DIM + tid + 256] += r1;
    }
}

// ---------------------------------------------------------------------------
extern "C" void kernel_launch(void* const* d_in, const int* in_sizes, int n_in,
                              void* d_out, int out_size, void* d_ws, size_t ws_size,
                              hipStream_t stream) {
    const float* X      = (const float*)d_in[0];
    const int*   labels = (const int*)  d_in[1];
    const float* W1     = (const float*)d_in[2];
    const float* b1     = (const float*)d_in[3];   // [3,512] flat == fused bias
    const float* gamma  = (const float*)d_in[4];
    const float* beta   = (const float*)d_in[5];
    const float* W2     = (const float*)d_in[6];
    const float* b2     = (const float*)d_in[7];
    const float* Wq     = (const float*)d_in[8];
    const float* bq     = (const float*)d_in[9];
    const float* Wk     = (const float*)d_in[10];
    const float* bk     = (const float*)d_in[11];
    const float* Wv     = (const float*)d_in[12];
    const float* bv     = (const float*)d_in[13];
    const float* Wo     = (const float*)d_in[14];
    const float* bo     = (const float*)d_in[15];
    const float* lvlw   = (const float*)d_in[16];
    const float* lvlt   = (const float*)d_in[17];
    float* out = (float*)d_out;

    // Workspace carve (~395 MB of the 512 MiB ws)
    char* p = (char*)d_ws;
    const size_t MSZ = (size_t)E_DIM * E_DIM;                       // 262144
    _Float16* Xh      = (_Float16*)p; p += (size_t)N_SUP * E_DIM * 2;         // 64 MB
    _Float16* bufPall = (_Float16*)p; p += (size_t)N_SUP * E_DIM * L_LEV * 2; // 192 MB
    _Float16* bufKV   = (_Float16*)p; p += (size_t)N_SUP * KV_LD * 2;         // 128 MB
    _Float16* W1allT  = (_Float16*)p; p += L_LEV * MSZ * 2;      // 1.5 MB
    _Float16* WkvqT   = (_Float16*)p; p += 3 * MSZ * 2;          // 1.5 MB (Wk,Wv,Wq ^T)
    _Float16* W2f16   = (_Float16*)p; p += L_LEV * MSZ * 2;      // 1.5 MB (orig layout)
    _Float16* W2compT = (_Float16*)p; p += (size_t)L_LEV * 1536 * E_DIM * 2; // 4.5 MB
    float* zeros512 = (float*)p; p += E_DIM * sizeof(float);
    float* bcomp = (float*)p; p += L_LEV * 1536 * sizeof(float);
    float* hsum  = (float*)p; p += C_CLS * E_DIM * sizeof(float);
    float* qb    = (float*)p; p += C_CLS * E_DIM * sizeof(float);
    float* ao    = (float*)p; p += C_CLS * E_DIM * sizeof(float);
    float* pm    = (float*)p; p += C_CLS * H_HEADS * ATTN_SPLITS * sizeof(float);
    float* pl    = (float*)p; p += C_CLS * H_HEADS * ATTN_SPLITS * sizeof(float);
    float* po    = (float*)p; p += C_CLS * H_HEADS * ATTN_SPLITS * 64 * sizeof(float);
    int* counts      = (int*)p; p += 256;
    int* offs        = (int*)p; p += 512;
    int* members     = (int*)p; p += (size_t)N_SUP * sizeof(int);
    int* blockCounts = (int*)p; p += (size_t)SCAT_BLOCKS * C_CLS * sizeof(int);
    int* blockOffs   = (int*)p; p += (size_t)SCAT_BLOCKS * C_CLS * sizeof(int);

    // Class membership: contention-free counting sort
    label_block_hist<<<SCAT_BLOCKS, 256, 0, stream>>>(labels, blockCounts);
    scan_offsets<<<1, 64, 0, stream>>>(blockCounts, counts, offs, blockOffs);
    scatter_sorted<<<SCAT_BLOCKS, 256, 0, stream>>>(labels, blockOffs, members);

    // Conversions / transposes
    conv32to16<<<(N_SUP * E_DIM / 4) / 256, 256, 0, stream>>>(X, Xh, N_SUP * E_DIM / 4);
    conv32to16<<<(int)(L_LEV * MSZ / 4 / 256), 256, 0, stream>>>(W2, W2f16, L_LEV * MSZ / 4);
    transpose_all<<<dim3(16, 16, 6), 256, 0, stream>>>(W1, Wk, Wv, Wq, W1allT, WkvqT);
    zero_f32<<<2, 256, 0, stream>>>(zeros512, E_DIM);

    // Composed weights: W2compT_l = [WkT;WvT;WqT] @ W2T_l  (fp16 MFMA, batched)
    // rows 0..1023 -> KV Bt (n-major), rows 1024..1535 -> q weights (n-major)
    hgemm_bt<<<dim3(12 * 4, L_LEV), 256, 0, stream>>>(
        WkvqT, E_DIM, 0, W2f16, MSZ, zeros512, 0,
        W2compT, E_DIM, (size_t)1536 * E_DIM, 4);
    bias_compose<<<dim3(6, L_LEV), 256, 0, stream>>>(b2, Wk, Wv, Wq, bk, bv, bq, bcomp);

    const int nRow = N_SUP / 128;
    // Fused pre = X @ [W1_0|W1_1|W1_2] + b1  -> bufPall [N x 1536]
    hgemm_bt<<<dim3(nRow * 12, 1), 256, 0, stream>>>(
        Xh, E_DIM, 0, W1allT, 0, b1, 0, bufPall, L_LEV * E_DIM, 0, 12);
    // LN+ReLU for all 3 levels in one dispatch (bufPall now holds h)
    ln_relu_all<<<dim3(N_SUP / 4, L_LEV), 256, 0, stream>>>(bufPall, gamma, beta);

    for (int l = 0; l < L_LEV; ++l) {
        // [K|V] = h_l @ (W2_l@[Wk|Wv]) + composed bias  -> bufKV [N x 1024]
        hgemm_bt<<<dim3(nRow * 8, 1), 256, 0, stream>>>(
            bufPall + (size_t)l * E_DIM, L_LEV * E_DIM, 0,
            W2compT + (size_t)l * 1536 * E_DIM, 0,
            bcomp + l * 1536, 0, bufKV, KV_LD, 0, 8);
        // hmean: segment sum of h_l
        zero_f32<<<(C_CLS * E_DIM) / 256, 256, 0, stream>>>(hsum, C_CLS * E_DIM);
        ctx_sum_kernel<<<dim3(C_CLS, CTX_SPLITS), 256, 0, stream>>>(
            bufPall + (size_t)l * E_DIM, L_LEV * E_DIM, members, offs, hsum);
        // q = (hmean) @ (W2_l@Wq) + composed bias
        row_gemm_q<<<C_CLS, 256, 0, stream>>>(
            hsum, counts, W2compT + (size_t)l * 1536 * E_DIM + (size_t)1024 * E_DIM,
            bcomp + l * 1536 + 1024, qb);
        attn_partial<<<dim3(C_CLS, H_HEADS, ATTN_SPLITS), 256, 0, stream>>>(
            qb, bufKV, members, offs, pm, pl, po);
        attn_combine<<<C_CLS * H_HEADS, 64, 0, stream>>>(pm, pl, po, ao);
        proto_accum<<<C_CLS, 256, 0, stream>>>(ao, Wo, bo, lvlw, lvlt, l, out);
    }
}

// Round 11
// 1002.853 us; speedup vs baseline: 6.6592x; 1.0831x over previous
//
#include <hip/hip_runtime.h>
#include <math.h>

// Problem constants (fixed by the reference)
#define N_SUP 65536
#define E_DIM 512
#define H_HEADS 8
#define C_CLS 64
#define DHD 64
#define L_LEV 3
#define LN_EPS 1e-5f
#define ATTN_SPLITS 8
#define CTX_SPLITS 16
#define SCAT_BLOCKS 256        // N_SUP / 256
#define KV_LD 1024

typedef _Float16 f16x8 __attribute__((ext_vector_type(8)));
typedef _Float16 f16x4 __attribute__((ext_vector_type(4)));
typedef float f32x4 __attribute__((ext_vector_type(4)));

// ---------------------------------------------------------------------------
// async global->LDS copy, 16B per lane (wave-uniform base + lane*16).
// ---------------------------------------------------------------------------
__device__ __forceinline__ void gload_lds16(const void* g, void* lds) {
    __builtin_amdgcn_global_load_lds((const __attribute__((address_space(1))) void*)g,
                                     (__attribute__((address_space(3))) void*)lds,
                                     16, 0, 0);
}

// ---------------------------------------------------------------------------
// fp16 GEMM: C[M x Ncols] = A[M x 512] @ B + bias; Bt is B^T [Ncols x 512].
// 1D grid.x = nRow*nCol 128x128 tiles, band-swizzled (all col-tiles of a row
// <=64 dispatches apart & same XCD under round-robin -> A fetched once).
// grid.y = batch; per-batch strides for A/Bt/bias/C.
// ---------------------------------------------------------------------------
__global__ __launch_bounds__(256)
void hgemm_bt(const _Float16* __restrict__ A, int lda, size_t aStride,
              const _Float16* __restrict__ Bt, size_t btStride,
              const float* __restrict__ bias, size_t biasStride,
              _Float16* __restrict__ C, int ldc, size_t cStride, int nCol) {
    const int z = blockIdx.y;
    A += z * aStride; Bt += z * btStride; bias += z * biasStride; C += z * cStride;

    const int nRow = gridDim.x / nCol;
    const int R = nRow < 64 ? nRow : 64;
    const int bid = blockIdx.x;
    const int bandSz = R * nCol;
    const int band = bid / bandSz;
    const int rem = bid % bandSz;
    const int colT = rem / R;
    const int rowT = band * R + (rem % R);

    __shared__ _Float16 As[128][32];
    __shared__ _Float16 Bs[128][32];
    const int tid = threadIdx.x;
    const int wave = tid >> 6, lane = tid & 63;
    const int row0 = rowT * 128, col0 = colT * 128;
    const int wm = (wave & 1) * 64, wn = (wave >> 1) * 64;

    const int ci0 = wave * 128 + lane, ci1 = ci0 + 64;
    const int r0 = ci0 >> 2, gc0 = (ci0 & 3) ^ ((r0 >> 1) & 3);
    const int r1 = ci1 >> 2, gc1 = (ci1 & 3) ^ ((r1 >> 1) & 3);
    const _Float16* Ar0 = A + (size_t)(row0 + r0) * lda + gc0 * 8;
    const _Float16* Ar1 = A + (size_t)(row0 + r1) * lda + gc1 * 8;
    const _Float16* Br0 = Bt + (size_t)(col0 + r0) * E_DIM + gc0 * 8;
    const _Float16* Br1 = Bt + (size_t)(col0 + r1) * E_DIM + gc1 * 8;
    char* ldsA = (char*)&As[0][0] + wave * 2048;
    char* ldsB = (char*)&Bs[0][0] + wave * 2048;

    const int m = lane & 15, q = lane >> 4;
    const int koff = ((q ^ ((m >> 1) & 3))) * 8;

    f32x4 acc[4][4];
#pragma unroll
    for (int i = 0; i < 4; ++i)
#pragma unroll
        for (int j = 0; j < 4; ++j) acc[i][j] = (f32x4){0.f, 0.f, 0.f, 0.f};

    for (int k0 = 0; k0 < E_DIM; k0 += 32) {
        gload_lds16(Ar0 + k0, ldsA);
        gload_lds16(Ar1 + k0, ldsA + 1024);
        gload_lds16(Br0 + k0, ldsB);
        gload_lds16(Br1 + k0, ldsB + 1024);
        __syncthreads();

        f16x8 af[4], bf[4];
#pragma unroll
        for (int i = 0; i < 4; ++i)
            af[i] = *(const f16x8*)&As[wm + i * 16 + m][koff];
#pragma unroll
        for (int j = 0; j < 4; ++j)
            bf[j] = *(const f16x8*)&Bs[wn + j * 16 + m][koff];
#pragma unroll
        for (int i = 0; i < 4; ++i)
#pragma unroll
            for (int j = 0; j < 4; ++j)
                acc[i][j] = __builtin_amdgcn_mfma_f32_16x16x32_f16(af[i], bf[j], acc[i][j], 0, 0, 0);
        __syncthreads();
    }

    // C/D layout: col = lane&15, row = (lane>>4)*4 + reg
#pragma unroll
    for (int i = 0; i < 4; ++i) {
        const int rbase = row0 + wm + i * 16 + q * 4;
#pragma unroll
        for (int j = 0; j < 4; ++j) {
            const int col = col0 + wn + j * 16 + m;
            const float bv = bias[col];
#pragma unroll
            for (int r = 0; r < 4; ++r)
                C[(size_t)(rbase + r) * ldc + col] = (_Float16)(acc[i][j][r] + bv);
        }
    }
}

// ---------------------------------------------------------------------------
// fp32 -> fp16 elementwise (vectorized x4)
// ---------------------------------------------------------------------------
__global__ __launch_bounds__(256)
void conv32to16(const float* __restrict__ in, _Float16* __restrict__ out, int n4) {
    int i = blockIdx.x * 256 + threadIdx.x;
    if (i < n4) {
        f32x4 v = ((const f32x4*)in)[i];
        f16x4 o = {(_Float16)v[0], (_Float16)v[1], (_Float16)v[2], (_Float16)v[3]};
        ((f16x4*)out)[i] = o;
    }
}

// ---------------------------------------------------------------------------
// Batched weight transpose fp32->fp16: z 0..2: W1[l]->W1allT; z 3..5:
// Wk,Wv,Wq -> WkvqT rows 0/512/1024.
// ---------------------------------------------------------------------------
__global__ __launch_bounds__(256)
void transpose_all(const float* __restrict__ W1, const float* __restrict__ Wk,
                   const float* __restrict__ Wv, const float* __restrict__ Wq,
                   _Float16* __restrict__ W1allT, _Float16* __restrict__ WkvqT) {
    const int z = blockIdx.z;
    const float* src;
    _Float16* dst;
    const size_t MSZ = (size_t)E_DIM * E_DIM;
    if (z < 3)       { src = W1 + z * MSZ; dst = W1allT + z * MSZ; }
    else if (z == 3) { src = Wk;           dst = WkvqT; }
    else if (z == 4) { src = Wv;           dst = WkvqT + MSZ; }
    else             { src = Wq;           dst = WkvqT + 2 * MSZ; }

    __shared__ float t[32][33];
    const int k0 = blockIdx.x * 32, n0 = blockIdx.y * 32;
    const int tx = threadIdx.x & 31, ty = threadIdx.x >> 5;
#pragma unroll
    for (int r = 0; r < 32; r += 8)
        t[ty + r][tx] = src[(size_t)(k0 + ty + r) * E_DIM + n0 + tx];
    __syncthreads();
#pragma unroll
    for (int r = 0; r < 32; r += 8)
        dst[(size_t)(n0 + ty + r) * E_DIM + k0 + tx] = (_Float16)t[tx][ty + r];
}

// ---------------------------------------------------------------------------
// Composed biases: bcomp[l][n] for n<512: b2_l@Wk + bk; [512,1024): Wv/bv;
// [1024,1536): Wq/bq.
// ---------------------------------------------------------------------------
__global__ __launch_bounds__(256)
void bias_compose(const float* __restrict__ b2, const float* __restrict__ Wk,
                  const float* __restrict__ Wv, const float* __restrict__ Wq,
                  const float* __restrict__ bk, const float* __restrict__ bv,
                  const float* __restrict__ bq, float* __restrict__ bcomp) {
    const int l = blockIdx.y;
    const int n = blockIdx.x * 256 + threadIdx.x;   // 0..1535
    const float* W; const float* bb; int nn;
    if (n < 512)       { W = Wk; bb = bk; nn = n; }
    else if (n < 1024) { W = Wv; bb = bv; nn = n - 512; }
    else               { W = Wq; bb = bq; nn = n - 1024; }
    float acc = 0.f;
    for (int j = 0; j < E_DIM; ++j)
        acc = fmaf(b2[l * E_DIM + j], W[(size_t)j * E_DIM + nn], acc);
    bcomp[l * 1536 + n] = acc + bb[nn];
}

// ---------------------------------------------------------------------------
// LayerNorm + ReLU over bufPall [N x 1536], all 3 levels in one dispatch.
// ---------------------------------------------------------------------------
__global__ __launch_bounds__(256)
void ln_relu_all(_Float16* __restrict__ P, const float* __restrict__ gamma,
                 const float* __restrict__ beta) {
    const int row = blockIdx.x * 4 + (threadIdx.x >> 6);
    const int l = blockIdx.y;
    const int lane = threadIdx.x & 63;
    _Float16* prow = P + (size_t)row * (L_LEV * E_DIM) + l * E_DIM + lane * 8;
    const float* g = gamma + l * E_DIM + lane * 8;
    const float* b = beta  + l * E_DIM + lane * 8;
    f16x8 v = *(const f16x8*)prow;
    float x[8];
    float s = 0.f, s2 = 0.f;
#pragma unroll
    for (int e = 0; e < 8; ++e) {
        x[e] = (float)v[e];
        s += x[e];
        s2 = fmaf(x[e], x[e], s2);
    }
#pragma unroll
    for (int off = 32; off; off >>= 1) {
        s  += __shfl_xor(s, off);
        s2 += __shfl_xor(s2, off);
    }
    const float mean = s * (1.f / E_DIM);
    const float var  = s2 * (1.f / E_DIM) - mean * mean;
    const float rstd = rsqrtf(var + LN_EPS);
    f32x4 g0 = *(const f32x4*)g;
    f32x4 g1 = *(const f32x4*)(g + 4);
    f32x4 b0 = *(const f32x4*)b;
    f32x4 b1 = *(const f32x4*)(b + 4);
    f16x8 o;
#pragma unroll
    for (int e = 0; e < 4; ++e) {
        o[e]     = (_Float16)fmaxf(fmaf((x[e]     - mean) * rstd, g0[e], b0[e]), 0.f);
        o[e + 4] = (_Float16)fmaxf(fmaf((x[e + 4] - mean) * rstd, g1[e], b1[e]), 0.f);
    }
    *(f16x8*)prow = o;
}

// ---------------------------------------------------------------------------
// Contention-free counting sort
// ---------------------------------------------------------------------------
__global__ __launch_bounds__(256)
void label_block_hist(const int* __restrict__ labels, int* __restrict__ blockCounts) {
    __shared__ int h[C_CLS];
    const int tid = threadIdx.x;
    if (tid < C_CLS) h[tid] = 0;
    __syncthreads();
    atomicAdd(&h[labels[blockIdx.x * 256 + tid]], 1);
    __syncthreads();
    if (tid < C_CLS) blockCounts[blockIdx.x * C_CLS + tid] = h[tid];
}

__global__ __launch_bounds__(64)
void scan_offsets(const int* __restrict__ blockCounts, int* __restrict__ counts,
                  int* __restrict__ offs, int* __restrict__ blockOffs) {
    const int c = threadIdx.x;
    int total = 0;
    for (int b = 0; b < SCAT_BLOCKS; ++b) total += blockCounts[b * C_CLS + c];
    counts[c] = total;
    __shared__ int tot[C_CLS];
    tot[c] = total;
    __syncthreads();
    int off = 0;
    for (int cc = 0; cc < c; ++cc) off += tot[cc];
    offs[c] = off;
    if (c == C_CLS - 1) offs[C_CLS] = off + total;
    int run = off;
    for (int b = 0; b < SCAT_BLOCKS; ++b) {
        blockOffs[b * C_CLS + c] = run;
        run += blockCounts[b * C_CLS + c];
    }
}

__global__ __launch_bounds__(256)
void scatter_sorted(const int* __restrict__ labels, const int* __restrict__ blockOffs,
                    int* __restrict__ members) {
    __shared__ int cur[C_CLS];
    const int tid = threadIdx.x;
    if (tid < C_CLS) cur[tid] = blockOffs[blockIdx.x * C_CLS + tid];
    __syncthreads();
    const int i = blockIdx.x * 256 + tid;
    const int c = labels[i];
    const int p = atomicAdd(&cur[c], 1);
    members[p] = i;
}

__global__ __launch_bounds__(256)
void zero_f32(float* __restrict__ p, int n) {
    int i = blockIdx.x * 256 + threadIdx.x;
    if (i < n) p[i] = 0.f;
}

// ---------------------------------------------------------------------------
// hpart[l][c][split][:] = partial segment-sum of h_l over class members.
// Batched over levels (grid.z); write-based (no atomics, no zero pass).
// ---------------------------------------------------------------------------
__global__ __launch_bounds__(256)
void ctx_partial(const _Float16* __restrict__ P, const int* __restrict__ members,
                 const int* __restrict__ offsets, float* __restrict__ hpart) {
    const int c = blockIdx.x, split = blockIdx.y, l = blockIdx.z;
    const _Float16* src = P + (size_t)l * E_DIM;
    const int tid = threadIdx.x;
    const int wave = tid >> 6, lane = tid & 63;
    const int start = offsets[c], end = offsets[c + 1];
    const int wg = split * 4 + wave;
    const int stride = 4 * CTX_SPLITS;
    const int ld = L_LEV * E_DIM;

    float acc[8];
#pragma unroll
    for (int e = 0; e < 8; ++e) acc[e] = 0.f;

    int i = start + wg;
    for (; i + stride < end; i += 2 * stride) {
        const int n0 = members[i];
        const int n1 = members[i + stride];
        f16x8 r0 = *(const f16x8*)(src + (size_t)n0 * ld + lane * 8);
        f16x8 r1 = *(const f16x8*)(src + (size_t)n1 * ld + lane * 8);
#pragma unroll
        for (int e = 0; e < 8; ++e) acc[e] += (float)r0[e] + (float)r1[e];
    }
    if (i < end) {
        const int n0 = members[i];
        f16x8 r0 = *(const f16x8*)(src + (size_t)n0 * ld + lane * 8);
#pragma unroll
        for (int e = 0; e < 8; ++e) acc[e] += (float)r0[e];
    }

    __shared__ float red[4][64][8];
#pragma unroll
    for (int e = 0; e < 8; ++e) red[wave][lane][e] = acc[e];
    __syncthreads();
    float* dst = hpart + (((size_t)l * C_CLS + c) * CTX_SPLITS + split) * E_DIM;
#pragma unroll
    for (int t = 0; t < 2; ++t) {
        const int col = tid * 2 + t;
        const int ln = col >> 3, e = col & 7;
        dst[col] = red[0][ln][e] + red[1][ln][e] + red[2][ln][e] + red[3][ln][e];
    }
}

// ---------------------------------------------------------------------------
// q[l][c][:] = (mean of h_l over class c) @ (W2_l@Wq) + composed bias.
// Batched over levels (grid.y). Reduces the CTX_SPLITS partials inline.
// ---------------------------------------------------------------------------
__global__ __launch_bounds__(256)
void row_gemm_q(const float* __restrict__ hpart, const int* __restrict__ counts,
                const _Float16* __restrict__ W2compT, const float* __restrict__ bcomp,
                float* __restrict__ q) {
    const int c = blockIdx.x, l = blockIdx.y;
    const int tid = threadIdx.x;
    const float inv = 1.f / (float)counts[c];
    __shared__ float xrow[E_DIM];
    const float* hp = hpart + ((size_t)l * C_CLS + c) * CTX_SPLITS * E_DIM;
    float s0 = 0.f, s1 = 0.f;
#pragma unroll
    for (int s = 0; s < CTX_SPLITS; ++s) {
        s0 += hp[s * E_DIM + tid];
        s1 += hp[s * E_DIM + tid + 256];
    }
    xrow[tid]       = s0 * inv;
    xrow[tid + 256] = s1 * inv;
    __syncthreads();

    const _Float16* Wq = W2compT + (size_t)l * 1536 * E_DIM + (size_t)1024 * E_DIM;
    const float* bias = bcomp + l * 1536 + 1024;
    const int n0 = tid, n1 = tid + 256;
    float a0 = 0.f, a1 = 0.f;
#pragma unroll 4
    for (int k0 = 0; k0 < E_DIM; k0 += 8) {
        f16x8 w0 = *(const f16x8*)(Wq + (size_t)n0 * E_DIM + k0);
        f16x8 w1 = *(const f16x8*)(Wq + (size_t)n1 * E_DIM + k0);
#pragma unroll
        for (int e = 0; e < 8; ++e) {
            const float xv = xrow[k0 + e];
            a0 = fmaf(xv, (float)w0[e], a0);
            a1 = fmaf(xv, (float)w1[e], a1);
        }
    }
    float* qq = q + (size_t)l * C_CLS * E_DIM;
    qq[c * E_DIM + n0] = a0 + bias[n0];
    qq[c * E_DIM + n1] = a1 + bias[n1];
}

// ---------------------------------------------------------------------------
// Segment attention, phase 1. K/V packed: row n = [K(512) | V(512)] in bufKV.
// grid (C, H, ATTN_SPLITS). NOTE: splits/waves beyond the member count are
// legitimately empty (m=-inf); the combine must guard exp(-inf - -inf).
// ---------------------------------------------------------------------------
__global__ __launch_bounds__(256)
void attn_partial(const float* __restrict__ q, const _Float16* __restrict__ kv,
                  const int* __restrict__ members, const int* __restrict__ offsets,
                  float* __restrict__ pm, float* __restrict__ pl,
                  float* __restrict__ po) {
    const int c = blockIdx.x, h = blockIdx.y, s = blockIdx.z;
    const int tid = threadIdx.x;
    const int wave = tid >> 6, lane = tid & 63;
    const int start = offsets[c], end = offsets[c + 1];
    const int g = s * 4 + wave;                 // 0..4*SPLITS-1

    float qv[64];
    const bool active = (start + g * 64) < end;
    if (active) {
        const float* qrow = q + c * E_DIM + h * DHD;
#pragma unroll
        for (int d = 0; d < 64; ++d) qv[d] = qrow[d];
    }

    __shared__ float ps[4][64];
    float m = -INFINITY, lsum = 0.f, out = 0.f; // lane owns output dim `lane`

    for (int ch0 = start + g * 64; ch0 < end; ch0 += 4 * ATTN_SPLITS * 64) {
        const int nvalid = min(64, end - ch0);
        const int idx = ch0 + lane;
        const int mi = members[idx < end ? idx : end - 1];
        const _Float16* krow = kv + (size_t)mi * KV_LD + h * DHD;
        float dot = 0.f;
#pragma unroll
        for (int j = 0; j < 8; ++j) {
            f16x8 kr = *(const f16x8*)(krow + j * 8);
#pragma unroll
            for (int e = 0; e < 8; ++e)
                dot = fmaf((float)kr[e], qv[j * 8 + e], dot);
        }
        float sc = (lane < nvalid) ? dot * 0.125f : -INFINITY;
        float cm = sc;
#pragma unroll
        for (int off = 32; off; off >>= 1) cm = fmaxf(cm, __shfl_xor(cm, off));
        const float nm = fmaxf(m, cm);
        const float alpha = __expf(m - nm);
        const float p = (lane < nvalid) ? __expf(sc - nm) : 0.f;
        ps[wave][lane] = p;
        out *= alpha;
        lsum *= alpha;
        m = nm;
        asm volatile("" ::: "memory");
#pragma unroll 16
        for (int j = 0; j < 64; ++j) {
            const int nj = __shfl(mi, j);
            const float pj = ps[wave][j];
            const float vv = (float)kv[(size_t)nj * KV_LD + E_DIM + h * DHD + lane];
            out = fmaf(pj, vv, out);
            lsum += pj;
        }
    }

    __shared__ float rm[4], rl[4], racc[4][64];
    racc[wave][lane] = out;
    if (lane == 0) { rm[wave] = m; rl[wave] = lsum; }
    __syncthreads();
    if (wave == 0) {
        float M = fmaxf(fmaxf(rm[0], rm[1]), fmaxf(rm[2], rm[3]));
        float o = 0.f, Lt = 0.f;
#pragma unroll
        for (int w = 0; w < 4; ++w) {
            // guard: rm[w]==-inf (empty wave) AND possibly M==-inf (all empty)
            // -> exp(-inf - -inf) = NaN without the guard. [R10 NaN bug]
            const float al = (rm[w] > -INFINITY) ? __expf(rm[w] - M) : 0.f;
            o  += al * racc[w][lane];
            Lt += al * rl[w];
        }
        const int pidx = (c * H_HEADS + h) * ATTN_SPLITS + s;
        po[pidx * 64 + lane] = o;      // 0 for all-empty block
        if (lane == 0) { pm[pidx] = M; pl[pidx] = Lt; }
    }
}

// ---------------------------------------------------------------------------
// Combine ATTN_SPLITS partials for all 8 heads of class c into LDS xrow,
// then proto = xrow @ Wo + bo; out (+)= coef_l * proto.
// ---------------------------------------------------------------------------
__global__ __launch_bounds__(256)
void proto_accum(const float* __restrict__ pm, const float* __restrict__ pl,
                 const float* __restrict__ po, const float* __restrict__ Wo,
                 const float* __restrict__ bo, const float* __restrict__ lvlw,
                 const float* __restrict__ lvlt, int l, float* __restrict__ out) {
    const int c = blockIdx.x;
    const int tid = threadIdx.x;
    const int wave = tid >> 6, lane = tid & 63;
    __shared__ float xrow[E_DIM];
#pragma unroll
    for (int hh = wave; hh < H_HEADS; hh += 4) {
        const int ch = c * H_HEADS + hh;
        float M = -INFINITY;
#pragma unroll
        for (int s = 0; s < ATTN_SPLITS; ++s) M = fmaxf(M, pm[ch * ATTN_SPLITS + s]);
        float o = 0.f, Lt = 0.f;
#pragma unroll
        for (int s = 0; s < ATTN_SPLITS; ++s) {
            const int pidx = ch * ATTN_SPLITS + s;
            // guard empty split: pm=-inf -> weight 0 (avoids 0*NaN / exp NaN)
            const float al = (pm[pidx] > -INFINITY) ? __expf(pm[pidx] - M) : 0.f;
            o  += al * po[pidx * 64 + lane];
            Lt += al * pl[pidx];
        }
        xrow[hh * 64 + lane] = o / Lt;
    }
    __syncthreads();

    float a0 = 0.f, a1 = 0.f;
#pragma unroll 8
    for (int k = 0; k < E_DIM; ++k) {
        float cv = xrow[k];
        a0 = fmaf(cv, Wo[(size_t)k * E_DIM + tid], a0);
        a1 = fmaf(cv, Wo[(size_t)k * E_DIM + tid + 256], a1);
    }
    float w0 = lvlw[0], w1 = lvlw[1], w2 = lvlw[2];
    float mx = fmaxf(w0, fmaxf(w1, w2));
    float e0 = expf(w0 - mx), e1 = expf(w1 - mx), e2 = expf(w2 - mx);
    float ssum = e0 + e1 + e2;
    float lw = (l == 0 ? e0 : (l == 1 ? e1 : e2)) / ssum;
    float coef = lw / lvlt[l];
    float r0 = (a0 + bo[tid]) * coef;
    float r1 = (a1 + bo[tid + 256]) * coef;
    if (l == 0) {
        out[c * E_DIM + tid]       = r0;
        out[c * E_DIM + tid + 256] = r1;
    } else {
        out[c * E_DIM + tid]       += r0;
        out[c * E_DIM + tid + 256] += r1;
    }
}

// ---------------------------------------------------------------------------
extern "C" void kernel_launch(void* const* d_in, const int* in_sizes, int n_in,
                              void* d_out, int out_size, void* d_ws, size_t ws_size,
                              hipStream_t stream) {
    const float* X      = (const float*)d_in[0];
    const int*   labels = (const int*)  d_in[1];
    const float* W1     = (const float*)d_in[2];
    const float* b1     = (const float*)d_in[3];   // [3,512] flat == fused bias
    const float* gamma  = (const float*)d_in[4];
    const float* beta   = (const float*)d_in[5];
    const float* W2     = (const float*)d_in[6];
    const float* b2     = (const float*)d_in[7];
    const float* Wq     = (const float*)d_in[8];
    const float* bq     = (const float*)d_in[9];
    const float* Wk     = (const float*)d_in[10];
    const float* bk     = (const float*)d_in[11];
    const float* Wv     = (const float*)d_in[12];
    const float* bv     = (const float*)d_in[13];
    const float* Wo     = (const float*)d_in[14];
    const float* bo     = (const float*)d_in[15];
    const float* lvlw   = (const float*)d_in[16];
    const float* lvlt   = (const float*)d_in[17];
    float* out = (float*)d_out;

    // Workspace carve (~401 MB of the 512 MiB ws)
    char* p = (char*)d_ws;
    const size_t MSZ = (size_t)E_DIM * E_DIM;                       // 262144
    _Float16* Xh      = (_Float16*)p; p += (size_t)N_SUP * E_DIM * 2;         // 64 MB
    _Float16* bufPall = (_Float16*)p; p += (size_t)N_SUP * E_DIM * L_LEV * 2; // 192 MB
    _Float16* bufKV   = (_Float16*)p; p += (size_t)N_SUP * KV_LD * 2;         // 128 MB
    _Float16* W1allT  = (_Float16*)p; p += L_LEV * MSZ * 2;
    _Float16* WkvqT   = (_Float16*)p; p += 3 * MSZ * 2;
    _Float16* W2f16   = (_Float16*)p; p += L_LEV * MSZ * 2;
    _Float16* W2compT = (_Float16*)p; p += (size_t)L_LEV * 1536 * E_DIM * 2;
    float* zeros512 = (float*)p; p += E_DIM * sizeof(float);
    float* bcomp = (float*)p; p += L_LEV * 1536 * sizeof(float);
    float* hpart = (float*)p; p += (size_t)L_LEV * C_CLS * CTX_SPLITS * E_DIM * sizeof(float); // 6 MB
    float* qb    = (float*)p; p += (size_t)L_LEV * C_CLS * E_DIM * sizeof(float);
    float* pm    = (float*)p; p += C_CLS * H_HEADS * ATTN_SPLITS * sizeof(float);
    float* pl    = (float*)p; p += C_CLS * H_HEADS * ATTN_SPLITS * sizeof(float);
    float* po    = (float*)p; p += (size_t)C_CLS * H_HEADS * ATTN_SPLITS * 64 * sizeof(float);
    int* counts      = (int*)p; p += 256;
    int* offs        = (int*)p; p += 512;
    int* members     = (int*)p; p += (size_t)N_SUP * sizeof(int);
    int* blockCounts = (int*)p; p += (size_t)SCAT_BLOCKS * C_CLS * sizeof(int);
    int* blockOffs   = (int*)p; p += (size_t)SCAT_BLOCKS * C_CLS * sizeof(int);

    // Class membership: contention-free counting sort
    label_block_hist<<<SCAT_BLOCKS, 256, 0, stream>>>(labels, blockCounts);
    scan_offsets<<<1, 64, 0, stream>>>(blockCounts, counts, offs, blockOffs);
    scatter_sorted<<<SCAT_BLOCKS, 256, 0, stream>>>(labels, blockOffs, members);

    // Conversions / transposes
    conv32to16<<<(N_SUP * E_DIM / 4) / 256, 256, 0, stream>>>(X, Xh, N_SUP * E_DIM / 4);
    conv32to16<<<(int)(L_LEV * MSZ / 4 / 256), 256, 0, stream>>>(W2, W2f16, L_LEV * MSZ / 4);
    transpose_all<<<dim3(16, 16, 6), 256, 0, stream>>>(W1, Wk, Wv, Wq, W1allT, WkvqT);
    zero_f32<<<2, 256, 0, stream>>>(zeros512, E_DIM);

    // Composed weights: W2compT_l = [WkT;WvT;WqT] @ W2T_l  (fp16 MFMA, batched)
    hgemm_bt<<<dim3(12 * 4, L_LEV), 256, 0, stream>>>(
        WkvqT, E_DIM, 0, W2f16, MSZ, zeros512, 0,
        W2compT, E_DIM, (size_t)1536 * E_DIM, 4);
    bias_compose<<<dim3(6, L_LEV), 256, 0, stream>>>(b2, Wk, Wv, Wq, bk, bv, bq, bcomp);

    const int nRow = N_SUP / 128;
    // Fused pre = X @ [W1_0|W1_1|W1_2] + b1  -> bufPall [N x 1536]
    hgemm_bt<<<dim3(nRow * 12, 1), 256, 0, stream>>>(
        Xh, E_DIM, 0, W1allT, 0, b1, 0, bufPall, L_LEV * E_DIM, 0, 12);
    // LN+ReLU for all 3 levels (bufPall now holds h)
    ln_relu_all<<<dim3(N_SUP / 4, L_LEV), 256, 0, stream>>>(bufPall, gamma, beta);

    // Level-independent tail, batched once: segment-sum partials + q
    ctx_partial<<<dim3(C_CLS, CTX_SPLITS, L_LEV), 256, 0, stream>>>(
        bufPall, members, offs, hpart);
    row_gemm_q<<<dim3(C_CLS, L_LEV), 256, 0, stream>>>(
        hpart, counts, W2compT, bcomp, qb);

    for (int l = 0; l < L_LEV; ++l) {
        // [K|V] = h_l @ (W2_l@[Wk|Wv]) + composed bias  -> bufKV [N x 1024]
        hgemm_bt<<<dim3(nRow * 8, 1), 256, 0, stream>>>(
            bufPall + (size_t)l * E_DIM, L_LEV * E_DIM, 0,
            W2compT + (size_t)l * 1536 * E_DIM, 0,
            bcomp + l * 1536, 0, bufKV, KV_LD, 0, 8);
        attn_partial<<<dim3(C_CLS, H_HEADS, ATTN_SPLITS), 256, 0, stream>>>(
            qb + (size_t)l * C_CLS * E_DIM, bufKV, members, offs, pm, pl, po);
        proto_accum<<<C_CLS, 256, 0, stream>>>(pm, pl, po, Wo, bo, lvlw, lvlt, l, out);
    }
}